// Round 8
// baseline (896.066 us; speedup 1.0000x reference)
//
#include <hip/hip_runtime.h>

// EstraNetBlock: pre-norm linear attention (fourier feature kernel) + FFN.
// B=4, L=4096, D=1024, H=16, Dh=64, M=128 (2M=256), D_INNER=4096.
//
// R8 = R7 with the macro brace bug fixed (phases written as a plain unrolled
// loop). gemm256 = 256x256, BK=64, 8 waves (2Mx4N), 4 phases/K-tile each
// {12 ds_read | 2 gload_lds | barrier | lgkm0 | setprio 16 MFMA | barrier};
// staging order A0A2 / B0B1+vmcnt(4) / B2B3 / A1A3+vmcnt(2). LDS 2x64KB.
//
// ws layout (MB): unchanged.

#define RS128 0.08838834764831845f

typedef short bf16x8 __attribute__((ext_vector_type(8)));
typedef float f32x4 __attribute__((ext_vector_type(4)));

__device__ __forceinline__ unsigned short f2bf(float f) {
  unsigned int u = __float_as_uint(f);
  u += 0x7fffu + ((u >> 16) & 1u);
  return (unsigned short)(u >> 16);
}
__device__ __forceinline__ float bf2f(unsigned short h) {
  return __uint_as_float(((unsigned int)h) << 16);
}
__device__ __forceinline__ unsigned int pack2f(float a, float b) {
  return (unsigned int)f2bf(a) | ((unsigned int)f2bf(b) << 16);
}
__device__ __forceinline__ void gload_lds16(const void* g, void* l) {
  __builtin_amdgcn_global_load_lds(
      (const __attribute__((address_space(1))) void*)g,
      (__attribute__((address_space(3))) void*)l, 16, 0, 0);
}
__device__ __forceinline__ void barrier_pin() {
  __builtin_amdgcn_sched_barrier(0);
  __builtin_amdgcn_s_barrier();
  __builtin_amdgcn_sched_barrier(0);
}
#define WAIT_VM(N) { asm volatile("s_waitcnt vmcnt(" #N ")" ::: "memory"); __builtin_amdgcn_sched_barrier(0); }
#define WAIT_LGKM0() { asm volatile("s_waitcnt lgkmcnt(0)" ::: "memory"); __builtin_amdgcn_sched_barrier(0); }

// -------- 256x256 8-wave 4-phase GEMM: C = A @ Bt^T + bias (+res) -----------
template <bool OBF16, bool RELU, bool RES>
__global__ __launch_bounds__(512, 2) void gemm256(
    const unsigned short* __restrict__ A, const unsigned short* __restrict__ Bt,
    void* Cv, const float* __restrict__ bias, const float* res,
    int M, int N, int K) {
  __shared__ __align__(16) char lds[131072];
  const int tid = threadIdx.x;
  const int lane = tid & 63, wid = tid >> 6;
  const int e = lane & 15, g = lane >> 4;
  const int wm = wid >> 2, wn = wid & 3;
  const int ntn = N >> 8;
  const int nwg = (int)gridDim.x, cpx = nwg >> 3;
  const int swz = ((int)blockIdx.x & 7) * cpx + ((int)blockIdx.x >> 3);
  const int bm = swz / ntn, bn = swz % ntn;
  const long row0 = (long)bm << 8, col0 = (long)bn << 8;

  // staging: chunk = 64 rows x 64 k (8KB); thread row tid>>3, 16B slot tid&7,
  // global k-byte pre-XORed by ((row&7)<<4) -> LDS linear, reads XOR back.
  const int srow = tid >> 3;
  const int skb = ((tid & 7) << 4) ^ ((srow & 7) << 4);
  const unsigned short* Abase = A + (row0 + srow) * (long)K + (skb >> 1);
  const unsigned short* Bbase = Bt + (col0 + srow) * (long)K + (skb >> 1);
  const int lof = wid << 10;  // wave's 1KB slice within an 8KB chunk

  f32x4 acc[8][4] = {};
  const int nkt = K >> 6;
  const int rx = (e & 7) << 4;

  // prologue: tile 0 in steady-state order; vmcnt(2) leaves A1,A3 in flight
  {
    char* b0 = lds;
    gload_lds16(Abase + 0 * 64 * (long)K, b0 + 0 * 8192 + lof);
    gload_lds16(Abase + 2 * 64 * (long)K, b0 + 2 * 8192 + lof);
    gload_lds16(Bbase + 0 * 64 * (long)K, b0 + 32768 + 0 * 8192 + lof);
    gload_lds16(Bbase + 1 * 64 * (long)K, b0 + 32768 + 1 * 8192 + lof);
    gload_lds16(Bbase + 2 * 64 * (long)K, b0 + 32768 + 2 * 8192 + lof);
    gload_lds16(Bbase + 3 * 64 * (long)K, b0 + 32768 + 3 * 8192 + lof);
    gload_lds16(Abase + 1 * 64 * (long)K, b0 + 1 * 8192 + lof);
    gload_lds16(Abase + 3 * 64 * (long)K, b0 + 3 * 8192 + lof);
    WAIT_VM(2);
    barrier_pin();
  }

  for (int kt = 0; kt < nkt; ++kt) {
    char* const Ac = lds + ((kt & 1) << 16);
    char* const Anx = lds + (((kt & 1) ^ 1) << 16);
    const bool pf = (kt + 1 < nkt);
    const long kn = (long)(kt + 1) << 6;

#pragma unroll
    for (int p = 0; p < 4; ++p) {
      // --- ds_read: A quadrant p (4 reads) + B panel re-read (8 reads) ---
      bf16x8 af[2][2], bfr[4][2];
#pragma unroll
      for (int i = 0; i < 2; ++i) {
        const int r = wm * 128 + (2 * p + i) * 16 + e;
#pragma unroll
        for (int kh = 0; kh < 2; ++kh)
          af[i][kh] = *(const bf16x8*)(Ac + (r >> 6) * 8192 + (r & 63) * 128 +
                                       ((g * 16 + kh * 64) ^ rx));
      }
#pragma unroll
      for (int j = 0; j < 4; ++j) {
        const int r = wn * 64 + j * 16 + e;
#pragma unroll
        for (int kh = 0; kh < 2; ++kh)
          bfr[j][kh] = *(const bf16x8*)(Ac + 32768 + (r >> 6) * 8192 +
                                        (r & 63) * 128 + ((g * 16 + kh * 64) ^ rx));
      }
      // --- stage 2 chunks of tile kt+1; counted waits at p1/p3 ---
      if (pf) {
        if (p == 0) {
          gload_lds16(Abase + 0 * 64 * (long)K + kn, Anx + 0 * 8192 + lof);
          gload_lds16(Abase + 2 * 64 * (long)K + kn, Anx + 2 * 8192 + lof);
        } else if (p == 1) {
          gload_lds16(Bbase + 0 * 64 * (long)K + kn, Anx + 32768 + 0 * 8192 + lof);
          gload_lds16(Bbase + 1 * 64 * (long)K + kn, Anx + 32768 + 1 * 8192 + lof);
          WAIT_VM(4);  // validates A1,A3 of tile kt (issued >=2 phases ago)
        } else if (p == 2) {
          gload_lds16(Bbase + 2 * 64 * (long)K + kn, Anx + 32768 + 2 * 8192 + lof);
          gload_lds16(Bbase + 3 * 64 * (long)K + kn, Anx + 32768 + 3 * 8192 + lof);
        } else {
          gload_lds16(Abase + 1 * 64 * (long)K + kn, Anx + 1 * 8192 + lof);
          gload_lds16(Abase + 3 * 64 * (long)K + kn, Anx + 3 * 8192 + lof);
          WAIT_VM(2);  // validates kt+1's first 6 chunks; A1,A3 stay in flight
        }
      } else if (p == 1) {
        WAIT_VM(0);    // tail tile: everything resident
      }
      barrier_pin();
      WAIT_LGKM0();
      __builtin_amdgcn_s_setprio(1);
#pragma unroll
      for (int i = 0; i < 2; ++i)
#pragma unroll
        for (int j = 0; j < 4; ++j)
#pragma unroll
          for (int kh = 0; kh < 2; ++kh)
            acc[2 * p + i][j] = __builtin_amdgcn_mfma_f32_16x16x32_bf16(
                af[i][kh], bfr[j][kh], acc[2 * p + i][j], 0, 0, 0);
      __builtin_amdgcn_s_setprio(0);
      barrier_pin();
    }
  }

  // epilogue: C/D mapping col=lane&15, row=(lane>>4)*4+r
  const int r0 = wm * 128 + (g << 2);
  const int c0 = wn * 64 + e;
#pragma unroll
  for (int j = 0; j < 4; ++j) {
    const long gcol = col0 + c0 + (j << 4);
    const float bvv = bias[gcol];
#pragma unroll
    for (int mf = 0; mf < 8; ++mf) {
#pragma unroll
      for (int r = 0; r < 4; ++r) {
        const long grow = row0 + r0 + (mf << 4) + r;
        float v = acc[mf][j][r] + bvv;
        if (RES) v += res[grow * N + gcol];
        if (RELU) v = fmaxf(v, 0.f);
        if (OBF16) ((unsigned short*)Cv)[grow * N + gcol] = f2bf(v);
        else ((float*)Cv)[grow * N + gcol] = v;
      }
    }
  }
}

// -------- weight transpose + cast: W[K][N] f32 -> Wt[N][K] bf16 --------
__global__ __launch_bounds__(256) void wtrans(const float* __restrict__ W,
                                              unsigned short* __restrict__ Wt,
                                              int K, int N) {
  __shared__ float t[32][33];
  const int tx = threadIdx.x & 31, ty = threadIdx.x >> 5;
  const int n0 = blockIdx.x << 5, k0 = blockIdx.y << 5;
#pragma unroll
  for (int i = 0; i < 32; i += 8)
    t[ty + i][tx] = W[(long)(k0 + ty + i) * N + n0 + tx];
  __syncthreads();
#pragma unroll
  for (int i = 0; i < 32; i += 8)
    Wt[(long)(n0 + ty + i) * K + k0 + tx] = f2bf(t[tx][ty + i]);
}

// -------- WP prep: WPT[h*128+m][D] = 0.125 * sum_d w[D][h*64+d]*proj[d][m] ----
__global__ __launch_bounds__(256) void wp_prep(const float* __restrict__ w,
                                               const float* __restrict__ proj,
                                               unsigned short* __restrict__ WPT) {
  __shared__ float wkt[64 * 66];
  __shared__ float projL[64 * 128];
  const int tid = threadIdx.x;
  const int h = blockIdx.x, D0 = blockIdx.y << 6;
  {
    const int r = tid >> 2, dseg = (tid & 3) << 4;
    const float* src = w + (long)(D0 + r) * 1024 + h * 64 + dseg;
#pragma unroll
    for (int q = 0; q < 4; ++q) {
      float4 v = *(const float4*)(src + q * 4);
      wkt[(dseg + q * 4 + 0) * 66 + r] = v.x;
      wkt[(dseg + q * 4 + 1) * 66 + r] = v.y;
      wkt[(dseg + q * 4 + 2) * 66 + r] = v.z;
      wkt[(dseg + q * 4 + 3) * 66 + r] = v.w;
    }
#pragma unroll
    for (int q = 0; q < 8; ++q)
      *(float4*)(projL + tid * 32 + q * 4) = *(const float4*)(proj + tid * 32 + q * 4);
  }
  __syncthreads();
  const int r = tid & 63, mseg = (tid >> 6) << 5;
  float acc[32];
#pragma unroll
  for (int i = 0; i < 32; ++i) acc[i] = 0.f;
  for (int d = 0; d < 64; ++d) {
    const float wv = wkt[d * 66 + r];
    const float* pr = projL + d * 128 + mseg;
#pragma unroll
    for (int i = 0; i < 32; ++i) acc[i] += wv * pr[i];
  }
#pragma unroll
  for (int i = 0; i < 32; ++i)
    WPT[(long)(h * 128 + mseg + i) * 1024 + D0 + r] = f2bf(acc[i] * 0.125f);
}

// -------- BP prep --------
__global__ __launch_bounds__(256) void bp_prep(const float* __restrict__ b,
                                               const float* __restrict__ proj,
                                               float* __restrict__ BP) {
  const int hm = blockIdx.x * 256 + threadIdx.x;
  const int h = hm >> 7, m = hm & 127;
  float s = 0.f;
  for (int d = 0; d < 64; ++d) s += b[h * 64 + d] * proj[d * 128 + m];
  BP[hm] = s * 0.125f;
}

// -------- LayerNorm over 1024 cols, f32 in -> bf16 out --------
__global__ __launch_bounds__(256) void ln_kernel(const float* __restrict__ x,
                                                 const float* __restrict__ g,
                                                 const float* __restrict__ b,
                                                 unsigned short* __restrict__ out) {
  const int row = blockIdx.x, tid = threadIdx.x;
  const float* xr = x + (long)row * 1024;
  const float4 xv = *(const float4*)(xr + tid * 4);
  float s = xv.x + xv.y + xv.z + xv.w;
  float s2 = xv.x * xv.x + xv.y * xv.y + xv.z * xv.z + xv.w * xv.w;
#pragma unroll
  for (int off = 32; off > 0; off >>= 1) {
    s += __shfl_down(s, off);
    s2 += __shfl_down(s2, off);
  }
  __shared__ float ps[4], ps2[4];
  if ((tid & 63) == 0) { ps[tid >> 6] = s; ps2[tid >> 6] = s2; }
  __syncthreads();
  const float ts = ps[0] + ps[1] + ps[2] + ps[3];
  const float ts2 = ps2[0] + ps2[1] + ps2[2] + ps2[3];
  const float mu = ts * (1.f / 1024.f);
  const float rstd = rsqrtf(ts2 * (1.f / 1024.f) - mu * mu + 1e-5f);
  const float4 gv = *(const float4*)(g + tid * 4);
  const float4 bv = *(const float4*)(b + tid * 4);
  ushort4 o;
  o.x = f2bf((xv.x - mu) * rstd * gv.x + bv.x);
  o.y = f2bf((xv.y - mu) * rstd * gv.y + bv.y);
  o.z = f2bf((xv.z - mu) * rstd * gv.z + bv.z);
  o.w = f2bf((xv.w - mu) * rstd * gv.w + bv.w);
  *(ushort4*)(out + (long)row * 1024 + tid * 4) = o;
}

// -------- 128x128 GEMM with V-transpose epilogue (V path only) --------
__global__ __launch_bounds__(256, 2) void gemm_vt(
    const unsigned short* __restrict__ A, const unsigned short* __restrict__ Bt,
    void* Cv, const float* __restrict__ bias, int M, int N, int K) {
  __shared__ __align__(16) unsigned short sm[128 * 128];
  unsigned short* As = sm;
  unsigned short* Bs = sm + 128 * 64;
  const int tid = threadIdx.x;
  const int lane = tid & 63, wid = tid >> 6;
  const int ntn = N >> 7;
  const int bm = blockIdx.x / ntn, bn = blockIdx.x % ntn;
  const long row0 = (long)bm << 7, col0 = (long)bn << 7;
  const int wr = (wid >> 1) << 6, wc = (wid & 1) << 6;

  f32x4 acc[4][4] = {};
  const unsigned short* Ag = A + (row0 + (tid >> 3)) * (long)K + ((tid & 7) << 3);
  const unsigned short* Bg = Bt + (col0 + (tid >> 3)) * (long)K + ((tid & 7) << 3);
  char* AsB = (char*)As + (wid << 10);
  char* BsB = (char*)Bs + (wid << 10);

  for (int kt = 0; kt < K; kt += 64) {
#pragma unroll
    for (int c = 0; c < 4; ++c) {
      gload_lds16(Ag + kt + (long)c * 32 * K, AsB + (c << 12));
      gload_lds16(Bg + kt + (long)c * 32 * K, BsB + (c << 12));
    }
    __syncthreads();
#pragma unroll
    for (int kk = 0; kk < 2; ++kk) {
      const int krow = (kk << 5) + ((lane >> 4) << 3);
      bf16x8 af[4], bfr[4];
#pragma unroll
      for (int i = 0; i < 4; ++i)
        af[i] = *(const bf16x8*)(As + (wr + (i << 4) + (lane & 15)) * 64 + krow);
#pragma unroll
      for (int j = 0; j < 4; ++j)
        bfr[j] = *(const bf16x8*)(Bs + (wc + (j << 4) + (lane & 15)) * 64 + krow);
#pragma unroll
      for (int i = 0; i < 4; ++i)
#pragma unroll
        for (int j = 0; j < 4; ++j)
          acc[i][j] = __builtin_amdgcn_mfma_f32_16x16x32_bf16(af[i], bfr[j],
                                                              acc[i][j], 0, 0, 0);
    }
    __syncthreads();
  }

  const int r0 = wr + ((lane >> 4) << 2);
  const int c0l = wc + (lane & 15);
#pragma unroll
  for (int j = 0; j < 4; ++j) {
    const int cc = c0l + (j << 4);
    const float bvv = bias[col0 + cc];
#pragma unroll
    for (int i = 0; i < 4; ++i)
#pragma unroll
      for (int r = 0; r < 4; ++r) {
        const int ll = r0 + (i << 4) + r;
        sm[ll * 128 + (cc ^ ((ll & 7) << 1))] = f2bf(acc[i][j][r] + bvv);
      }
  }
  __syncthreads();
  const int c = tid & 127, lh = tid >> 7;
  const long gc = col0 + c;
  const int b = (int)(row0 >> 12);
  const int hh = (int)(gc >> 6), dd = (int)(gc & 63);
  const int lb = (int)(row0 & 4095) + lh * 64;
  char* basep = (char*)Cv + (((long)(b * 16 + hh) * 64 + dd) * 4096 + lb) * 2;
#pragma unroll
  for (int cc8 = 0; cc8 < 8; ++cc8) {
    unsigned short v[8];
#pragma unroll
    for (int k = 0; k < 8; ++k)
      v[k] = sm[(lh * 64 + cc8 * 8 + k) * 128 + (c ^ (k << 1))];
    uint4 o;
    o.x = (unsigned)v[0] | ((unsigned)v[1] << 16);
    o.y = (unsigned)v[2] | ((unsigned)v[3] << 16);
    o.z = (unsigned)v[4] | ((unsigned)v[5] << 16);
    o.w = (unsigned)v[6] | ((unsigned)v[7] << 16);
    *(uint4*)(basep + ((cc8 ^ (dd & 7)) << 4)) = o;
  }
}

// -------- kv kernel: PART[chunk][bhh][d][m] = sum_l vT[d][l]*kp[l][m] --------
__global__ __launch_bounds__(256, 2) void kv_kernel(
    const unsigned short* __restrict__ PH, const unsigned short* __restrict__ VTg,
    float* __restrict__ PART, int half) {
  __shared__ __align__(16) unsigned short Ps[64 * 128];
  __shared__ __align__(16) unsigned short Vs[64 * 64];
  __shared__ __align__(16) unsigned short KPT[256 * 64];
  const int tid = threadIdx.x;
  const int lane = tid & 63, wid = tid >> 6;
  const int bhh = blockIdx.x, chunk = blockIdx.y;
  const int b2 = bhh >> 4, h = bhh & 15;
  const int bh = (half * 2 + b2) * 16 + h;

  f32x4 acc[4][4] = {};
  const int e = lane & 15, g = lane >> 4;
  const int m = tid & 127, isin = tid >> 7;
  const int m2 = (isin << 7) + m, swm = m & 7;

  for (int ti = 0; ti < 4; ++ti) {
    const int l0 = chunk * 256 + ti * 64;
    __syncthreads();
#pragma unroll
    for (int c = 0; c < 4; ++c) {
      const int r = l0 + c * 16 + (tid >> 4);
      gload_lds16((const char*)PH + (long)(b2 * 4096 + r) * 4096 + h * 256 + (tid & 15) * 16,
                  (char*)Ps + c * 4096 + (wid << 10));
    }
#pragma unroll
    for (int c = 0; c < 2; ++c) {
      const int d = c * 32 + (tid >> 3);
      gload_lds16((const char*)VTg + ((long)(bh * 64 + d) * 4096 + l0) * 2 + (tid & 7) * 16,
                  (char*)Vs + c * 4096 + (wid << 10));
    }
    __syncthreads();
    {
      char* krow = (char*)KPT + m2 * 128;
#pragma unroll
      for (int g8 = 0; g8 < 8; ++g8) {
        unsigned pk[4];
#pragma unroll
        for (int k2 = 0; k2 < 4; ++k2) {
          const float p0 = bf2f(Ps[(g8 * 8 + k2 * 2) * 128 + m]);
          const float p1 = bf2f(Ps[(g8 * 8 + k2 * 2 + 1) * 128 + m]);
          const float v0 = (isin ? __sinf(p0) : __cosf(p0)) * RS128;
          const float v1 = (isin ? __sinf(p1) : __cosf(p1)) * RS128;
          pk[k2] = pack2f(v0, v1);
        }
        uint4 o; o.x = pk[0]; o.y = pk[1]; o.z = pk[2]; o.w = pk[3];
        *(uint4*)(krow + ((g8 ^ swm) << 4)) = o;
      }
    }
    __syncthreads();
#pragma unroll
    for (int kk = 0; kk < 2; ++kk) {
      const int ch = (kk << 2) + g;
      bf16x8 af[4], bfr[4];
#pragma unroll
      for (int i = 0; i < 4; ++i) {
        const int dr = (i << 4) + e;
        af[i] = *(const bf16x8*)((char*)Vs + dr * 128 + ((ch ^ (e & 7)) << 4));
      }
#pragma unroll
      for (int j = 0; j < 4; ++j) {
        const int mr = (wid << 6) + (j << 4) + e;
        bfr[j] = *(const bf16x8*)((char*)KPT + mr * 128 + ((ch ^ (e & 7)) << 4));
      }
#pragma unroll
      for (int i = 0; i < 4; ++i)
#pragma unroll
        for (int j = 0; j < 4; ++j)
          acc[i][j] = __builtin_amdgcn_mfma_f32_16x16x32_bf16(af[i], bfr[j],
                                                              acc[i][j], 0, 0, 0);
    }
  }
  float* slice = PART + ((long)chunk * 32 + bhh) * 16384;
#pragma unroll
  for (int i = 0; i < 4; ++i)
#pragma unroll
    for (int j = 0; j < 4; ++j)
#pragma unroll
      for (int r = 0; r < 4; ++r) {
        const int d = (i << 4) + (g << 2) + r;
        const int mc = (wid << 6) + (j << 4) + e;
        slice[d * 256 + mc] = acc[i][j][r];
      }
}

__global__ __launch_bounds__(256) void kv_reduce(const float* __restrict__ PART,
                                                 float* __restrict__ KVacc, int half) {
  const int bhh = blockIdx.x, seg = blockIdx.y;
  const long off = (long)bhh * 16384 + seg * 1024 + threadIdx.x * 4;
  float4 s = make_float4(0.f, 0.f, 0.f, 0.f);
#pragma unroll
  for (int c = 0; c < 16; ++c) {
    const float4 v = *(const float4*)(PART + ((long)c * 32) * 16384 + off);
    s.x += v.x; s.y += v.y; s.z += v.z; s.w += v.w;
  }
  *(float4*)(KVacc + (long)(half * 32) * 16384 + off) = s;
}

__global__ __launch_bounds__(256) void kvt_conv(const float* __restrict__ KVacc,
                                                unsigned short* __restrict__ KVT) {
  const int bh = blockIdx.x, tid = threadIdx.x;
  const int d = tid >> 2, mq = tid & 3;
  const float* src = KVacc + (long)bh * 16384 + d * 256 + mq * 64;
  char* dst = (char*)KVT + bh * 32768 + d * 512;
#pragma unroll
  for (int cc = 0; cc < 8; ++cc) {
    const float4 a = *(const float4*)(src + cc * 8);
    const float4 b = *(const float4*)(src + cc * 8 + 4);
    uint4 o;
    o.x = pack2f(a.x, a.y); o.y = pack2f(a.z, a.w);
    o.z = pack2f(b.x, b.y); o.w = pack2f(b.z, b.w);
    const int chunk = mq * 8 + cc;
    *(uint4*)(dst + ((chunk ^ (d & 7)) << 4)) = o;
  }
}

// -------- attn kernel: ATTN[l][h*64+d] = sum_m qp[l][m]*kvT[d][m] --------
__global__ __launch_bounds__(256, 2) void attn_kernel(
    const unsigned short* __restrict__ PH, const unsigned short* __restrict__ KVT,
    unsigned short* __restrict__ ATTN, int half) {
  __shared__ __align__(16) unsigned short QPs[64 * 256];
  __shared__ __align__(16) unsigned short KVs[64 * 256];
  const int tid = threadIdx.x;
  const int lane = tid & 63, wid = tid >> 6;
  const int bhh = blockIdx.x, chunk = blockIdx.y;
  const int b2 = bhh >> 4, h = bhh & 15;
  const int b = half * 2 + b2, bh = b * 16 + h;
  const int e = lane & 15, g = lane >> 4;

#pragma unroll
  for (int c = 0; c < 8; ++c)
    gload_lds16((const char*)KVT + bh * 32768 + c * 4096 + tid * 16,
                (char*)KVs + c * 4096 + (wid << 10));

  const int lrow = tid >> 2, ms = tid & 3, swl = lrow & 7;

  for (int ti = 0; ti < 4; ++ti) {
    const int l0 = chunk * 256 + ti * 64;
    const char* pg = (const char*)PH + (long)(b2 * 4096 + l0 + lrow) * 4096 + h * 256 + ms * 64;
    uint4 P[4];
#pragma unroll
    for (int q = 0; q < 4; ++q) P[q] = *(const uint4*)(pg + q * 16);
    uint4 CQ[4], SQ[4];
#pragma unroll
    for (int q = 0; q < 4; ++q) {
      const unsigned w[4] = {P[q].x, P[q].y, P[q].z, P[q].w};
      unsigned cw[4], sw[4];
#pragma unroll
      for (int k = 0; k < 4; ++k) {
        float c0, s0, c1, s1;
        __sincosf(bf2f((unsigned short)(w[k] & 0xffff)), &s0, &c0);
        __sincosf(bf2f((unsigned short)(w[k] >> 16)), &s1, &c1);
        cw[k] = pack2f(c0 * RS128, c1 * RS128);
        sw[k] = pack2f(s0 * RS128, s1 * RS128);
      }
      CQ[q].x = cw[0]; CQ[q].y = cw[1]; CQ[q].z = cw[2]; CQ[q].w = cw[3];
      SQ[q].x = sw[0]; SQ[q].y = sw[1]; SQ[q].z = sw[2]; SQ[q].w = sw[3];
    }
    __syncthreads();
    {
      char* qrow = (char*)QPs + lrow * 512;
#pragma unroll
      for (int q = 0; q < 4; ++q) {
        const int c = ms * 4 + q;
        *(uint4*)(qrow + ((c ^ swl) << 4)) = CQ[q];
        *(uint4*)(qrow + ((16 + (c ^ swl)) << 4)) = SQ[q];
      }
    }
    __syncthreads();
    f32x4 acc[4] = {};
    const int lr = (wid << 4) + e;
#pragma unroll
    for (int kk = 0; kk < 8; ++kk) {
      const int ch = (kk << 2) + g;
      const bf16x8 af = *(const bf16x8*)((char*)QPs + lr * 512 + ((ch ^ (e & 7)) << 4));
#pragma unroll
      for (int j = 0; j < 4; ++j) {
        const bf16x8 bfr = *(const bf16x8*)((char*)KVs + ((j << 4) + e) * 512 + ((ch ^ (e & 7)) << 4));
        acc[j] = __builtin_amdgcn_mfma_f32_16x16x32_bf16(af, bfr, acc[j], 0, 0, 0);
      }
    }
#pragma unroll
    for (int j = 0; j < 4; ++j)
#pragma unroll
      for (int r = 0; r < 4; ++r) {
        const int lo = (wid << 4) + (g << 2) + r;
        ATTN[(long)(b * 4096 + l0 + lo) * 1024 + h * 64 + (j << 4) + e] = f2bf(acc[j][r]);
      }
  }
}

extern "C" void kernel_launch(void* const* d_in, const int* in_sizes, int n_in,
                              void* d_out, int out_size, void* d_ws, size_t ws_size,
                              hipStream_t stream) {
  (void)in_sizes; (void)n_in; (void)out_size; (void)ws_size;
  const float* x    = (const float*)d_in[0];
  const float* proj = (const float*)d_in[1];
  const float* wq = (const float*)d_in[2];
  const float* bq = (const float*)d_in[3];
  const float* wk = (const float*)d_in[4];
  const float* bk = (const float*)d_in[5];
  const float* wv = (const float*)d_in[6];
  const float* bv = (const float*)d_in[7];
  const float* wo = (const float*)d_in[8];
  const float* bo = (const float*)d_in[9];
  const float* g1  = (const float*)d_in[10];
  const float* be1 = (const float*)d_in[11];
  const float* w1 = (const float*)d_in[12];
  const float* b1 = (const float*)d_in[13];
  const float* w2 = (const float*)d_in[14];
  const float* b2 = (const float*)d_in[15];
  const float* g2  = (const float*)d_in[16];
  const float* be2 = (const float*)d_in[17];
  float* out = (float*)d_out;

  char* ws = (char*)d_ws;
  const size_t MB = 1u << 20;
  unsigned short* WQPT = (unsigned short*)(ws + 0 * MB);
  unsigned short* WKPT = (unsigned short*)(ws + 4 * MB);
  unsigned short* WVT  = (unsigned short*)(ws + 8 * MB);
  unsigned short* WOT  = (unsigned short*)(ws + 10 * MB);
  float* BQP = (float*)(ws + 12 * MB);
  float* BKP = (float*)(ws + 12 * MB + 8192);
  unsigned short* VTg  = (unsigned short*)(ws + 16 * MB);   // -> ATTN
  unsigned short* PH   = (unsigned short*)(ws + 48 * MB);
  float* PART  = (float*)(ws + 80 * MB);
  float* KVacc = (float*)(ws + 112 * MB);
  unsigned short* KVT = (unsigned short*)(ws + 116 * MB);
  unsigned short* Hb  = (unsigned short*)(ws + 0 * MB);     // FFN hidden (128MB)
  unsigned short* X2  = (unsigned short*)(ws + 128 * MB);   // -> X2B
  unsigned short* W1T = (unsigned short*)(ws + 160 * MB);
  unsigned short* W2T = (unsigned short*)(ws + 168 * MB);
  unsigned short* ATTN = VTg;
  unsigned short* X2B  = X2;

  dim3 blk(256), blk5(512);

  // weights prep
  wtrans<<<dim3(32, 32), blk, 0, stream>>>(wv, WVT, 1024, 1024);
  wtrans<<<dim3(32, 32), blk, 0, stream>>>(wo, WOT, 1024, 1024);
  wtrans<<<dim3(128, 32), blk, 0, stream>>>(w1, W1T, 1024, 4096);
  wtrans<<<dim3(32, 128), blk, 0, stream>>>(w2, W2T, 4096, 1024);
  wp_prep<<<dim3(16, 16), blk, 0, stream>>>(wq, proj, WQPT);
  wp_prep<<<dim3(16, 16), blk, 0, stream>>>(wk, proj, WKPT);
  bp_prep<<<8, blk, 0, stream>>>(bq, proj, BQP);
  bp_prep<<<8, blk, 0, stream>>>(bk, proj, BKP);

  // LN1
  ln_kernel<<<16384, blk, 0, stream>>>(x, g1, be1, X2);

  // V gemm -> VTg (transposed + swizzled)
  gemm_vt<<<1024, blk, 0, stream>>>(X2, WVT, VTg, bv, 16384, 1024, 1024);

  // kv pipeline, two L-halves
  for (int half = 0; half < 2; ++half) {
    gemm256<true, false, false><<<256, blk5, 0, stream>>>(
        X2 + (long)half * 8192 * 1024, WKPT, PH, BKP, nullptr, 8192, 2048, 1024);
    kv_kernel<<<dim3(32, 16), blk, 0, stream>>>(PH, VTg, PART, half);
    kv_reduce<<<dim3(32, 16), blk, 0, stream>>>(PART, KVacc, half);
  }
  kvt_conv<<<64, blk, 0, stream>>>(KVacc, KVT);

  // attn pipeline, two L-halves
  for (int half = 0; half < 2; ++half) {
    gemm256<true, false, false><<<256, blk5, 0, stream>>>(
        X2 + (long)half * 8192 * 1024, WQPT, PH, BQP, nullptr, 8192, 2048, 1024);
    attn_kernel<<<dim3(32, 16), blk, 0, stream>>>(PH, KVT, ATTN, half);
  }

  // Wo + residual -> out (f32)
  gemm256<false, false, true><<<256, blk5, 0, stream>>>(
      ATTN, WOT, out, bo, x, 16384, 1024, 1024);

  // LN2
  ln_kernel<<<16384, blk, 0, stream>>>(out, g2, be2, X2B);

  // FFN (unchunked)
  gemm256<true, true, false><<<1024, blk5, 0, stream>>>(
      X2B, W1T, Hb, b1, nullptr, 16384, 4096, 1024);
  gemm256<false, false, true><<<256, blk5, 0, stream>>>(
      Hb, W2T, out, b2, out, 16384, 1024, 4096);
}

// Round 9
// 849.038 us; speedup vs baseline: 1.0554x; 1.0554x over previous
//
#include <hip/hip_runtime.h>

// EstraNetBlock: pre-norm linear attention (fourier feature kernel) + FFN.
// B=4, L=4096, D=1024, H=16, Dh=64, M=128 (2M=256), D_INNER=4096.
//
// R9 = R8 with B-panel hoisted to registers at phase 0 (24 ds_read/K-tile
// instead of 48 — the serial LDS+MFMA sum model says LDS traffic was R8's
// regression). Counted-wait ledger unchanged from R8:
// stage A0A2 / B0B1+vmcnt(4) / B2B3 / A1A3+vmcnt(2). LDS 2x64KB.
//
// ws layout (MB): unchanged.

#define RS128 0.08838834764831845f

typedef short bf16x8 __attribute__((ext_vector_type(8)));
typedef float f32x4 __attribute__((ext_vector_type(4)));

__device__ __forceinline__ unsigned short f2bf(float f) {
  unsigned int u = __float_as_uint(f);
  u += 0x7fffu + ((u >> 16) & 1u);
  return (unsigned short)(u >> 16);
}
__device__ __forceinline__ float bf2f(unsigned short h) {
  return __uint_as_float(((unsigned int)h) << 16);
}
__device__ __forceinline__ unsigned int pack2f(float a, float b) {
  return (unsigned int)f2bf(a) | ((unsigned int)f2bf(b) << 16);
}
__device__ __forceinline__ void gload_lds16(const void* g, void* l) {
  __builtin_amdgcn_global_load_lds(
      (const __attribute__((address_space(1))) void*)g,
      (__attribute__((address_space(3))) void*)l, 16, 0, 0);
}
__device__ __forceinline__ void barrier_pin() {
  __builtin_amdgcn_sched_barrier(0);
  __builtin_amdgcn_s_barrier();
  __builtin_amdgcn_sched_barrier(0);
}
#define WAIT_VM(N) { asm volatile("s_waitcnt vmcnt(" #N ")" ::: "memory"); __builtin_amdgcn_sched_barrier(0); }
#define WAIT_LGKM0() { asm volatile("s_waitcnt lgkmcnt(0)" ::: "memory"); __builtin_amdgcn_sched_barrier(0); }

// -------- 256x256 8-wave 4-phase GEMM: C = A @ Bt^T + bias (+res) -----------
template <bool OBF16, bool RELU, bool RES>
__global__ __launch_bounds__(512, 2) void gemm256(
    const unsigned short* __restrict__ A, const unsigned short* __restrict__ Bt,
    void* Cv, const float* __restrict__ bias, const float* res,
    int M, int N, int K) {
  __shared__ __align__(16) char lds[131072];
  const int tid = threadIdx.x;
  const int lane = tid & 63, wid = tid >> 6;
  const int e = lane & 15, g = lane >> 4;
  const int wm = wid >> 2, wn = wid & 3;
  const int ntn = N >> 8;
  const int nwg = (int)gridDim.x, cpx = nwg >> 3;
  const int swz = ((int)blockIdx.x & 7) * cpx + ((int)blockIdx.x >> 3);
  const int bm = swz / ntn, bn = swz % ntn;
  const long row0 = (long)bm << 8, col0 = (long)bn << 8;

  // staging: chunk = 64 rows x 64 k (8KB); thread row tid>>3, 16B slot tid&7,
  // global k-byte pre-XORed by ((row&7)<<4) -> LDS linear, reads XOR back.
  const int srow = tid >> 3;
  const int skb = ((tid & 7) << 4) ^ ((srow & 7) << 4);
  const unsigned short* Abase = A + (row0 + srow) * (long)K + (skb >> 1);
  const unsigned short* Bbase = Bt + (col0 + srow) * (long)K + (skb >> 1);
  const int lof = wid << 10;  // wave's 1KB slice within an 8KB chunk

  f32x4 acc[8][4] = {};
  const int nkt = K >> 6;
  const int rx = (e & 7) << 4;

  // prologue: tile 0 in steady-state order; vmcnt(2) leaves A1,A3 in flight
  {
    char* b0 = lds;
    gload_lds16(Abase + 0 * 64 * (long)K, b0 + 0 * 8192 + lof);
    gload_lds16(Abase + 2 * 64 * (long)K, b0 + 2 * 8192 + lof);
    gload_lds16(Bbase + 0 * 64 * (long)K, b0 + 32768 + 0 * 8192 + lof);
    gload_lds16(Bbase + 1 * 64 * (long)K, b0 + 32768 + 1 * 8192 + lof);
    gload_lds16(Bbase + 2 * 64 * (long)K, b0 + 32768 + 2 * 8192 + lof);
    gload_lds16(Bbase + 3 * 64 * (long)K, b0 + 32768 + 3 * 8192 + lof);
    gload_lds16(Abase + 1 * 64 * (long)K, b0 + 1 * 8192 + lof);
    gload_lds16(Abase + 3 * 64 * (long)K, b0 + 3 * 8192 + lof);
    WAIT_VM(2);
    barrier_pin();
  }

  for (int kt = 0; kt < nkt; ++kt) {
    char* const Ac = lds + ((kt & 1) << 16);
    char* const Anx = lds + (((kt & 1) ^ 1) << 16);
    const bool pf = (kt + 1 < nkt);
    const long kn = (long)(kt + 1) << 6;

    bf16x8 bfr[4][2];  // B panel fragments, loaded once per K-tile at p0
#pragma unroll
    for (int p = 0; p < 4; ++p) {
      // --- ds_read: A quadrant p (4 reads); B panel only at p0 (8 reads) ---
      bf16x8 af[2][2];
#pragma unroll
      for (int i = 0; i < 2; ++i) {
        const int r = wm * 128 + (2 * p + i) * 16 + e;
#pragma unroll
        for (int kh = 0; kh < 2; ++kh)
          af[i][kh] = *(const bf16x8*)(Ac + (r >> 6) * 8192 + (r & 63) * 128 +
                                       ((g * 16 + kh * 64) ^ rx));
      }
      if (p == 0) {
#pragma unroll
        for (int j = 0; j < 4; ++j) {
          const int r = wn * 64 + j * 16 + e;
#pragma unroll
          for (int kh = 0; kh < 2; ++kh)
            bfr[j][kh] = *(const bf16x8*)(Ac + 32768 + (r >> 6) * 8192 +
                                          (r & 63) * 128 + ((g * 16 + kh * 64) ^ rx));
        }
      }
      // --- stage 2 chunks of tile kt+1; counted waits at p1/p3 ---
      if (pf) {
        if (p == 0) {
          gload_lds16(Abase + 0 * 64 * (long)K + kn, Anx + 0 * 8192 + lof);
          gload_lds16(Abase + 2 * 64 * (long)K + kn, Anx + 2 * 8192 + lof);
        } else if (p == 1) {
          gload_lds16(Bbase + 0 * 64 * (long)K + kn, Anx + 32768 + 0 * 8192 + lof);
          gload_lds16(Bbase + 1 * 64 * (long)K + kn, Anx + 32768 + 1 * 8192 + lof);
          WAIT_VM(4);  // validates A1,A3 of tile kt (issued >=2 phases ago)
        } else if (p == 2) {
          gload_lds16(Bbase + 2 * 64 * (long)K + kn, Anx + 32768 + 2 * 8192 + lof);
          gload_lds16(Bbase + 3 * 64 * (long)K + kn, Anx + 32768 + 3 * 8192 + lof);
        } else {
          gload_lds16(Abase + 1 * 64 * (long)K + kn, Anx + 1 * 8192 + lof);
          gload_lds16(Abase + 3 * 64 * (long)K + kn, Anx + 3 * 8192 + lof);
          WAIT_VM(2);  // validates kt+1's first 6 chunks; A1,A3 stay in flight
        }
      } else if (p == 1) {
        WAIT_VM(0);    // tail tile: everything resident
      }
      barrier_pin();
      WAIT_LGKM0();
      __builtin_amdgcn_s_setprio(1);
#pragma unroll
      for (int i = 0; i < 2; ++i)
#pragma unroll
        for (int j = 0; j < 4; ++j)
#pragma unroll
          for (int kh = 0; kh < 2; ++kh)
            acc[2 * p + i][j] = __builtin_amdgcn_mfma_f32_16x16x32_bf16(
                af[i][kh], bfr[j][kh], acc[2 * p + i][j], 0, 0, 0);
      __builtin_amdgcn_s_setprio(0);
      barrier_pin();
    }
  }

  // epilogue: C/D mapping col=lane&15, row=(lane>>4)*4+r
  const int r0 = wm * 128 + (g << 2);
  const int c0 = wn * 64 + e;
#pragma unroll
  for (int j = 0; j < 4; ++j) {
    const long gcol = col0 + c0 + (j << 4);
    const float bvv = bias[gcol];
#pragma unroll
    for (int mf = 0; mf < 8; ++mf) {
#pragma unroll
      for (int r = 0; r < 4; ++r) {
        const long grow = row0 + r0 + (mf << 4) + r;
        float v = acc[mf][j][r] + bvv;
        if (RES) v += res[grow * N + gcol];
        if (RELU) v = fmaxf(v, 0.f);
        if (OBF16) ((unsigned short*)Cv)[grow * N + gcol] = f2bf(v);
        else ((float*)Cv)[grow * N + gcol] = v;
      }
    }
  }
}

// -------- weight transpose + cast: W[K][N] f32 -> Wt[N][K] bf16 --------
__global__ __launch_bounds__(256) void wtrans(const float* __restrict__ W,
                                              unsigned short* __restrict__ Wt,
                                              int K, int N) {
  __shared__ float t[32][33];
  const int tx = threadIdx.x & 31, ty = threadIdx.x >> 5;
  const int n0 = blockIdx.x << 5, k0 = blockIdx.y << 5;
#pragma unroll
  for (int i = 0; i < 32; i += 8)
    t[ty + i][tx] = W[(long)(k0 + ty + i) * N + n0 + tx];
  __syncthreads();
#pragma unroll
  for (int i = 0; i < 32; i += 8)
    Wt[(long)(n0 + ty + i) * K + k0 + tx] = f2bf(t[tx][ty + i]);
}

// -------- WP prep: WPT[h*128+m][D] = 0.125 * sum_d w[D][h*64+d]*proj[d][m] ----
__global__ __launch_bounds__(256) void wp_prep(const float* __restrict__ w,
                                               const float* __restrict__ proj,
                                               unsigned short* __restrict__ WPT) {
  __shared__ float wkt[64 * 66];
  __shared__ float projL[64 * 128];
  const int tid = threadIdx.x;
  const int h = blockIdx.x, D0 = blockIdx.y << 6;
  {
    const int r = tid >> 2, dseg = (tid & 3) << 4;
    const float* src = w + (long)(D0 + r) * 1024 + h * 64 + dseg;
#pragma unroll
    for (int q = 0; q < 4; ++q) {
      float4 v = *(const float4*)(src + q * 4);
      wkt[(dseg + q * 4 + 0) * 66 + r] = v.x;
      wkt[(dseg + q * 4 + 1) * 66 + r] = v.y;
      wkt[(dseg + q * 4 + 2) * 66 + r] = v.z;
      wkt[(dseg + q * 4 + 3) * 66 + r] = v.w;
    }
#pragma unroll
    for (int q = 0; q < 8; ++q)
      *(float4*)(projL + tid * 32 + q * 4) = *(const float4*)(proj + tid * 32 + q * 4);
  }
  __syncthreads();
  const int r = tid & 63, mseg = (tid >> 6) << 5;
  float acc[32];
#pragma unroll
  for (int i = 0; i < 32; ++i) acc[i] = 0.f;
  for (int d = 0; d < 64; ++d) {
    const float wv = wkt[d * 66 + r];
    const float* pr = projL + d * 128 + mseg;
#pragma unroll
    for (int i = 0; i < 32; ++i) acc[i] += wv * pr[i];
  }
#pragma unroll
  for (int i = 0; i < 32; ++i)
    WPT[(long)(h * 128 + mseg + i) * 1024 + D0 + r] = f2bf(acc[i] * 0.125f);
}

// -------- BP prep --------
__global__ __launch_bounds__(256) void bp_prep(const float* __restrict__ b,
                                               const float* __restrict__ proj,
                                               float* __restrict__ BP) {
  const int hm = blockIdx.x * 256 + threadIdx.x;
  const int h = hm >> 7, m = hm & 127;
  float s = 0.f;
  for (int d = 0; d < 64; ++d) s += b[h * 64 + d] * proj[d * 128 + m];
  BP[hm] = s * 0.125f;
}

// -------- LayerNorm over 1024 cols, f32 in -> bf16 out --------
__global__ __launch_bounds__(256) void ln_kernel(const float* __restrict__ x,
                                                 const float* __restrict__ g,
                                                 const float* __restrict__ b,
                                                 unsigned short* __restrict__ out) {
  const int row = blockIdx.x, tid = threadIdx.x;
  const float* xr = x + (long)row * 1024;
  const float4 xv = *(const float4*)(xr + tid * 4);
  float s = xv.x + xv.y + xv.z + xv.w;
  float s2 = xv.x * xv.x + xv.y * xv.y + xv.z * xv.z + xv.w * xv.w;
#pragma unroll
  for (int off = 32; off > 0; off >>= 1) {
    s += __shfl_down(s, off);
    s2 += __shfl_down(s2, off);
  }
  __shared__ float ps[4], ps2[4];
  if ((tid & 63) == 0) { ps[tid >> 6] = s; ps2[tid >> 6] = s2; }
  __syncthreads();
  const float ts = ps[0] + ps[1] + ps[2] + ps[3];
  const float ts2 = ps2[0] + ps2[1] + ps2[2] + ps2[3];
  const float mu = ts * (1.f / 1024.f);
  const float rstd = rsqrtf(ts2 * (1.f / 1024.f) - mu * mu + 1e-5f);
  const float4 gv = *(const float4*)(g + tid * 4);
  const float4 bv = *(const float4*)(b + tid * 4);
  ushort4 o;
  o.x = f2bf((xv.x - mu) * rstd * gv.x + bv.x);
  o.y = f2bf((xv.y - mu) * rstd * gv.y + bv.y);
  o.z = f2bf((xv.z - mu) * rstd * gv.z + bv.z);
  o.w = f2bf((xv.w - mu) * rstd * gv.w + bv.w);
  *(ushort4*)(out + (long)row * 1024 + tid * 4) = o;
}

// -------- 128x128 GEMM with V-transpose epilogue (V path only) --------
__global__ __launch_bounds__(256, 2) void gemm_vt(
    const unsigned short* __restrict__ A, const unsigned short* __restrict__ Bt,
    void* Cv, const float* __restrict__ bias, int M, int N, int K) {
  __shared__ __align__(16) unsigned short sm[128 * 128];
  unsigned short* As = sm;
  unsigned short* Bs = sm + 128 * 64;
  const int tid = threadIdx.x;
  const int lane = tid & 63, wid = tid >> 6;
  const int ntn = N >> 7;
  const int bm = blockIdx.x / ntn, bn = blockIdx.x % ntn;
  const long row0 = (long)bm << 7, col0 = (long)bn << 7;
  const int wr = (wid >> 1) << 6, wc = (wid & 1) << 6;

  f32x4 acc[4][4] = {};
  const unsigned short* Ag = A + (row0 + (tid >> 3)) * (long)K + ((tid & 7) << 3);
  const unsigned short* Bg = Bt + (col0 + (tid >> 3)) * (long)K + ((tid & 7) << 3);
  char* AsB = (char*)As + (wid << 10);
  char* BsB = (char*)Bs + (wid << 10);

  for (int kt = 0; kt < K; kt += 64) {
#pragma unroll
    for (int c = 0; c < 4; ++c) {
      gload_lds16(Ag + kt + (long)c * 32 * K, AsB + (c << 12));
      gload_lds16(Bg + kt + (long)c * 32 * K, BsB + (c << 12));
    }
    __syncthreads();
#pragma unroll
    for (int kk = 0; kk < 2; ++kk) {
      const int krow = (kk << 5) + ((lane >> 4) << 3);
      bf16x8 af[4], bfr[4];
#pragma unroll
      for (int i = 0; i < 4; ++i)
        af[i] = *(const bf16x8*)(As + (wr + (i << 4) + (lane & 15)) * 64 + krow);
#pragma unroll
      for (int j = 0; j < 4; ++j)
        bfr[j] = *(const bf16x8*)(Bs + (wc + (j << 4) + (lane & 15)) * 64 + krow);
#pragma unroll
      for (int i = 0; i < 4; ++i)
#pragma unroll
        for (int j = 0; j < 4; ++j)
          acc[i][j] = __builtin_amdgcn_mfma_f32_16x16x32_bf16(af[i], bfr[j],
                                                              acc[i][j], 0, 0, 0);
    }
    __syncthreads();
  }

  const int r0 = wr + ((lane >> 4) << 2);
  const int c0l = wc + (lane & 15);
#pragma unroll
  for (int j = 0; j < 4; ++j) {
    const int cc = c0l + (j << 4);
    const float bvv = bias[col0 + cc];
#pragma unroll
    for (int i = 0; i < 4; ++i)
#pragma unroll
      for (int r = 0; r < 4; ++r) {
        const int ll = r0 + (i << 4) + r;
        sm[ll * 128 + (cc ^ ((ll & 7) << 1))] = f2bf(acc[i][j][r] + bvv);
      }
  }
  __syncthreads();
  const int c = tid & 127, lh = tid >> 7;
  const long gc = col0 + c;
  const int b = (int)(row0 >> 12);
  const int hh = (int)(gc >> 6), dd = (int)(gc & 63);
  const int lb = (int)(row0 & 4095) + lh * 64;
  char* basep = (char*)Cv + (((long)(b * 16 + hh) * 64 + dd) * 4096 + lb) * 2;
#pragma unroll
  for (int cc8 = 0; cc8 < 8; ++cc8) {
    unsigned short v[8];
#pragma unroll
    for (int k = 0; k < 8; ++k)
      v[k] = sm[(lh * 64 + cc8 * 8 + k) * 128 + (c ^ (k << 1))];
    uint4 o;
    o.x = (unsigned)v[0] | ((unsigned)v[1] << 16);
    o.y = (unsigned)v[2] | ((unsigned)v[3] << 16);
    o.z = (unsigned)v[4] | ((unsigned)v[5] << 16);
    o.w = (unsigned)v[6] | ((unsigned)v[7] << 16);
    *(uint4*)(basep + ((cc8 ^ (dd & 7)) << 4)) = o;
  }
}

// -------- kv kernel: PART[chunk][bhh][d][m] = sum_l vT[d][l]*kp[l][m] --------
__global__ __launch_bounds__(256, 2) void kv_kernel(
    const unsigned short* __restrict__ PH, const unsigned short* __restrict__ VTg,
    float* __restrict__ PART, int half) {
  __shared__ __align__(16) unsigned short Ps[64 * 128];
  __shared__ __align__(16) unsigned short Vs[64 * 64];
  __shared__ __align__(16) unsigned short KPT[256 * 64];
  const int tid = threadIdx.x;
  const int lane = tid & 63, wid = tid >> 6;
  const int bhh = blockIdx.x, chunk = blockIdx.y;
  const int b2 = bhh >> 4, h = bhh & 15;
  const int bh = (half * 2 + b2) * 16 + h;

  f32x4 acc[4][4] = {};
  const int e = lane & 15, g = lane >> 4;
  const int m = tid & 127, isin = tid >> 7;
  const int m2 = (isin << 7) + m, swm = m & 7;

  for (int ti = 0; ti < 4; ++ti) {
    const int l0 = chunk * 256 + ti * 64;
    __syncthreads();
#pragma unroll
    for (int c = 0; c < 4; ++c) {
      const int r = l0 + c * 16 + (tid >> 4);
      gload_lds16((const char*)PH + (long)(b2 * 4096 + r) * 4096 + h * 256 + (tid & 15) * 16,
                  (char*)Ps + c * 4096 + (wid << 10));
    }
#pragma unroll
    for (int c = 0; c < 2; ++c) {
      const int d = c * 32 + (tid >> 3);
      gload_lds16((const char*)VTg + ((long)(bh * 64 + d) * 4096 + l0) * 2 + (tid & 7) * 16,
                  (char*)Vs + c * 4096 + (wid << 10));
    }
    __syncthreads();
    {
      char* krow = (char*)KPT + m2 * 128;
#pragma unroll
      for (int g8 = 0; g8 < 8; ++g8) {
        unsigned pk[4];
#pragma unroll
        for (int k2 = 0; k2 < 4; ++k2) {
          const float p0 = bf2f(Ps[(g8 * 8 + k2 * 2) * 128 + m]);
          const float p1 = bf2f(Ps[(g8 * 8 + k2 * 2 + 1) * 128 + m]);
          const float v0 = (isin ? __sinf(p0) : __cosf(p0)) * RS128;
          const float v1 = (isin ? __sinf(p1) : __cosf(p1)) * RS128;
          pk[k2] = pack2f(v0, v1);
        }
        uint4 o; o.x = pk[0]; o.y = pk[1]; o.z = pk[2]; o.w = pk[3];
        *(uint4*)(krow + ((g8 ^ swm) << 4)) = o;
      }
    }
    __syncthreads();
#pragma unroll
    for (int kk = 0; kk < 2; ++kk) {
      const int ch = (kk << 2) + g;
      bf16x8 af[4], bfr[4];
#pragma unroll
      for (int i = 0; i < 4; ++i) {
        const int dr = (i << 4) + e;
        af[i] = *(const bf16x8*)((char*)Vs + dr * 128 + ((ch ^ (e & 7)) << 4));
      }
#pragma unroll
      for (int j = 0; j < 4; ++j) {
        const int mr = (wid << 6) + (j << 4) + e;
        bfr[j] = *(const bf16x8*)((char*)KPT + mr * 128 + ((ch ^ (e & 7)) << 4));
      }
#pragma unroll
      for (int i = 0; i < 4; ++i)
#pragma unroll
        for (int j = 0; j < 4; ++j)
          acc[i][j] = __builtin_amdgcn_mfma_f32_16x16x32_bf16(af[i], bfr[j],
                                                              acc[i][j], 0, 0, 0);
    }
  }
  float* slice = PART + ((long)chunk * 32 + bhh) * 16384;
#pragma unroll
  for (int i = 0; i < 4; ++i)
#pragma unroll
    for (int j = 0; j < 4; ++j)
#pragma unroll
      for (int r = 0; r < 4; ++r) {
        const int d = (i << 4) + (g << 2) + r;
        const int mc = (wid << 6) + (j << 4) + e;
        slice[d * 256 + mc] = acc[i][j][r];
      }
}

__global__ __launch_bounds__(256) void kv_reduce(const float* __restrict__ PART,
                                                 float* __restrict__ KVacc, int half) {
  const int bhh = blockIdx.x, seg = blockIdx.y;
  const long off = (long)bhh * 16384 + seg * 1024 + threadIdx.x * 4;
  float4 s = make_float4(0.f, 0.f, 0.f, 0.f);
#pragma unroll
  for (int c = 0; c < 16; ++c) {
    const float4 v = *(const float4*)(PART + ((long)c * 32) * 16384 + off);
    s.x += v.x; s.y += v.y; s.z += v.z; s.w += v.w;
  }
  *(float4*)(KVacc + (long)(half * 32) * 16384 + off) = s;
}

__global__ __launch_bounds__(256) void kvt_conv(const float* __restrict__ KVacc,
                                                unsigned short* __restrict__ KVT) {
  const int bh = blockIdx.x, tid = threadIdx.x;
  const int d = tid >> 2, mq = tid & 3;
  const float* src = KVacc + (long)bh * 16384 + d * 256 + mq * 64;
  char* dst = (char*)KVT + bh * 32768 + d * 512;
#pragma unroll
  for (int cc = 0; cc < 8; ++cc) {
    const float4 a = *(const float4*)(src + cc * 8);
    const float4 b = *(const float4*)(src + cc * 8 + 4);
    uint4 o;
    o.x = pack2f(a.x, a.y); o.y = pack2f(a.z, a.w);
    o.z = pack2f(b.x, b.y); o.w = pack2f(b.z, b.w);
    const int chunk = mq * 8 + cc;
    *(uint4*)(dst + ((chunk ^ (d & 7)) << 4)) = o;
  }
}

// -------- attn kernel: ATTN[l][h*64+d] = sum_m qp[l][m]*kvT[d][m] --------
__global__ __launch_bounds__(256, 2) void attn_kernel(
    const unsigned short* __restrict__ PH, const unsigned short* __restrict__ KVT,
    unsigned short* __restrict__ ATTN, int half) {
  __shared__ __align__(16) unsigned short QPs[64 * 256];
  __shared__ __align__(16) unsigned short KVs[64 * 256];
  const int tid = threadIdx.x;
  const int lane = tid & 63, wid = tid >> 6;
  const int bhh = blockIdx.x, chunk = blockIdx.y;
  const int b2 = bhh >> 4, h = bhh & 15;
  const int b = half * 2 + b2, bh = b * 16 + h;
  const int e = lane & 15, g = lane >> 4;

#pragma unroll
  for (int c = 0; c < 8; ++c)
    gload_lds16((const char*)KVT + bh * 32768 + c * 4096 + tid * 16,
                (char*)KVs + c * 4096 + (wid << 10));

  const int lrow = tid >> 2, ms = tid & 3, swl = lrow & 7;

  for (int ti = 0; ti < 4; ++ti) {
    const int l0 = chunk * 256 + ti * 64;
    const char* pg = (const char*)PH + (long)(b2 * 4096 + l0 + lrow) * 4096 + h * 256 + ms * 64;
    uint4 P[4];
#pragma unroll
    for (int q = 0; q < 4; ++q) P[q] = *(const uint4*)(pg + q * 16);
    uint4 CQ[4], SQ[4];
#pragma unroll
    for (int q = 0; q < 4; ++q) {
      const unsigned w[4] = {P[q].x, P[q].y, P[q].z, P[q].w};
      unsigned cw[4], sw[4];
#pragma unroll
      for (int k = 0; k < 4; ++k) {
        float c0, s0, c1, s1;
        __sincosf(bf2f((unsigned short)(w[k] & 0xffff)), &s0, &c0);
        __sincosf(bf2f((unsigned short)(w[k] >> 16)), &s1, &c1);
        cw[k] = pack2f(c0 * RS128, c1 * RS128);
        sw[k] = pack2f(s0 * RS128, s1 * RS128);
      }
      CQ[q].x = cw[0]; CQ[q].y = cw[1]; CQ[q].z = cw[2]; CQ[q].w = cw[3];
      SQ[q].x = sw[0]; SQ[q].y = sw[1]; SQ[q].z = sw[2]; SQ[q].w = sw[3];
    }
    __syncthreads();
    {
      char* qrow = (char*)QPs + lrow * 512;
#pragma unroll
      for (int q = 0; q < 4; ++q) {
        const int c = ms * 4 + q;
        *(uint4*)(qrow + ((c ^ swl) << 4)) = CQ[q];
        *(uint4*)(qrow + ((16 + (c ^ swl)) << 4)) = SQ[q];
      }
    }
    __syncthreads();
    f32x4 acc[4] = {};
    const int lr = (wid << 4) + e;
#pragma unroll
    for (int kk = 0; kk < 8; ++kk) {
      const int ch = (kk << 2) + g;
      const bf16x8 af = *(const bf16x8*)((char*)QPs + lr * 512 + ((ch ^ (e & 7)) << 4));
#pragma unroll
      for (int j = 0; j < 4; ++j) {
        const bf16x8 bfr = *(const bf16x8*)((char*)KVs + ((j << 4) + e) * 512 + ((ch ^ (e & 7)) << 4));
        acc[j] = __builtin_amdgcn_mfma_f32_16x16x32_bf16(af, bfr, acc[j], 0, 0, 0);
      }
    }
#pragma unroll
    for (int j = 0; j < 4; ++j)
#pragma unroll
      for (int r = 0; r < 4; ++r) {
        const int lo = (wid << 4) + (g << 2) + r;
        ATTN[(long)(b * 4096 + l0 + lo) * 1024 + h * 64 + (j << 4) + e] = f2bf(acc[j][r]);
      }
  }
}

extern "C" void kernel_launch(void* const* d_in, const int* in_sizes, int n_in,
                              void* d_out, int out_size, void* d_ws, size_t ws_size,
                              hipStream_t stream) {
  (void)in_sizes; (void)n_in; (void)out_size; (void)ws_size;
  const float* x    = (const float*)d_in[0];
  const float* proj = (const float*)d_in[1];
  const float* wq = (const float*)d_in[2];
  const float* bq = (const float*)d_in[3];
  const float* wk = (const float*)d_in[4];
  const float* bk = (const float*)d_in[5];
  const float* wv = (const float*)d_in[6];
  const float* bv = (const float*)d_in[7];
  const float* wo = (const float*)d_in[8];
  const float* bo = (const float*)d_in[9];
  const float* g1  = (const float*)d_in[10];
  const float* be1 = (const float*)d_in[11];
  const float* w1 = (const float*)d_in[12];
  const float* b1 = (const float*)d_in[13];
  const float* w2 = (const float*)d_in[14];
  const float* b2 = (const float*)d_in[15];
  const float* g2  = (const float*)d_in[16];
  const float* be2 = (const float*)d_in[17];
  float* out = (float*)d_out;

  char* ws = (char*)d_ws;
  const size_t MB = 1u << 20;
  unsigned short* WQPT = (unsigned short*)(ws + 0 * MB);
  unsigned short* WKPT = (unsigned short*)(ws + 4 * MB);
  unsigned short* WVT  = (unsigned short*)(ws + 8 * MB);
  unsigned short* WOT  = (unsigned short*)(ws + 10 * MB);
  float* BQP = (float*)(ws + 12 * MB);
  float* BKP = (float*)(ws + 12 * MB + 8192);
  unsigned short* VTg  = (unsigned short*)(ws + 16 * MB);   // -> ATTN
  unsigned short* PH   = (unsigned short*)(ws + 48 * MB);
  float* PART  = (float*)(ws + 80 * MB);
  float* KVacc = (float*)(ws + 112 * MB);
  unsigned short* KVT = (unsigned short*)(ws + 116 * MB);
  unsigned short* Hb  = (unsigned short*)(ws + 0 * MB);     // FFN hidden (128MB)
  unsigned short* X2  = (unsigned short*)(ws + 128 * MB);   // -> X2B
  unsigned short* W1T = (unsigned short*)(ws + 160 * MB);
  unsigned short* W2T = (unsigned short*)(ws + 168 * MB);
  unsigned short* ATTN = VTg;
  unsigned short* X2B  = X2;

  dim3 blk(256), blk5(512);

  // weights prep
  wtrans<<<dim3(32, 32), blk, 0, stream>>>(wv, WVT, 1024, 1024);
  wtrans<<<dim3(32, 32), blk, 0, stream>>>(wo, WOT, 1024, 1024);
  wtrans<<<dim3(128, 32), blk, 0, stream>>>(w1, W1T, 1024, 4096);
  wtrans<<<dim3(32, 128), blk, 0, stream>>>(w2, W2T, 4096, 1024);
  wp_prep<<<dim3(16, 16), blk, 0, stream>>>(wq, proj, WQPT);
  wp_prep<<<dim3(16, 16), blk, 0, stream>>>(wk, proj, WKPT);
  bp_prep<<<8, blk, 0, stream>>>(bq, proj, BQP);
  bp_prep<<<8, blk, 0, stream>>>(bk, proj, BKP);

  // LN1
  ln_kernel<<<16384, blk, 0, stream>>>(x, g1, be1, X2);

  // V gemm -> VTg (transposed + swizzled)
  gemm_vt<<<1024, blk, 0, stream>>>(X2, WVT, VTg, bv, 16384, 1024, 1024);

  // kv pipeline, two L-halves
  for (int half = 0; half < 2; ++half) {
    gemm256<true, false, false><<<256, blk5, 0, stream>>>(
        X2 + (long)half * 8192 * 1024, WKPT, PH, BKP, nullptr, 8192, 2048, 1024);
    kv_kernel<<<dim3(32, 16), blk, 0, stream>>>(PH, VTg, PART, half);
    kv_reduce<<<dim3(32, 16), blk, 0, stream>>>(PART, KVacc, half);
  }
  kvt_conv<<<64, blk, 0, stream>>>(KVacc, KVT);

  // attn pipeline, two L-halves
  for (int half = 0; half < 2; ++half) {
    gemm256<true, false, false><<<256, blk5, 0, stream>>>(
        X2 + (long)half * 8192 * 1024, WQPT, PH, BQP, nullptr, 8192, 2048, 1024);
    attn_kernel<<<dim3(32, 16), blk, 0, stream>>>(PH, KVT, ATTN, half);
  }

  // Wo + residual -> out (f32)
  gemm256<false, false, true><<<256, blk5, 0, stream>>>(
      ATTN, WOT, out, bo, x, 16384, 1024, 1024);

  // LN2
  ln_kernel<<<16384, blk, 0, stream>>>(out, g2, be2, X2B);

  // FFN (unchunked)
  gemm256<true, true, false><<<1024, blk5, 0, stream>>>(
      X2B, W1T, Hb, b1, nullptr, 16384, 4096, 1024);
  gemm256<false, false, true><<<256, blk5, 0, stream>>>(
      Hb, W2T, out, b2, out, 16384, 1024, 4096);
}

// Round 10
// 760.700 us; speedup vs baseline: 1.1779x; 1.1161x over previous
//
#include <hip/hip_runtime.h>

// EstraNetBlock: pre-norm linear attention (fourier feature kernel) + FFN.
// B=4, L=4096, D=1024, H=16, Dh=64, M=128 (2M=256), D_INNER=4096.
//
// R10: FLOP cut — unfold fourier projection from Q/K weights. Q/K gemms are
// N=1024 (34.4 GF each, was 68.7 folded); a small MFMA p_gemm computes
// PH[l][h*128+m] = 0.125*(q@proj) per head (4.3 GF). kv/attn kernels
// unchanged (same PH layout). gemm256 reverted to R6's 3-ring 256x128 (best
// measured). ws (MB): 0 WQT,2 WKT,4 WVT,6 WOT,8 projTs(16KB),10 KVacc,
// 14 KVT,16 VTg(->ATTN),48 QKb_h,64 PH,96 PART,128 X2(->X2B),160 W1T,168 W2T;
// FFN H = arena 0..128.

#define RS128 0.08838834764831845f

typedef short bf16x8 __attribute__((ext_vector_type(8)));
typedef float f32x4 __attribute__((ext_vector_type(4)));

__device__ __forceinline__ unsigned short f2bf(float f) {
  unsigned int u = __float_as_uint(f);
  u += 0x7fffu + ((u >> 16) & 1u);
  return (unsigned short)(u >> 16);
}
__device__ __forceinline__ float bf2f(unsigned short h) {
  return __uint_as_float(((unsigned int)h) << 16);
}
__device__ __forceinline__ unsigned int pack2f(float a, float b) {
  return (unsigned int)f2bf(a) | ((unsigned int)f2bf(b) << 16);
}
__device__ __forceinline__ void gload_lds16(const void* g, void* l) {
  __builtin_amdgcn_global_load_lds(
      (const __attribute__((address_space(1))) void*)g,
      (__attribute__((address_space(3))) void*)l, 16, 0, 0);
}
__device__ __forceinline__ void barrier_pin() {
  __builtin_amdgcn_sched_barrier(0);
  __builtin_amdgcn_s_barrier();
  __builtin_amdgcn_sched_barrier(0);
}
#define WAIT_VM(N) { asm volatile("s_waitcnt vmcnt(" #N ")" ::: "memory"); __builtin_amdgcn_sched_barrier(0); }
#define WAIT_LGKM0() { asm volatile("s_waitcnt lgkmcnt(0)" ::: "memory"); __builtin_amdgcn_sched_barrier(0); }

// -------- 256x128-tile 8-wave GEMM (R6 structure, best measured) ------------
// 512 thr = 8 waves (4M x 2N), per-wave 64x64 out. LDS: 3 ring bufs x 48KB.
template <bool OBF16, bool RELU, bool RES>
__global__ __launch_bounds__(512, 2) void gemm256(
    const unsigned short* __restrict__ A, const unsigned short* __restrict__ Bt,
    void* Cv, const float* __restrict__ bias, const float* res,
    int M, int N, int K) {
  __shared__ __align__(16) char lds[147456];
  const int tid = threadIdx.x;
  const int lane = tid & 63, wid = tid >> 6;
  const int e = lane & 15, g = lane >> 4;
  const int wm = wid >> 1, wn = wid & 1;
  const int ntn = N >> 7;
  const int nwg = (int)gridDim.x, cpx = nwg >> 3;
  const int swz = ((int)blockIdx.x & 7) * cpx + ((int)blockIdx.x >> 3);
  const int bm = swz / ntn, bn = swz % ntn;
  const long row0 = (long)bm << 8, col0 = (long)bn << 7;

  const int srow = tid >> 3;
  const int skb = ((tid & 7) << 4) ^ ((srow & 7) << 4);
  const unsigned short* Abase = A + (row0 + srow) * (long)K + (skb >> 1);
  const unsigned short* Bbase = Bt + (col0 + srow) * (long)K + (skb >> 1);
  const int lof = wid << 10;

  f32x4 acc[4][4] = {};
  const int nkt = K >> 6;
  const int rx = (e & 7) << 4;

  char* bufA = lds;
  char* bufB = lds + 49152;
  char* bufC = lds + 98304;

#pragma unroll
  for (int c = 0; c < 4; ++c)
    gload_lds16(Abase + (long)c * 64 * K, bufA + lof + c * 8192);
#pragma unroll
  for (int c = 0; c < 2; ++c)
    gload_lds16(Bbase + (long)c * 64 * K, bufA + 32768 + lof + c * 8192);
#pragma unroll
  for (int c = 0; c < 4; ++c)
    gload_lds16(Abase + (long)c * 64 * K + 64, bufB + lof + c * 8192);
#pragma unroll
  for (int c = 0; c < 2; ++c)
    gload_lds16(Bbase + (long)c * 64 * K + 64, bufB + 32768 + lof + c * 8192);
  WAIT_VM(6);
  barrier_pin();

  for (int kt = 0; kt < nkt; ++kt) {
    char* Ac = bufA;
    char* Bc = bufA + 32768;
    const bool pf2 = (kt + 2 < nkt);
    const long kn2 = (long)(kt + 2) << 6;

    // phase 0
    bf16x8 bfr[4][2];
#pragma unroll
    for (int j = 0; j < 4; ++j) {
      const int r = wn * 64 + j * 16 + e;
#pragma unroll
      for (int kh = 0; kh < 2; ++kh)
        bfr[j][kh] = *(const bf16x8*)(Bc + r * 128 + ((g * 16 + kh * 64) ^ rx));
    }
    bf16x8 af0[2][2];
#pragma unroll
    for (int i = 0; i < 2; ++i) {
      const int r = wm * 64 + i * 16 + e;
#pragma unroll
      for (int kh = 0; kh < 2; ++kh)
        af0[i][kh] = *(const bf16x8*)(Ac + r * 128 + ((g * 16 + kh * 64) ^ rx));
    }
    if (pf2) {
#pragma unroll
      for (int c = 0; c < 3; ++c)
        gload_lds16(Abase + (long)c * 64 * K + kn2, bufC + lof + c * 8192);
    }
    barrier_pin();
    WAIT_LGKM0();
    __builtin_amdgcn_s_setprio(1);
#pragma unroll
    for (int i = 0; i < 2; ++i)
#pragma unroll
      for (int j = 0; j < 4; ++j)
#pragma unroll
        for (int kh = 0; kh < 2; ++kh)
          acc[i][j] = __builtin_amdgcn_mfma_f32_16x16x32_bf16(
              af0[i][kh], bfr[j][kh], acc[i][j], 0, 0, 0);
    __builtin_amdgcn_s_setprio(0);
    barrier_pin();

    // phase 1
    bf16x8 af1[2][2];
#pragma unroll
    for (int i = 0; i < 2; ++i) {
      const int r = wm * 64 + (2 + i) * 16 + e;
#pragma unroll
      for (int kh = 0; kh < 2; ++kh)
        af1[i][kh] = *(const bf16x8*)(Ac + r * 128 + ((g * 16 + kh * 64) ^ rx));
    }
    if (pf2) {
      gload_lds16(Abase + (long)3 * 64 * K + kn2, bufC + lof + 3 * 8192);
      gload_lds16(Bbase + kn2, bufC + 32768 + lof);
      gload_lds16(Bbase + (long)64 * K + kn2, bufC + 32768 + lof + 8192);
      WAIT_VM(6);
    } else if (kt + 1 < nkt) {
      WAIT_VM(0);
    }
    barrier_pin();
    WAIT_LGKM0();
    __builtin_amdgcn_s_setprio(1);
#pragma unroll
    for (int i = 0; i < 2; ++i)
#pragma unroll
      for (int j = 0; j < 4; ++j)
#pragma unroll
        for (int kh = 0; kh < 2; ++kh)
          acc[2 + i][j] = __builtin_amdgcn_mfma_f32_16x16x32_bf16(
              af1[i][kh], bfr[j][kh], acc[2 + i][j], 0, 0, 0);
    __builtin_amdgcn_s_setprio(0);
    barrier_pin();

    char* t = bufA; bufA = bufB; bufB = bufC; bufC = t;
  }

  const int r0 = wm * 64 + (g << 2);
  const int c0 = wn * 64 + e;
#pragma unroll
  for (int j = 0; j < 4; ++j) {
    const long gcol = col0 + c0 + (j << 4);
    const float bvv = bias[gcol];
#pragma unroll
    for (int mf = 0; mf < 4; ++mf) {
#pragma unroll
      for (int r = 0; r < 4; ++r) {
        const long grow = row0 + r0 + (mf << 4) + r;
        float v = acc[mf][j][r] + bvv;
        if (RES) v += res[grow * N + gcol];
        if (RELU) v = fmaxf(v, 0.f);
        if (OBF16) ((unsigned short*)Cv)[grow * N + gcol] = f2bf(v);
        else ((float*)Cv)[grow * N + gcol] = v;
      }
    }
  }
}

// -------- weight transpose + cast: W[K][N] f32 -> Wt[N][K] bf16 --------
__global__ __launch_bounds__(256) void wtrans(const float* __restrict__ W,
                                              unsigned short* __restrict__ Wt,
                                              int K, int N) {
  __shared__ float t[32][33];
  const int tx = threadIdx.x & 31, ty = threadIdx.x >> 5;
  const int n0 = blockIdx.x << 5, k0 = blockIdx.y << 5;
#pragma unroll
  for (int i = 0; i < 32; i += 8)
    t[ty + i][tx] = W[(long)(k0 + ty + i) * N + n0 + tx];
  __syncthreads();
#pragma unroll
  for (int i = 0; i < 32; i += 8)
    Wt[(long)(n0 + ty + i) * K + k0 + tx] = f2bf(t[tx][ty + i]);
}

// -------- projT prep: projTs[m][d] = bf16(proj[d][m]*0.125), pre-swizzled ----
__global__ __launch_bounds__(256) void projt_prep(const float* __restrict__ proj,
                                                  unsigned short* __restrict__ projTs) {
  const int t = threadIdx.x;
  const int m = t >> 1, sh = t & 1;
#pragma unroll
  for (int s4 = 0; s4 < 4; ++s4) {
    const int s = sh * 4 + s4;
    unsigned short v[8];
#pragma unroll
    for (int k = 0; k < 8; ++k)
      v[k] = f2bf(proj[(s * 8 + k) * 128 + m] * 0.125f);
    uint4 o;
    o.x = (unsigned)v[0] | ((unsigned)v[1] << 16);
    o.y = (unsigned)v[2] | ((unsigned)v[3] << 16);
    o.z = (unsigned)v[4] | ((unsigned)v[5] << 16);
    o.w = (unsigned)v[6] | ((unsigned)v[7] << 16);
    *(uint4*)((char*)projTs + m * 128 + ((s ^ (m & 7)) << 4)) = o;
  }
}

// -------- p_gemm: PH[l][h*128+m] = sum_d Qh[l][h*64+d]*projTs[m][d] ----------
// grid (64 lchunk, 16 h); 256 thr (4 waves); per block 128 l x 128 m, K=64.
__global__ __launch_bounds__(256, 2) void p_gemm(
    const unsigned short* __restrict__ Qh,      // [8192][1024] bf16 (w/ bias)
    const unsigned short* __restrict__ projTs,  // [128][64] bf16 swz, x0.125
    unsigned short* __restrict__ PH) {          // [8192][2048]
  __shared__ __align__(16) unsigned short Qt[128 * 64];
  __shared__ __align__(16) unsigned short Pj[128 * 64];
  const int tid = threadIdx.x;
  const int lane = tid & 63, wid = tid >> 6;
  const int e = lane & 15, g = lane >> 4;
  const int l0 = (int)blockIdx.x << 7, h = (int)blockIdx.y;
  {
    const int rowg = tid >> 3, sb = (tid & 7) << 4;
#pragma unroll
    for (int c = 0; c < 4; ++c) {
      const int r = c * 32 + rowg;
      gload_lds16((const char*)Qh + (long)(l0 + r) * 2048 + h * 128 + (sb ^ ((r & 7) << 4)),
                  (char*)Qt + c * 4096 + (wid << 10));
      gload_lds16((const char*)projTs + c * 4096 + tid * 16 - (wid << 10) * 0,
                  (char*)Pj + c * 4096 + (wid << 10));
    }
  }
  __syncthreads();
  const int rx = (e & 7) << 4;
  f32x4 acc[2][8] = {};
  bf16x8 af[2][2], bf[8][2];
#pragma unroll
  for (int i = 0; i < 2; ++i) {
    const int r = (wid << 5) + (i << 4) + e;
#pragma unroll
    for (int kh = 0; kh < 2; ++kh)
      af[i][kh] = *(const bf16x8*)((char*)Qt + r * 128 + ((g * 16 + kh * 64) ^ rx));
  }
#pragma unroll
  for (int j = 0; j < 8; ++j) {
    const int m = (j << 4) + e;
#pragma unroll
    for (int kh = 0; kh < 2; ++kh)
      bf[j][kh] = *(const bf16x8*)((char*)Pj + m * 128 + ((g * 16 + kh * 64) ^ rx));
  }
#pragma unroll
  for (int i = 0; i < 2; ++i)
#pragma unroll
    for (int j = 0; j < 8; ++j)
#pragma unroll
      for (int kh = 0; kh < 2; ++kh)
        acc[i][j] = __builtin_amdgcn_mfma_f32_16x16x32_bf16(af[i][kh], bf[j][kh],
                                                            acc[i][j], 0, 0, 0);
  unsigned short* dst = PH + (long)l0 * 2048 + h * 128;
#pragma unroll
  for (int i = 0; i < 2; ++i)
#pragma unroll
    for (int j = 0; j < 8; ++j)
#pragma unroll
      for (int r = 0; r < 4; ++r) {
        const int l = (wid << 5) + (i << 4) + (g << 2) + r;
        dst[(long)l * 2048 + (j << 4) + e] = f2bf(acc[i][j][r]);
      }
}

// -------- LayerNorm over 1024 cols, f32 in -> bf16 out --------
__global__ __launch_bounds__(256) void ln_kernel(const float* __restrict__ x,
                                                 const float* __restrict__ g,
                                                 const float* __restrict__ b,
                                                 unsigned short* __restrict__ out) {
  const int row = blockIdx.x, tid = threadIdx.x;
  const float* xr = x + (long)row * 1024;
  const float4 xv = *(const float4*)(xr + tid * 4);
  float s = xv.x + xv.y + xv.z + xv.w;
  float s2 = xv.x * xv.x + xv.y * xv.y + xv.z * xv.z + xv.w * xv.w;
#pragma unroll
  for (int off = 32; off > 0; off >>= 1) {
    s += __shfl_down(s, off);
    s2 += __shfl_down(s2, off);
  }
  __shared__ float ps[4], ps2[4];
  if ((tid & 63) == 0) { ps[tid >> 6] = s; ps2[tid >> 6] = s2; }
  __syncthreads();
  const float ts = ps[0] + ps[1] + ps[2] + ps[3];
  const float ts2 = ps2[0] + ps2[1] + ps2[2] + ps2[3];
  const float mu = ts * (1.f / 1024.f);
  const float rstd = rsqrtf(ts2 * (1.f / 1024.f) - mu * mu + 1e-5f);
  const float4 gv = *(const float4*)(g + tid * 4);
  const float4 bv = *(const float4*)(b + tid * 4);
  ushort4 o;
  o.x = f2bf((xv.x - mu) * rstd * gv.x + bv.x);
  o.y = f2bf((xv.y - mu) * rstd * gv.y + bv.y);
  o.z = f2bf((xv.z - mu) * rstd * gv.z + bv.z);
  o.w = f2bf((xv.w - mu) * rstd * gv.w + bv.w);
  *(ushort4*)(out + (long)row * 1024 + tid * 4) = o;
}

// -------- 128x128 GEMM with V-transpose epilogue (V path only) --------
__global__ __launch_bounds__(256, 2) void gemm_vt(
    const unsigned short* __restrict__ A, const unsigned short* __restrict__ Bt,
    void* Cv, const float* __restrict__ bias, int M, int N, int K) {
  __shared__ __align__(16) unsigned short sm[128 * 128];
  unsigned short* As = sm;
  unsigned short* Bs = sm + 128 * 64;
  const int tid = threadIdx.x;
  const int lane = tid & 63, wid = tid >> 6;
  const int ntn = N >> 7;
  const int bm = blockIdx.x / ntn, bn = blockIdx.x % ntn;
  const long row0 = (long)bm << 7, col0 = (long)bn << 7;
  const int wr = (wid >> 1) << 6, wc = (wid & 1) << 6;

  f32x4 acc[4][4] = {};
  const unsigned short* Ag = A + (row0 + (tid >> 3)) * (long)K + ((tid & 7) << 3);
  const unsigned short* Bg = Bt + (col0 + (tid >> 3)) * (long)K + ((tid & 7) << 3);
  char* AsB = (char*)As + (wid << 10);
  char* BsB = (char*)Bs + (wid << 10);

  for (int kt = 0; kt < K; kt += 64) {
#pragma unroll
    for (int c = 0; c < 4; ++c) {
      gload_lds16(Ag + kt + (long)c * 32 * K, AsB + (c << 12));
      gload_lds16(Bg + kt + (long)c * 32 * K, BsB + (c << 12));
    }
    __syncthreads();
#pragma unroll
    for (int kk = 0; kk < 2; ++kk) {
      const int krow = (kk << 5) + ((lane >> 4) << 3);
      bf16x8 af[4], bfr[4];
#pragma unroll
      for (int i = 0; i < 4; ++i)
        af[i] = *(const bf16x8*)(As + (wr + (i << 4) + (lane & 15)) * 64 + krow);
#pragma unroll
      for (int j = 0; j < 4; ++j)
        bfr[j] = *(const bf16x8*)(Bs + (wc + (j << 4) + (lane & 15)) * 64 + krow);
#pragma unroll
      for (int i = 0; i < 4; ++i)
#pragma unroll
        for (int j = 0; j < 4; ++j)
          acc[i][j] = __builtin_amdgcn_mfma_f32_16x16x32_bf16(af[i], bfr[j],
                                                              acc[i][j], 0, 0, 0);
    }
    __syncthreads();
  }

  const int r0 = wr + ((lane >> 4) << 2);
  const int c0l = wc + (lane & 15);
#pragma unroll
  for (int j = 0; j < 4; ++j) {
    const int cc = c0l + (j << 4);
    const float bvv = bias[col0 + cc];
#pragma unroll
    for (int i = 0; i < 4; ++i)
#pragma unroll
      for (int r = 0; r < 4; ++r) {
        const int ll = r0 + (i << 4) + r;
        sm[ll * 128 + (cc ^ ((ll & 7) << 1))] = f2bf(acc[i][j][r] + bvv);
      }
  }
  __syncthreads();
  const int c = tid & 127, lh = tid >> 7;
  const long gc = col0 + c;
  const int b = (int)(row0 >> 12);
  const int hh = (int)(gc >> 6), dd = (int)(gc & 63);
  const int lb = (int)(row0 & 4095) + lh * 64;
  char* basep = (char*)Cv + (((long)(b * 16 + hh) * 64 + dd) * 4096 + lb) * 2;
#pragma unroll
  for (int cc8 = 0; cc8 < 8; ++cc8) {
    unsigned short v[8];
#pragma unroll
    for (int k = 0; k < 8; ++k)
      v[k] = sm[(lh * 64 + cc8 * 8 + k) * 128 + (c ^ (k << 1))];
    uint4 o;
    o.x = (unsigned)v[0] | ((unsigned)v[1] << 16);
    o.y = (unsigned)v[2] | ((unsigned)v[3] << 16);
    o.z = (unsigned)v[4] | ((unsigned)v[5] << 16);
    o.w = (unsigned)v[6] | ((unsigned)v[7] << 16);
    *(uint4*)(basep + ((cc8 ^ (dd & 7)) << 4)) = o;
  }
}

// -------- kv kernel: PART[chunk][bhh][d][m] = sum_l vT[d][l]*kp[l][m] --------
__global__ __launch_bounds__(256, 2) void kv_kernel(
    const unsigned short* __restrict__ PH, const unsigned short* __restrict__ VTg,
    float* __restrict__ PART, int half) {
  __shared__ __align__(16) unsigned short Ps[64 * 128];
  __shared__ __align__(16) unsigned short Vs[64 * 64];
  __shared__ __align__(16) unsigned short KPT[256 * 64];
  const int tid = threadIdx.x;
  const int lane = tid & 63, wid = tid >> 6;
  const int bhh = blockIdx.x, chunk = blockIdx.y;
  const int b2 = bhh >> 4, h = bhh & 15;
  const int bh = (half * 2 + b2) * 16 + h;

  f32x4 acc[4][4] = {};
  const int e = lane & 15, g = lane >> 4;
  const int m = tid & 127, isin = tid >> 7;
  const int m2 = (isin << 7) + m, swm = m & 7;

  for (int ti = 0; ti < 4; ++ti) {
    const int l0 = chunk * 256 + ti * 64;
    __syncthreads();
#pragma unroll
    for (int c = 0; c < 4; ++c) {
      const int r = l0 + c * 16 + (tid >> 4);
      gload_lds16((const char*)PH + (long)(b2 * 4096 + r) * 4096 + h * 256 + (tid & 15) * 16,
                  (char*)Ps + c * 4096 + (wid << 10));
    }
#pragma unroll
    for (int c = 0; c < 2; ++c) {
      const int d = c * 32 + (tid >> 3);
      gload_lds16((const char*)VTg + ((long)(bh * 64 + d) * 4096 + l0) * 2 + (tid & 7) * 16,
                  (char*)Vs + c * 4096 + (wid << 10));
    }
    __syncthreads();
    {
      char* krow = (char*)KPT + m2 * 128;
#pragma unroll
      for (int g8 = 0; g8 < 8; ++g8) {
        unsigned pk[4];
#pragma unroll
        for (int k2 = 0; k2 < 4; ++k2) {
          const float p0 = bf2f(Ps[(g8 * 8 + k2 * 2) * 128 + m]);
          const float p1 = bf2f(Ps[(g8 * 8 + k2 * 2 + 1) * 128 + m]);
          const float v0 = (isin ? __sinf(p0) : __cosf(p0)) * RS128;
          const float v1 = (isin ? __sinf(p1) : __cosf(p1)) * RS128;
          pk[k2] = pack2f(v0, v1);
        }
        uint4 o; o.x = pk[0]; o.y = pk[1]; o.z = pk[2]; o.w = pk[3];
        *(uint4*)(krow + ((g8 ^ swm) << 4)) = o;
      }
    }
    __syncthreads();
#pragma unroll
    for (int kk = 0; kk < 2; ++kk) {
      const int ch = (kk << 2) + g;
      bf16x8 af[4], bfr[4];
#pragma unroll
      for (int i = 0; i < 4; ++i) {
        const int dr = (i << 4) + e;
        af[i] = *(const bf16x8*)((char*)Vs + dr * 128 + ((ch ^ (e & 7)) << 4));
      }
#pragma unroll
      for (int j = 0; j < 4; ++j) {
        const int mr = (wid << 6) + (j << 4) + e;
        bfr[j] = *(const bf16x8*)((char*)KPT + mr * 128 + ((ch ^ (e & 7)) << 4));
      }
#pragma unroll
      for (int i = 0; i < 4; ++i)
#pragma unroll
        for (int j = 0; j < 4; ++j)
          acc[i][j] = __builtin_amdgcn_mfma_f32_16x16x32_bf16(af[i], bfr[j],
                                                              acc[i][j], 0, 0, 0);
    }
  }
  float* slice = PART + ((long)chunk * 32 + bhh) * 16384;
#pragma unroll
  for (int i = 0; i < 4; ++i)
#pragma unroll
    for (int j = 0; j < 4; ++j)
#pragma unroll
      for (int r = 0; r < 4; ++r) {
        const int d = (i << 4) + (g << 2) + r;
        const int mc = (wid << 6) + (j << 4) + e;
        slice[d * 256 + mc] = acc[i][j][r];
      }
}

__global__ __launch_bounds__(256) void kv_reduce(const float* __restrict__ PART,
                                                 float* __restrict__ KVacc, int half) {
  const int bhh = blockIdx.x, seg = blockIdx.y;
  const long off = (long)bhh * 16384 + seg * 1024 + threadIdx.x * 4;
  float4 s = make_float4(0.f, 0.f, 0.f, 0.f);
#pragma unroll
  for (int c = 0; c < 16; ++c) {
    const float4 v = *(const float4*)(PART + ((long)c * 32) * 16384 + off);
    s.x += v.x; s.y += v.y; s.z += v.z; s.w += v.w;
  }
  *(float4*)(KVacc + (long)(half * 32) * 16384 + off) = s;
}

__global__ __launch_bounds__(256) void kvt_conv(const float* __restrict__ KVacc,
                                                unsigned short* __restrict__ KVT) {
  const int bh = blockIdx.x, tid = threadIdx.x;
  const int d = tid >> 2, mq = tid & 3;
  const float* src = KVacc + (long)bh * 16384 + d * 256 + mq * 64;
  char* dst = (char*)KVT + bh * 32768 + d * 512;
#pragma unroll
  for (int cc = 0; cc < 8; ++cc) {
    const float4 a = *(const float4*)(src + cc * 8);
    const float4 b = *(const float4*)(src + cc * 8 + 4);
    uint4 o;
    o.x = pack2f(a.x, a.y); o.y = pack2f(a.z, a.w);
    o.z = pack2f(b.x, b.y); o.w = pack2f(b.z, b.w);
    const int chunk = mq * 8 + cc;
    *(uint4*)(dst + ((chunk ^ (d & 7)) << 4)) = o;
  }
}

// -------- attn kernel: ATTN[l][h*64+d] = sum_m qp[l][m]*kvT[d][m] --------
__global__ __launch_bounds__(256, 2) void attn_kernel(
    const unsigned short* __restrict__ PH, const unsigned short* __restrict__ KVT,
    unsigned short* __restrict__ ATTN, int half) {
  __shared__ __align__(16) unsigned short QPs[64 * 256];
  __shared__ __align__(16) unsigned short KVs[64 * 256];
  const int tid = threadIdx.x;
  const int lane = tid & 63, wid = tid >> 6;
  const int bhh = blockIdx.x, chunk = blockIdx.y;
  const int b2 = bhh >> 4, h = bhh & 15;
  const int b = half * 2 + b2, bh = b * 16 + h;
  const int e = lane & 15, g = lane >> 4;

#pragma unroll
  for (int c = 0; c < 8; ++c)
    gload_lds16((const char*)KVT + bh * 32768 + c * 4096 + tid * 16,
                (char*)KVs + c * 4096 + (wid << 10));

  const int lrow = tid >> 2, ms = tid & 3, swl = lrow & 7;

  for (int ti = 0; ti < 4; ++ti) {
    const int l0 = chunk * 256 + ti * 64;
    const char* pg = (const char*)PH + (long)(b2 * 4096 + l0 + lrow) * 4096 + h * 256 + ms * 64;
    uint4 P[4];
#pragma unroll
    for (int q = 0; q < 4; ++q) P[q] = *(const uint4*)(pg + q * 16);
    uint4 CQ[4], SQ[4];
#pragma unroll
    for (int q = 0; q < 4; ++q) {
      const unsigned w[4] = {P[q].x, P[q].y, P[q].z, P[q].w};
      unsigned cw[4], sw[4];
#pragma unroll
      for (int k = 0; k < 4; ++k) {
        float c0, s0, c1, s1;
        __sincosf(bf2f((unsigned short)(w[k] & 0xffff)), &s0, &c0);
        __sincosf(bf2f((unsigned short)(w[k] >> 16)), &s1, &c1);
        cw[k] = pack2f(c0 * RS128, c1 * RS128);
        sw[k] = pack2f(s0 * RS128, s1 * RS128);
      }
      CQ[q].x = cw[0]; CQ[q].y = cw[1]; CQ[q].z = cw[2]; CQ[q].w = cw[3];
      SQ[q].x = sw[0]; SQ[q].y = sw[1]; SQ[q].z = sw[2]; SQ[q].w = sw[3];
    }
    __syncthreads();
    {
      char* qrow = (char*)QPs + lrow * 512;
#pragma unroll
      for (int q = 0; q < 4; ++q) {
        const int c = ms * 4 + q;
        *(uint4*)(qrow + ((c ^ swl) << 4)) = CQ[q];
        *(uint4*)(qrow + ((16 + (c ^ swl)) << 4)) = SQ[q];
      }
    }
    __syncthreads();
    f32x4 acc[4] = {};
    const int lr = (wid << 4) + e;
#pragma unroll
    for (int kk = 0; kk < 8; ++kk) {
      const int ch = (kk << 2) + g;
      const bf16x8 af = *(const bf16x8*)((char*)QPs + lr * 512 + ((ch ^ (e & 7)) << 4));
#pragma unroll
      for (int j = 0; j < 4; ++j) {
        const bf16x8 bfr = *(const bf16x8*)((char*)KVs + ((j << 4) + e) * 512 + ((ch ^ (e & 7)) << 4));
        acc[j] = __builtin_amdgcn_mfma_f32_16x16x32_bf16(af, bfr, acc[j], 0, 0, 0);
      }
    }
#pragma unroll
    for (int j = 0; j < 4; ++j)
#pragma unroll
      for (int r = 0; r < 4; ++r) {
        const int lo = (wid << 4) + (g << 2) + r;
        ATTN[(long)(b * 4096 + l0 + lo) * 1024 + h * 64 + (j << 4) + e] = f2bf(acc[j][r]);
      }
  }
}

extern "C" void kernel_launch(void* const* d_in, const int* in_sizes, int n_in,
                              void* d_out, int out_size, void* d_ws, size_t ws_size,
                              hipStream_t stream) {
  (void)in_sizes; (void)n_in; (void)out_size; (void)ws_size;
  const float* x    = (const float*)d_in[0];
  const float* proj = (const float*)d_in[1];
  const float* wq = (const float*)d_in[2];
  const float* bq = (const float*)d_in[3];
  const float* wk = (const float*)d_in[4];
  const float* bk = (const float*)d_in[5];
  const float* wv = (const float*)d_in[6];
  const float* bv = (const float*)d_in[7];
  const float* wo = (const float*)d_in[8];
  const float* bo = (const float*)d_in[9];
  const float* g1  = (const float*)d_in[10];
  const float* be1 = (const float*)d_in[11];
  const float* w1 = (const float*)d_in[12];
  const float* b1 = (const float*)d_in[13];
  const float* w2 = (const float*)d_in[14];
  const float* b2 = (const float*)d_in[15];
  const float* g2  = (const float*)d_in[16];
  const float* be2 = (const float*)d_in[17];
  float* out = (float*)d_out;

  char* ws = (char*)d_ws;
  const size_t MB = 1u << 20;
  unsigned short* WQT    = (unsigned short*)(ws + 0 * MB);
  unsigned short* WKT    = (unsigned short*)(ws + 2 * MB);
  unsigned short* WVT    = (unsigned short*)(ws + 4 * MB);
  unsigned short* WOT    = (unsigned short*)(ws + 6 * MB);
  unsigned short* projTs = (unsigned short*)(ws + 8 * MB);
  float* KVacc = (float*)(ws + 10 * MB);
  unsigned short* KVT = (unsigned short*)(ws + 14 * MB);
  unsigned short* VTg  = (unsigned short*)(ws + 16 * MB);   // -> ATTN
  unsigned short* QKb  = (unsigned short*)(ws + 48 * MB);   // per-half Q/K [8192][1024]
  unsigned short* PH   = (unsigned short*)(ws + 64 * MB);   // [8192][2048]
  float* PART  = (float*)(ws + 96 * MB);
  unsigned short* Hb  = (unsigned short*)(ws + 0 * MB);     // FFN hidden (128MB)
  unsigned short* X2  = (unsigned short*)(ws + 128 * MB);   // -> X2B
  unsigned short* W1T = (unsigned short*)(ws + 160 * MB);
  unsigned short* W2T = (unsigned short*)(ws + 168 * MB);
  unsigned short* ATTN = VTg;
  unsigned short* X2B  = X2;

  dim3 blk(256), blk5(512);

  // weights prep
  wtrans<<<dim3(32, 32), blk, 0, stream>>>(wq, WQT, 1024, 1024);
  wtrans<<<dim3(32, 32), blk, 0, stream>>>(wk, WKT, 1024, 1024);
  wtrans<<<dim3(32, 32), blk, 0, stream>>>(wv, WVT, 1024, 1024);
  wtrans<<<dim3(32, 32), blk, 0, stream>>>(wo, WOT, 1024, 1024);
  wtrans<<<dim3(128, 32), blk, 0, stream>>>(w1, W1T, 1024, 4096);
  wtrans<<<dim3(32, 128), blk, 0, stream>>>(w2, W2T, 4096, 1024);
  projt_prep<<<1, blk, 0, stream>>>(proj, projTs);

  // LN1
  ln_kernel<<<16384, blk, 0, stream>>>(x, g1, be1, X2);

  // V gemm -> VTg (transposed + swizzled)
  gemm_vt<<<1024, blk, 0, stream>>>(X2, WVT, VTg, bv, 16384, 1024, 1024);

  // kv pipeline, two L-halves: K gemm (N=1024) -> per-head proj -> kv
  for (int half = 0; half < 2; ++half) {
    gemm256<true, false, false><<<256, blk5, 0, stream>>>(
        X2 + (long)half * 8192 * 1024, WKT, QKb, bk, nullptr, 8192, 1024, 1024);
    p_gemm<<<dim3(64, 16), blk, 0, stream>>>(QKb, projTs, PH);
    kv_kernel<<<dim3(32, 16), blk, 0, stream>>>(PH, VTg, PART, half);
    kv_reduce<<<dim3(32, 16), blk, 0, stream>>>(PART, KVacc, half);
  }
  kvt_conv<<<64, blk, 0, stream>>>(KVacc, KVT);

  // attn pipeline, two L-halves
  for (int half = 0; half < 2; ++half) {
    gemm256<true, false, false><<<256, blk5, 0, stream>>>(
        X2 + (long)half * 8192 * 1024, WQT, QKb, bq, nullptr, 8192, 1024, 1024);
    p_gemm<<<dim3(64, 16), blk, 0, stream>>>(QKb, projTs, PH);
    attn_kernel<<<dim3(32, 16), blk, 0, stream>>>(PH, KVT, ATTN, half);
  }

  // Wo + residual -> out (f32)
  gemm256<false, false, true><<<512, blk5, 0, stream>>>(
      ATTN, WOT, out, bo, x, 16384, 1024, 1024);

  // LN2
  ln_kernel<<<16384, blk, 0, stream>>>(out, g2, be2, X2B);

  // FFN (unchunked)
  gemm256<true, true, false><<<2048, blk5, 0, stream>>>(
      X2B, W1T, Hb, b1, nullptr, 16384, 4096, 1024);
  gemm256<false, false, true><<<512, blk5, 0, stream>>>(
      Hb, W2T, out, b2, out, 16384, 1024, 4096);
}

// Round 11
// 738.418 us; speedup vs baseline: 1.2135x; 1.0302x over previous
//
#include <hip/hip_runtime.h>

// EstraNetBlock: pre-norm linear attention (fourier feature kernel) + FFN.
// B=4, L=4096, D=1024, H=16, Dh=64, M=128 (2M=256), D_INNER=4096.
//
// R11 = R10 + p_gemm fused into gemm256<PROJ> epilogue: Q/K gemms write PH
// directly (per-wave 64x64 q quadrant == one head's d-range; q->LDS, 64 MFMA
// vs LDS projT staged in prologue). QKb round-trip + 4 p_gemm launches gone.
// LDS = 144KB ring + 16KB projT = 160KB.
//
// ws (MB): 0 WQT,2 WKT,4 WVT,6 WOT,8 projTs,10 KVacc,14 KVT,16 VTg(->ATTN),
// 64 PH,96 PART,128 X2(->X2B),160 W1T,168 W2T; FFN H = arena 0..128.

#define RS128 0.08838834764831845f

typedef short bf16x8 __attribute__((ext_vector_type(8)));
typedef float f32x4 __attribute__((ext_vector_type(4)));

__device__ __forceinline__ unsigned short f2bf(float f) {
  unsigned int u = __float_as_uint(f);
  u += 0x7fffu + ((u >> 16) & 1u);
  return (unsigned short)(u >> 16);
}
__device__ __forceinline__ float bf2f(unsigned short h) {
  return __uint_as_float(((unsigned int)h) << 16);
}
__device__ __forceinline__ unsigned int pack2f(float a, float b) {
  return (unsigned int)f2bf(a) | ((unsigned int)f2bf(b) << 16);
}
__device__ __forceinline__ void gload_lds16(const void* g, void* l) {
  __builtin_amdgcn_global_load_lds(
      (const __attribute__((address_space(1))) void*)g,
      (__attribute__((address_space(3))) void*)l, 16, 0, 0);
}
__device__ __forceinline__ void barrier_pin() {
  __builtin_amdgcn_sched_barrier(0);
  __builtin_amdgcn_s_barrier();
  __builtin_amdgcn_sched_barrier(0);
}
#define WAIT_VM(N) { asm volatile("s_waitcnt vmcnt(" #N ")" ::: "memory"); __builtin_amdgcn_sched_barrier(0); }
#define WAIT_LGKM0() { asm volatile("s_waitcnt lgkmcnt(0)" ::: "memory"); __builtin_amdgcn_sched_barrier(0); }

// -------- 256x128-tile 8-wave GEMM (R6 ring structure) ----------------------
// 512 thr = 8 waves (4M x 2N), per-wave 64x64 out. LDS: 3 ring bufs x 48KB
// + 16KB projT (PROJ). PROJ: epilogue computes p = (q+bias) @ projT^T per
// head and writes PH[l][hh*128+m] (Cv = PH base).
template <bool OBF16, bool RELU, bool RES, bool PROJ>
__global__ __launch_bounds__(512, 2) void gemm256(
    const unsigned short* __restrict__ A, const unsigned short* __restrict__ Bt,
    void* Cv, const float* __restrict__ bias, const float* res,
    const unsigned short* __restrict__ projTs, int M, int N, int K) {
  __shared__ __align__(16) char lds[163840];
  const int tid = threadIdx.x;
  const int lane = tid & 63, wid = tid >> 6;
  const int e = lane & 15, g = lane >> 4;
  const int wm = wid >> 1, wn = wid & 1;
  const int ntn = N >> 7;
  const int nwg = (int)gridDim.x, cpx = nwg >> 3;
  const int swz = ((int)blockIdx.x & 7) * cpx + ((int)blockIdx.x >> 3);
  const int bm = swz / ntn, bn = swz % ntn;
  const long row0 = (long)bm << 8, col0 = (long)bn << 7;

  const int srow = tid >> 3;
  const int skb = ((tid & 7) << 4) ^ ((srow & 7) << 4);
  const unsigned short* Abase = A + (row0 + srow) * (long)K + (skb >> 1);
  const unsigned short* Bbase = Bt + (col0 + srow) * (long)K + (skb >> 1);
  const int lof = wid << 10;

  f32x4 acc[4][4] = {};
  const int nkt = K >> 6;
  const int rx = (e & 7) << 4;

  char* bufA = lds;
  char* bufB = lds + 49152;
  char* bufC = lds + 98304;

  if (PROJ) {
    // stage projT (16KB, pre-swizzled) into lds+147456; issued BEFORE tile
    // loads so prologue WAIT_VM(6) completes these + bufA, leaves bufB's 6.
    gload_lds16((const char*)projTs + (wid << 10) + (lane << 4),
                lds + 147456 + (wid << 10));
    gload_lds16((const char*)projTs + 8192 + (wid << 10) + (lane << 4),
                lds + 147456 + 8192 + (wid << 10));
  }
#pragma unroll
  for (int c = 0; c < 4; ++c)
    gload_lds16(Abase + (long)c * 64 * K, bufA + lof + c * 8192);
#pragma unroll
  for (int c = 0; c < 2; ++c)
    gload_lds16(Bbase + (long)c * 64 * K, bufA + 32768 + lof + c * 8192);
#pragma unroll
  for (int c = 0; c < 4; ++c)
    gload_lds16(Abase + (long)c * 64 * K + 64, bufB + lof + c * 8192);
#pragma unroll
  for (int c = 0; c < 2; ++c)
    gload_lds16(Bbase + (long)c * 64 * K + 64, bufB + 32768 + lof + c * 8192);
  WAIT_VM(6);
  barrier_pin();

  for (int kt = 0; kt < nkt; ++kt) {
    char* Ac = bufA;
    char* Bc = bufA + 32768;
    const bool pf2 = (kt + 2 < nkt);
    const long kn2 = (long)(kt + 2) << 6;

    // phase 0
    bf16x8 bfr[4][2];
#pragma unroll
    for (int j = 0; j < 4; ++j) {
      const int r = wn * 64 + j * 16 + e;
#pragma unroll
      for (int kh = 0; kh < 2; ++kh)
        bfr[j][kh] = *(const bf16x8*)(Bc + r * 128 + ((g * 16 + kh * 64) ^ rx));
    }
    bf16x8 af0[2][2];
#pragma unroll
    for (int i = 0; i < 2; ++i) {
      const int r = wm * 64 + i * 16 + e;
#pragma unroll
      for (int kh = 0; kh < 2; ++kh)
        af0[i][kh] = *(const bf16x8*)(Ac + r * 128 + ((g * 16 + kh * 64) ^ rx));
    }
    if (pf2) {
#pragma unroll
      for (int c = 0; c < 3; ++c)
        gload_lds16(Abase + (long)c * 64 * K + kn2, bufC + lof + c * 8192);
    }
    barrier_pin();
    WAIT_LGKM0();
    __builtin_amdgcn_s_setprio(1);
#pragma unroll
    for (int i = 0; i < 2; ++i)
#pragma unroll
      for (int j = 0; j < 4; ++j)
#pragma unroll
        for (int kh = 0; kh < 2; ++kh)
          acc[i][j] = __builtin_amdgcn_mfma_f32_16x16x32_bf16(
              af0[i][kh], bfr[j][kh], acc[i][j], 0, 0, 0);
    __builtin_amdgcn_s_setprio(0);
    barrier_pin();

    // phase 1
    bf16x8 af1[2][2];
#pragma unroll
    for (int i = 0; i < 2; ++i) {
      const int r = wm * 64 + (2 + i) * 16 + e;
#pragma unroll
      for (int kh = 0; kh < 2; ++kh)
        af1[i][kh] = *(const bf16x8*)(Ac + r * 128 + ((g * 16 + kh * 64) ^ rx));
    }
    if (pf2) {
      gload_lds16(Abase + (long)3 * 64 * K + kn2, bufC + lof + 3 * 8192);
      gload_lds16(Bbase + kn2, bufC + 32768 + lof);
      gload_lds16(Bbase + (long)64 * K + kn2, bufC + 32768 + lof + 8192);
      WAIT_VM(6);
    } else if (kt + 1 < nkt) {
      WAIT_VM(0);
    }
    barrier_pin();
    WAIT_LGKM0();
    __builtin_amdgcn_s_setprio(1);
#pragma unroll
    for (int i = 0; i < 2; ++i)
#pragma unroll
      for (int j = 0; j < 4; ++j)
#pragma unroll
        for (int kh = 0; kh < 2; ++kh)
          acc[2 + i][j] = __builtin_amdgcn_mfma_f32_16x16x32_bf16(
              af1[i][kh], bfr[j][kh], acc[2 + i][j], 0, 0, 0);
    __builtin_amdgcn_s_setprio(0);
    barrier_pin();

    char* t = bufA; bufA = bufB; bufB = bufC; bufC = t;
  }

  if (PROJ) {
    // ---- fused per-head projection epilogue ----
    // wave's 64x64 quadrant = head hh = 2*bn+wn, rows row0+wm*64..+64.
    char* qt = lds + (wid << 13);  // ring is dead after final barrier
    const int c0p = wn * 64 + e;
#pragma unroll
    for (int j = 0; j < 4; ++j) {
      const float bvv = bias[col0 + c0p + (j << 4)];
#pragma unroll
      for (int mf = 0; mf < 4; ++mf)
#pragma unroll
        for (int r = 0; r < 4; ++r) {
          const int lrow = (mf << 4) + (g << 2) + r;
          const int dby = ((((j << 4) + e) << 1)) ^ ((lrow & 7) << 4);
          *(unsigned short*)(qt + lrow * 128 + dby) = f2bf(acc[mf][j][r] + bvv);
        }
    }
    WAIT_LGKM0();  // own-wave LDS writes drained before reads
    const char* pj = lds + 147456;
    bf16x8 paf[4][2];
#pragma unroll
    for (int i = 0; i < 4; ++i) {
      const int r = (i << 4) + e;
#pragma unroll
      for (int kh = 0; kh < 2; ++kh)
        paf[i][kh] = *(const bf16x8*)(qt + r * 128 + ((g * 16 + kh * 64) ^ rx));
    }
    f32x4 pacc[4][8] = {};
#pragma unroll
    for (int j = 0; j < 8; ++j) {
      const int m = (j << 4) + e;
      const bf16x8 pb0 = *(const bf16x8*)(pj + m * 128 + ((g * 16) ^ rx));
      const bf16x8 pb1 = *(const bf16x8*)(pj + m * 128 + ((g * 16 + 64) ^ rx));
#pragma unroll
      for (int i = 0; i < 4; ++i) {
        pacc[i][j] = __builtin_amdgcn_mfma_f32_16x16x32_bf16(paf[i][0], pb0,
                                                             pacc[i][j], 0, 0, 0);
        pacc[i][j] = __builtin_amdgcn_mfma_f32_16x16x32_bf16(paf[i][1], pb1,
                                                             pacc[i][j], 0, 0, 0);
      }
    }
    unsigned short* PHp = (unsigned short*)Cv;
    const int hh = 2 * bn + wn;
    const long lbase = row0 + wm * 64;
#pragma unroll
    for (int i = 0; i < 4; ++i)
#pragma unroll
      for (int j = 0; j < 8; ++j)
#pragma unroll
        for (int r = 0; r < 4; ++r) {
          const long l = lbase + (i << 4) + (g << 2) + r;
          PHp[l * 2048 + hh * 128 + (j << 4) + e] = f2bf(pacc[i][j][r]);
        }
    return;
  }

  const int r0 = wm * 64 + (g << 2);
  const int c0 = wn * 64 + e;
#pragma unroll
  for (int j = 0; j < 4; ++j) {
    const long gcol = col0 + c0 + (j << 4);
    const float bvv = bias[gcol];
#pragma unroll
    for (int mf = 0; mf < 4; ++mf) {
#pragma unroll
      for (int r = 0; r < 4; ++r) {
        const long grow = row0 + r0 + (mf << 4) + r;
        float v = acc[mf][j][r] + bvv;
        if (RES) v += res[grow * N + gcol];
        if (RELU) v = fmaxf(v, 0.f);
        if (OBF16) ((unsigned short*)Cv)[grow * N + gcol] = f2bf(v);
        else ((float*)Cv)[grow * N + gcol] = v;
      }
    }
  }
}

// -------- weight transpose + cast: W[K][N] f32 -> Wt[N][K] bf16 --------
__global__ __launch_bounds__(256) void wtrans(const float* __restrict__ W,
                                              unsigned short* __restrict__ Wt,
                                              int K, int N) {
  __shared__ float t[32][33];
  const int tx = threadIdx.x & 31, ty = threadIdx.x >> 5;
  const int n0 = blockIdx.x << 5, k0 = blockIdx.y << 5;
#pragma unroll
  for (int i = 0; i < 32; i += 8)
    t[ty + i][tx] = W[(long)(k0 + ty + i) * N + n0 + tx];
  __syncthreads();
#pragma unroll
  for (int i = 0; i < 32; i += 8)
    Wt[(long)(n0 + ty + i) * K + k0 + tx] = f2bf(t[tx][ty + i]);
}

// -------- projT prep: projTs[m][d] = bf16(proj[d][m]*0.125), pre-swizzled ----
__global__ __launch_bounds__(256) void projt_prep(const float* __restrict__ proj,
                                                  unsigned short* __restrict__ projTs) {
  const int t = threadIdx.x;
  const int m = t >> 1, sh = t & 1;
#pragma unroll
  for (int s4 = 0; s4 < 4; ++s4) {
    const int s = sh * 4 + s4;
    unsigned short v[8];
#pragma unroll
    for (int k = 0; k < 8; ++k)
      v[k] = f2bf(proj[(s * 8 + k) * 128 + m] * 0.125f);
    uint4 o;
    o.x = (unsigned)v[0] | ((unsigned)v[1] << 16);
    o.y = (unsigned)v[2] | ((unsigned)v[3] << 16);
    o.z = (unsigned)v[4] | ((unsigned)v[5] << 16);
    o.w = (unsigned)v[6] | ((unsigned)v[7] << 16);
    *(uint4*)((char*)projTs + m * 128 + ((s ^ (m & 7)) << 4)) = o;
  }
}

// -------- LayerNorm over 1024 cols, f32 in -> bf16 out --------
__global__ __launch_bounds__(256) void ln_kernel(const float* __restrict__ x,
                                                 const float* __restrict__ g,
                                                 const float* __restrict__ b,
                                                 unsigned short* __restrict__ out) {
  const int row = blockIdx.x, tid = threadIdx.x;
  const float* xr = x + (long)row * 1024;
  const float4 xv = *(const float4*)(xr + tid * 4);
  float s = xv.x + xv.y + xv.z + xv.w;
  float s2 = xv.x * xv.x + xv.y * xv.y + xv.z * xv.z + xv.w * xv.w;
#pragma unroll
  for (int off = 32; off > 0; off >>= 1) {
    s += __shfl_down(s, off);
    s2 += __shfl_down(s2, off);
  }
  __shared__ float ps[4], ps2[4];
  if ((tid & 63) == 0) { ps[tid >> 6] = s; ps2[tid >> 6] = s2; }
  __syncthreads();
  const float ts = ps[0] + ps[1] + ps[2] + ps[3];
  const float ts2 = ps2[0] + ps2[1] + ps2[2] + ps2[3];
  const float mu = ts * (1.f / 1024.f);
  const float rstd = rsqrtf(ts2 * (1.f / 1024.f) - mu * mu + 1e-5f);
  const float4 gv = *(const float4*)(g + tid * 4);
  const float4 bv = *(const float4*)(b + tid * 4);
  ushort4 o;
  o.x = f2bf((xv.x - mu) * rstd * gv.x + bv.x);
  o.y = f2bf((xv.y - mu) * rstd * gv.y + bv.y);
  o.z = f2bf((xv.z - mu) * rstd * gv.z + bv.z);
  o.w = f2bf((xv.w - mu) * rstd * gv.w + bv.w);
  *(ushort4*)(out + (long)row * 1024 + tid * 4) = o;
}

// -------- 128x128 GEMM with V-transpose epilogue (V path only) --------
__global__ __launch_bounds__(256, 2) void gemm_vt(
    const unsigned short* __restrict__ A, const unsigned short* __restrict__ Bt,
    void* Cv, const float* __restrict__ bias, int M, int N, int K) {
  __shared__ __align__(16) unsigned short sm[128 * 128];
  unsigned short* As = sm;
  unsigned short* Bs = sm + 128 * 64;
  const int tid = threadIdx.x;
  const int lane = tid & 63, wid = tid >> 6;
  const int ntn = N >> 7;
  const int bm = blockIdx.x / ntn, bn = blockIdx.x % ntn;
  const long row0 = (long)bm << 7, col0 = (long)bn << 7;
  const int wr = (wid >> 1) << 6, wc = (wid & 1) << 6;

  f32x4 acc[4][4] = {};
  const unsigned short* Ag = A + (row0 + (tid >> 3)) * (long)K + ((tid & 7) << 3);
  const unsigned short* Bg = Bt + (col0 + (tid >> 3)) * (long)K + ((tid & 7) << 3);
  char* AsB = (char*)As + (wid << 10);
  char* BsB = (char*)Bs + (wid << 10);

  for (int kt = 0; kt < K; kt += 64) {
#pragma unroll
    for (int c = 0; c < 4; ++c) {
      gload_lds16(Ag + kt + (long)c * 32 * K, AsB + (c << 12));
      gload_lds16(Bg + kt + (long)c * 32 * K, BsB + (c << 12));
    }
    __syncthreads();
#pragma unroll
    for (int kk = 0; kk < 2; ++kk) {
      const int krow = (kk << 5) + ((lane >> 4) << 3);
      bf16x8 af[4], bfr[4];
#pragma unroll
      for (int i = 0; i < 4; ++i)
        af[i] = *(const bf16x8*)(As + (wr + (i << 4) + (lane & 15)) * 64 + krow);
#pragma unroll
      for (int j = 0; j < 4; ++j)
        bfr[j] = *(const bf16x8*)(Bs + (wc + (j << 4) + (lane & 15)) * 64 + krow);
#pragma unroll
      for (int i = 0; i < 4; ++i)
#pragma unroll
        for (int j = 0; j < 4; ++j)
          acc[i][j] = __builtin_amdgcn_mfma_f32_16x16x32_bf16(af[i], bfr[j],
                                                              acc[i][j], 0, 0, 0);
    }
    __syncthreads();
  }

  const int r0 = wr + ((lane >> 4) << 2);
  const int c0l = wc + (lane & 15);
#pragma unroll
  for (int j = 0; j < 4; ++j) {
    const int cc = c0l + (j << 4);
    const float bvv = bias[col0 + cc];
#pragma unroll
    for (int i = 0; i < 4; ++i)
#pragma unroll
      for (int r = 0; r < 4; ++r) {
        const int ll = r0 + (i << 4) + r;
        sm[ll * 128 + (cc ^ ((ll & 7) << 1))] = f2bf(acc[i][j][r] + bvv);
      }
  }
  __syncthreads();
  const int c = tid & 127, lh = tid >> 7;
  const long gc = col0 + c;
  const int b = (int)(row0 >> 12);
  const int hh = (int)(gc >> 6), dd = (int)(gc & 63);
  const int lb = (int)(row0 & 4095) + lh * 64;
  char* basep = (char*)Cv + (((long)(b * 16 + hh) * 64 + dd) * 4096 + lb) * 2;
#pragma unroll
  for (int cc8 = 0; cc8 < 8; ++cc8) {
    unsigned short v[8];
#pragma unroll
    for (int k = 0; k < 8; ++k)
      v[k] = sm[(lh * 64 + cc8 * 8 + k) * 128 + (c ^ (k << 1))];
    uint4 o;
    o.x = (unsigned)v[0] | ((unsigned)v[1] << 16);
    o.y = (unsigned)v[2] | ((unsigned)v[3] << 16);
    o.z = (unsigned)v[4] | ((unsigned)v[5] << 16);
    o.w = (unsigned)v[6] | ((unsigned)v[7] << 16);
    *(uint4*)(basep + ((cc8 ^ (dd & 7)) << 4)) = o;
  }
}

// -------- kv kernel: PART[chunk][bhh][d][m] = sum_l vT[d][l]*kp[l][m] --------
__global__ __launch_bounds__(256, 2) void kv_kernel(
    const unsigned short* __restrict__ PH, const unsigned short* __restrict__ VTg,
    float* __restrict__ PART, int half) {
  __shared__ __align__(16) unsigned short Ps[64 * 128];
  __shared__ __align__(16) unsigned short Vs[64 * 64];
  __shared__ __align__(16) unsigned short KPT[256 * 64];
  const int tid = threadIdx.x;
  const int lane = tid & 63, wid = tid >> 6;
  const int bhh = blockIdx.x, chunk = blockIdx.y;
  const int b2 = bhh >> 4, h = bhh & 15;
  const int bh = (half * 2 + b2) * 16 + h;

  f32x4 acc[4][4] = {};
  const int e = lane & 15, g = lane >> 4;
  const int m = tid & 127, isin = tid >> 7;
  const int m2 = (isin << 7) + m, swm = m & 7;

  for (int ti = 0; ti < 4; ++ti) {
    const int l0 = chunk * 256 + ti * 64;
    __syncthreads();
#pragma unroll
    for (int c = 0; c < 4; ++c) {
      const int r = l0 + c * 16 + (tid >> 4);
      gload_lds16((const char*)PH + (long)(b2 * 4096 + r) * 4096 + h * 256 + (tid & 15) * 16,
                  (char*)Ps + c * 4096 + (wid << 10));
    }
#pragma unroll
    for (int c = 0; c < 2; ++c) {
      const int d = c * 32 + (tid >> 3);
      gload_lds16((const char*)VTg + ((long)(bh * 64 + d) * 4096 + l0) * 2 + (tid & 7) * 16,
                  (char*)Vs + c * 4096 + (wid << 10));
    }
    __syncthreads();
    {
      char* krow = (char*)KPT + m2 * 128;
#pragma unroll
      for (int g8 = 0; g8 < 8; ++g8) {
        unsigned pk[4];
#pragma unroll
        for (int k2 = 0; k2 < 4; ++k2) {
          const float p0 = bf2f(Ps[(g8 * 8 + k2 * 2) * 128 + m]);
          const float p1 = bf2f(Ps[(g8 * 8 + k2 * 2 + 1) * 128 + m]);
          const float v0 = (isin ? __sinf(p0) : __cosf(p0)) * RS128;
          const float v1 = (isin ? __sinf(p1) : __cosf(p1)) * RS128;
          pk[k2] = pack2f(v0, v1);
        }
        uint4 o; o.x = pk[0]; o.y = pk[1]; o.z = pk[2]; o.w = pk[3];
        *(uint4*)(krow + ((g8 ^ swm) << 4)) = o;
      }
    }
    __syncthreads();
#pragma unroll
    for (int kk = 0; kk < 2; ++kk) {
      const int ch = (kk << 2) + g;
      bf16x8 af[4], bfr[4];
#pragma unroll
      for (int i = 0; i < 4; ++i) {
        const int dr = (i << 4) + e;
        af[i] = *(const bf16x8*)((char*)Vs + dr * 128 + ((ch ^ (e & 7)) << 4));
      }
#pragma unroll
      for (int j = 0; j < 4; ++j) {
        const int mr = (wid << 6) + (j << 4) + e;
        bfr[j] = *(const bf16x8*)((char*)KPT + mr * 128 + ((ch ^ (e & 7)) << 4));
      }
#pragma unroll
      for (int i = 0; i < 4; ++i)
#pragma unroll
        for (int j = 0; j < 4; ++j)
          acc[i][j] = __builtin_amdgcn_mfma_f32_16x16x32_bf16(af[i], bfr[j],
                                                              acc[i][j], 0, 0, 0);
    }
  }
  float* slice = PART + ((long)chunk * 32 + bhh) * 16384;
#pragma unroll
  for (int i = 0; i < 4; ++i)
#pragma unroll
    for (int j = 0; j < 4; ++j)
#pragma unroll
      for (int r = 0; r < 4; ++r) {
        const int d = (i << 4) + (g << 2) + r;
        const int mc = (wid << 6) + (j << 4) + e;
        slice[d * 256 + mc] = acc[i][j][r];
      }
}

__global__ __launch_bounds__(256) void kv_reduce(const float* __restrict__ PART,
                                                 float* __restrict__ KVacc, int half) {
  const int bhh = blockIdx.x, seg = blockIdx.y;
  const long off = (long)bhh * 16384 + seg * 1024 + threadIdx.x * 4;
  float4 s = make_float4(0.f, 0.f, 0.f, 0.f);
#pragma unroll
  for (int c = 0; c < 16; ++c) {
    const float4 v = *(const float4*)(PART + ((long)c * 32) * 16384 + off);
    s.x += v.x; s.y += v.y; s.z += v.z; s.w += v.w;
  }
  *(float4*)(KVacc + (long)(half * 32) * 16384 + off) = s;
}

__global__ __launch_bounds__(256) void kvt_conv(const float* __restrict__ KVacc,
                                                unsigned short* __restrict__ KVT) {
  const int bh = blockIdx.x, tid = threadIdx.x;
  const int d = tid >> 2, mq = tid & 3;
  const float* src = KVacc + (long)bh * 16384 + d * 256 + mq * 64;
  char* dst = (char*)KVT + bh * 32768 + d * 512;
#pragma unroll
  for (int cc = 0; cc < 8; ++cc) {
    const float4 a = *(const float4*)(src + cc * 8);
    const float4 b = *(const float4*)(src + cc * 8 + 4);
    uint4 o;
    o.x = pack2f(a.x, a.y); o.y = pack2f(a.z, a.w);
    o.z = pack2f(b.x, b.y); o.w = pack2f(b.z, b.w);
    const int chunk = mq * 8 + cc;
    *(uint4*)(dst + ((chunk ^ (d & 7)) << 4)) = o;
  }
}

// -------- attn kernel: ATTN[l][h*64+d] = sum_m qp[l][m]*kvT[d][m] --------
__global__ __launch_bounds__(256, 2) void attn_kernel(
    const unsigned short* __restrict__ PH, const unsigned short* __restrict__ KVT,
    unsigned short* __restrict__ ATTN, int half) {
  __shared__ __align__(16) unsigned short QPs[64 * 256];
  __shared__ __align__(16) unsigned short KVs[64 * 256];
  const int tid = threadIdx.x;
  const int lane = tid & 63, wid = tid >> 6;
  const int bhh = blockIdx.x, chunk = blockIdx.y;
  const int b2 = bhh >> 4, h = bhh & 15;
  const int b = half * 2 + b2, bh = b * 16 + h;
  const int e = lane & 15, g = lane >> 4;

#pragma unroll
  for (int c = 0; c < 8; ++c)
    gload_lds16((const char*)KVT + bh * 32768 + c * 4096 + tid * 16,
                (char*)KVs + c * 4096 + (wid << 10));

  const int lrow = tid >> 2, ms = tid & 3, swl = lrow & 7;

  for (int ti = 0; ti < 4; ++ti) {
    const int l0 = chunk * 256 + ti * 64;
    const char* pg = (const char*)PH + (long)(b2 * 4096 + l0 + lrow) * 4096 + h * 256 + ms * 64;
    uint4 P[4];
#pragma unroll
    for (int q = 0; q < 4; ++q) P[q] = *(const uint4*)(pg + q * 16);
    uint4 CQ[4], SQ[4];
#pragma unroll
    for (int q = 0; q < 4; ++q) {
      const unsigned w[4] = {P[q].x, P[q].y, P[q].z, P[q].w};
      unsigned cw[4], sw[4];
#pragma unroll
      for (int k = 0; k < 4; ++k) {
        float c0, s0, c1, s1;
        __sincosf(bf2f((unsigned short)(w[k] & 0xffff)), &s0, &c0);
        __sincosf(bf2f((unsigned short)(w[k] >> 16)), &s1, &c1);
        cw[k] = pack2f(c0 * RS128, c1 * RS128);
        sw[k] = pack2f(s0 * RS128, s1 * RS128);
      }
      CQ[q].x = cw[0]; CQ[q].y = cw[1]; CQ[q].z = cw[2]; CQ[q].w = cw[3];
      SQ[q].x = sw[0]; SQ[q].y = sw[1]; SQ[q].z = sw[2]; SQ[q].w = sw[3];
    }
    __syncthreads();
    {
      char* qrow = (char*)QPs + lrow * 512;
#pragma unroll
      for (int q = 0; q < 4; ++q) {
        const int c = ms * 4 + q;
        *(uint4*)(qrow + ((c ^ swl) << 4)) = CQ[q];
        *(uint4*)(qrow + ((16 + (c ^ swl)) << 4)) = SQ[q];
      }
    }
    __syncthreads();
    f32x4 acc[4] = {};
    const int lr = (wid << 4) + e;
#pragma unroll
    for (int kk = 0; kk < 8; ++kk) {
      const int ch = (kk << 2) + g;
      const bf16x8 af = *(const bf16x8*)((char*)QPs + lr * 512 + ((ch ^ (e & 7)) << 4));
#pragma unroll
      for (int j = 0; j < 4; ++j) {
        const bf16x8 bfr = *(const bf16x8*)((char*)KVs + ((j << 4) + e) * 512 + ((ch ^ (e & 7)) << 4));
        acc[j] = __builtin_amdgcn_mfma_f32_16x16x32_bf16(af, bfr, acc[j], 0, 0, 0);
      }
    }
#pragma unroll
    for (int j = 0; j < 4; ++j)
#pragma unroll
      for (int r = 0; r < 4; ++r) {
        const int lo = (wid << 4) + (g << 2) + r;
        ATTN[(long)(b * 4096 + l0 + lo) * 1024 + h * 64 + (j << 4) + e] = f2bf(acc[j][r]);
      }
  }
}

extern "C" void kernel_launch(void* const* d_in, const int* in_sizes, int n_in,
                              void* d_out, int out_size, void* d_ws, size_t ws_size,
                              hipStream_t stream) {
  (void)in_sizes; (void)n_in; (void)out_size; (void)ws_size;
  const float* x    = (const float*)d_in[0];
  const float* proj = (const float*)d_in[1];
  const float* wq = (const float*)d_in[2];
  const float* bq = (const float*)d_in[3];
  const float* wk = (const float*)d_in[4];
  const float* bk = (const float*)d_in[5];
  const float* wv = (const float*)d_in[6];
  const float* bv = (const float*)d_in[7];
  const float* wo = (const float*)d_in[8];
  const float* bo = (const float*)d_in[9];
  const float* g1  = (const float*)d_in[10];
  const float* be1 = (const float*)d_in[11];
  const float* w1 = (const float*)d_in[12];
  const float* b1 = (const float*)d_in[13];
  const float* w2 = (const float*)d_in[14];
  const float* b2 = (const float*)d_in[15];
  const float* g2  = (const float*)d_in[16];
  const float* be2 = (const float*)d_in[17];
  float* out = (float*)d_out;

  char* ws = (char*)d_ws;
  const size_t MB = 1u << 20;
  unsigned short* WQT    = (unsigned short*)(ws + 0 * MB);
  unsigned short* WKT    = (unsigned short*)(ws + 2 * MB);
  unsigned short* WVT    = (unsigned short*)(ws + 4 * MB);
  unsigned short* WOT    = (unsigned short*)(ws + 6 * MB);
  unsigned short* projTs = (unsigned short*)(ws + 8 * MB);
  float* KVacc = (float*)(ws + 10 * MB);
  unsigned short* KVT = (unsigned short*)(ws + 14 * MB);
  unsigned short* VTg  = (unsigned short*)(ws + 16 * MB);   // -> ATTN
  unsigned short* PH   = (unsigned short*)(ws + 64 * MB);   // [8192][2048]
  float* PART  = (float*)(ws + 96 * MB);
  unsigned short* Hb  = (unsigned short*)(ws + 0 * MB);     // FFN hidden (128MB)
  unsigned short* X2  = (unsigned short*)(ws + 128 * MB);   // -> X2B
  unsigned short* W1T = (unsigned short*)(ws + 160 * MB);
  unsigned short* W2T = (unsigned short*)(ws + 168 * MB);
  unsigned short* ATTN = VTg;
  unsigned short* X2B  = X2;

  dim3 blk(256), blk5(512);

  // weights prep
  wtrans<<<dim3(32, 32), blk, 0, stream>>>(wq, WQT, 1024, 1024);
  wtrans<<<dim3(32, 32), blk, 0, stream>>>(wk, WKT, 1024, 1024);
  wtrans<<<dim3(32, 32), blk, 0, stream>>>(wv, WVT, 1024, 1024);
  wtrans<<<dim3(32, 32), blk, 0, stream>>>(wo, WOT, 1024, 1024);
  wtrans<<<dim3(128, 32), blk, 0, stream>>>(w1, W1T, 1024, 4096);
  wtrans<<<dim3(32, 128), blk, 0, stream>>>(w2, W2T, 4096, 1024);
  projt_prep<<<1, blk, 0, stream>>>(proj, projTs);

  // LN1
  ln_kernel<<<16384, blk, 0, stream>>>(x, g1, be1, X2);

  // V gemm -> VTg (transposed + swizzled)
  gemm_vt<<<1024, blk, 0, stream>>>(X2, WVT, VTg, bv, 16384, 1024, 1024);

  // kv pipeline, two L-halves: K gemm + fused per-head proj -> PH -> kv
  for (int half = 0; half < 2; ++half) {
    gemm256<true, false, false, true><<<256, blk5, 0, stream>>>(
        X2 + (long)half * 8192 * 1024, WKT, PH, bk, nullptr, projTs, 8192, 1024, 1024);
    kv_kernel<<<dim3(32, 16), blk, 0, stream>>>(PH, VTg, PART, half);
    kv_reduce<<<dim3(32, 16), blk, 0, stream>>>(PART, KVacc, half);
  }
  kvt_conv<<<64, blk, 0, stream>>>(KVacc, KVT);

  // attn pipeline, two L-halves
  for (int half = 0; half < 2; ++half) {
    gemm256<true, false, false, true><<<256, blk5, 0, stream>>>(
        X2 + (long)half * 8192 * 1024, WQT, PH, bq, nullptr, projTs, 8192, 1024, 1024);
    attn_kernel<<<dim3(32, 16), blk, 0, stream>>>(PH, KVT, ATTN, half);
  }

  // Wo + residual -> out (f32)
  gemm256<false, false, true, false><<<512, blk5, 0, stream>>>(
      ATTN, WOT, out, bo, x, nullptr, 16384, 1024, 1024);

  // LN2
  ln_kernel<<<16384, blk, 0, stream>>>(out, g2, be2, X2B);

  // FFN (unchunked)
  gemm256<true, true, false, false><<<2048, blk5, 0, stream>>>(
      X2B, W1T, Hb, b1, nullptr, nullptr, 16384, 4096, 1024);
  gemm256<false, false, true, false><<<512, blk5, 0, stream>>>(
      Hb, W2T, out, b2, out, nullptr, 16384, 1024, 4096);
}

// Round 12
// 732.407 us; speedup vs baseline: 1.2235x; 1.0082x over previous
//
#include <hip/hip_runtime.h>

// EstraNetBlock: pre-norm linear attention (fourier feature kernel) + FFN.
// B=4, L=4096, D=1024, H=16, Dh=64, M=128 (2M=256), D_INNER=4096.
//
// R12 = R11 + V ported into the ring gemm256 via TRANSV epilogue (per-wave
// 64x64 quadrant == one head's l x d block; transpose in wave-private LDS,
// write VTg with the same chunk swizzle kv_kernel expects). gemm_vt deleted.
//
// ws (MB): 0 WQT,2 WKT,4 WVT,6 WOT,8 projTs,10 KVacc,14 KVT,16 VTg(->ATTN),
// 64 PH,96 PART,128 X2(->X2B),160 W1T,168 W2T; FFN H = arena 0..128.

#define RS128 0.08838834764831845f

typedef short bf16x8 __attribute__((ext_vector_type(8)));
typedef float f32x4 __attribute__((ext_vector_type(4)));

__device__ __forceinline__ unsigned short f2bf(float f) {
  unsigned int u = __float_as_uint(f);
  u += 0x7fffu + ((u >> 16) & 1u);
  return (unsigned short)(u >> 16);
}
__device__ __forceinline__ float bf2f(unsigned short h) {
  return __uint_as_float(((unsigned int)h) << 16);
}
__device__ __forceinline__ unsigned int pack2f(float a, float b) {
  return (unsigned int)f2bf(a) | ((unsigned int)f2bf(b) << 16);
}
__device__ __forceinline__ void gload_lds16(const void* g, void* l) {
  __builtin_amdgcn_global_load_lds(
      (const __attribute__((address_space(1))) void*)g,
      (__attribute__((address_space(3))) void*)l, 16, 0, 0);
}
__device__ __forceinline__ void barrier_pin() {
  __builtin_amdgcn_sched_barrier(0);
  __builtin_amdgcn_s_barrier();
  __builtin_amdgcn_sched_barrier(0);
}
#define WAIT_VM(N) { asm volatile("s_waitcnt vmcnt(" #N ")" ::: "memory"); __builtin_amdgcn_sched_barrier(0); }
#define WAIT_LGKM0() { asm volatile("s_waitcnt lgkmcnt(0)" ::: "memory"); __builtin_amdgcn_sched_barrier(0); }

// -------- 256x128-tile 8-wave GEMM (R6 ring structure) ----------------------
// 512 thr = 8 waves (4M x 2N), per-wave 64x64 out. LDS: 3 ring bufs x 48KB
// + 16KB projT (PROJ). PROJ: fused per-head fourier projection epilogue.
// TRANSV: fused per-head V-transpose epilogue -> VTg[bh*64+d][4096 l], swz.
template <bool OBF16, bool RELU, bool RES, bool PROJ, bool TRANSV>
__global__ __launch_bounds__(512, 2) void gemm256(
    const unsigned short* __restrict__ A, const unsigned short* __restrict__ Bt,
    void* Cv, const float* __restrict__ bias, const float* res,
    const unsigned short* __restrict__ projTs, int M, int N, int K) {
  __shared__ __align__(16) char lds[163840];
  const int tid = threadIdx.x;
  const int lane = tid & 63, wid = tid >> 6;
  const int e = lane & 15, g = lane >> 4;
  const int wm = wid >> 1, wn = wid & 1;
  const int ntn = N >> 7;
  const int nwg = (int)gridDim.x, cpx = nwg >> 3;
  const int swz = ((int)blockIdx.x & 7) * cpx + ((int)blockIdx.x >> 3);
  const int bm = swz / ntn, bn = swz % ntn;
  const long row0 = (long)bm << 8, col0 = (long)bn << 7;

  const int srow = tid >> 3;
  const int skb = ((tid & 7) << 4) ^ ((srow & 7) << 4);
  const unsigned short* Abase = A + (row0 + srow) * (long)K + (skb >> 1);
  const unsigned short* Bbase = Bt + (col0 + srow) * (long)K + (skb >> 1);
  const int lof = wid << 10;

  f32x4 acc[4][4] = {};
  const int nkt = K >> 6;
  const int rx = (e & 7) << 4;

  char* bufA = lds;
  char* bufB = lds + 49152;
  char* bufC = lds + 98304;

  if (PROJ) {
    // stage projT (16KB, pre-swizzled); issued BEFORE tile loads so the
    // prologue WAIT_VM(6) completes these + bufA, leaves bufB's 6.
    gload_lds16((const char*)projTs + (wid << 10) + (lane << 4),
                lds + 147456 + (wid << 10));
    gload_lds16((const char*)projTs + 8192 + (wid << 10) + (lane << 4),
                lds + 147456 + 8192 + (wid << 10));
  }
#pragma unroll
  for (int c = 0; c < 4; ++c)
    gload_lds16(Abase + (long)c * 64 * K, bufA + lof + c * 8192);
#pragma unroll
  for (int c = 0; c < 2; ++c)
    gload_lds16(Bbase + (long)c * 64 * K, bufA + 32768 + lof + c * 8192);
#pragma unroll
  for (int c = 0; c < 4; ++c)
    gload_lds16(Abase + (long)c * 64 * K + 64, bufB + lof + c * 8192);
#pragma unroll
  for (int c = 0; c < 2; ++c)
    gload_lds16(Bbase + (long)c * 64 * K + 64, bufB + 32768 + lof + c * 8192);
  WAIT_VM(6);
  barrier_pin();

  for (int kt = 0; kt < nkt; ++kt) {
    char* Ac = bufA;
    char* Bc = bufA + 32768;
    const bool pf2 = (kt + 2 < nkt);
    const long kn2 = (long)(kt + 2) << 6;

    // phase 0
    bf16x8 bfr[4][2];
#pragma unroll
    for (int j = 0; j < 4; ++j) {
      const int r = wn * 64 + j * 16 + e;
#pragma unroll
      for (int kh = 0; kh < 2; ++kh)
        bfr[j][kh] = *(const bf16x8*)(Bc + r * 128 + ((g * 16 + kh * 64) ^ rx));
    }
    bf16x8 af0[2][2];
#pragma unroll
    for (int i = 0; i < 2; ++i) {
      const int r = wm * 64 + i * 16 + e;
#pragma unroll
      for (int kh = 0; kh < 2; ++kh)
        af0[i][kh] = *(const bf16x8*)(Ac + r * 128 + ((g * 16 + kh * 64) ^ rx));
    }
    if (pf2) {
#pragma unroll
      for (int c = 0; c < 3; ++c)
        gload_lds16(Abase + (long)c * 64 * K + kn2, bufC + lof + c * 8192);
    }
    barrier_pin();
    WAIT_LGKM0();
    __builtin_amdgcn_s_setprio(1);
#pragma unroll
    for (int i = 0; i < 2; ++i)
#pragma unroll
      for (int j = 0; j < 4; ++j)
#pragma unroll
        for (int kh = 0; kh < 2; ++kh)
          acc[i][j] = __builtin_amdgcn_mfma_f32_16x16x32_bf16(
              af0[i][kh], bfr[j][kh], acc[i][j], 0, 0, 0);
    __builtin_amdgcn_s_setprio(0);
    barrier_pin();

    // phase 1
    bf16x8 af1[2][2];
#pragma unroll
    for (int i = 0; i < 2; ++i) {
      const int r = wm * 64 + (2 + i) * 16 + e;
#pragma unroll
      for (int kh = 0; kh < 2; ++kh)
        af1[i][kh] = *(const bf16x8*)(Ac + r * 128 + ((g * 16 + kh * 64) ^ rx));
    }
    if (pf2) {
      gload_lds16(Abase + (long)3 * 64 * K + kn2, bufC + lof + 3 * 8192);
      gload_lds16(Bbase + kn2, bufC + 32768 + lof);
      gload_lds16(Bbase + (long)64 * K + kn2, bufC + 32768 + lof + 8192);
      WAIT_VM(6);
    } else if (kt + 1 < nkt) {
      WAIT_VM(0);
    }
    barrier_pin();
    WAIT_LGKM0();
    __builtin_amdgcn_s_setprio(1);
#pragma unroll
    for (int i = 0; i < 2; ++i)
#pragma unroll
      for (int j = 0; j < 4; ++j)
#pragma unroll
        for (int kh = 0; kh < 2; ++kh)
          acc[2 + i][j] = __builtin_amdgcn_mfma_f32_16x16x32_bf16(
              af1[i][kh], bfr[j][kh], acc[2 + i][j], 0, 0, 0);
    __builtin_amdgcn_s_setprio(0);
    barrier_pin();

    char* t = bufA; bufA = bufB; bufB = bufC; bufC = t;
  }

  if (PROJ) {
    // ---- fused per-head projection epilogue (head hh = 2*bn+wn) ----
    char* qt = lds + (wid << 13);  // ring is dead after final barrier
    const int c0p = wn * 64 + e;
#pragma unroll
    for (int j = 0; j < 4; ++j) {
      const float bvv = bias[col0 + c0p + (j << 4)];
#pragma unroll
      for (int mf = 0; mf < 4; ++mf)
#pragma unroll
        for (int r = 0; r < 4; ++r) {
          const int lrow = (mf << 4) + (g << 2) + r;
          const int dby = ((((j << 4) + e) << 1)) ^ ((lrow & 7) << 4);
          *(unsigned short*)(qt + lrow * 128 + dby) = f2bf(acc[mf][j][r] + bvv);
        }
    }
    WAIT_LGKM0();
    const char* pj = lds + 147456;
    bf16x8 paf[4][2];
#pragma unroll
    for (int i = 0; i < 4; ++i) {
      const int r = (i << 4) + e;
#pragma unroll
      for (int kh = 0; kh < 2; ++kh)
        paf[i][kh] = *(const bf16x8*)(qt + r * 128 + ((g * 16 + kh * 64) ^ rx));
    }
    f32x4 pacc[4][8] = {};
#pragma unroll
    for (int j = 0; j < 8; ++j) {
      const int m = (j << 4) + e;
      const bf16x8 pb0 = *(const bf16x8*)(pj + m * 128 + ((g * 16) ^ rx));
      const bf16x8 pb1 = *(const bf16x8*)(pj + m * 128 + ((g * 16 + 64) ^ rx));
#pragma unroll
      for (int i = 0; i < 4; ++i) {
        pacc[i][j] = __builtin_amdgcn_mfma_f32_16x16x32_bf16(paf[i][0], pb0,
                                                             pacc[i][j], 0, 0, 0);
        pacc[i][j] = __builtin_amdgcn_mfma_f32_16x16x32_bf16(paf[i][1], pb1,
                                                             pacc[i][j], 0, 0, 0);
      }
    }
    unsigned short* PHp = (unsigned short*)Cv;
    const int hh = 2 * bn + wn;
    const long lbase = row0 + wm * 64;
#pragma unroll
    for (int i = 0; i < 4; ++i)
#pragma unroll
      for (int j = 0; j < 8; ++j)
#pragma unroll
        for (int r = 0; r < 4; ++r) {
          const long l = lbase + (i << 4) + (g << 2) + r;
          PHp[l * 2048 + hh * 128 + (j << 4) + e] = f2bf(pacc[i][j][r]);
        }
    return;
  }

  if (TRANSV) {
    // ---- fused per-head V-transpose epilogue (head hh = 2*bn+wn) ----
    // store wave quadrant to private 8KB as [l][d ^ ((l&7)<<1)] (elements),
    // then lane d writes its 64-l chunk with kv_kernel's (cc8 ^ (d&7)) swz.
    unsigned short* qt = (unsigned short*)(lds + (wid << 13));
#pragma unroll
    for (int j = 0; j < 4; ++j) {
      const int dcol = (j << 4) + e;
      const float bvv = bias[col0 + wn * 64 + dcol];
#pragma unroll
      for (int mf = 0; mf < 4; ++mf)
#pragma unroll
        for (int r = 0; r < 4; ++r) {
          const int lr = (mf << 4) + (g << 2) + r;
          qt[lr * 64 + (dcol ^ ((lr & 7) << 1))] = f2bf(acc[mf][j][r] + bvv);
        }
    }
    WAIT_LGKM0();  // same-wave DS ops are in-order; belt and suspenders
    const int b = (int)(row0 >> 12);
    const int hh = 2 * bn + wn;
    const int lb0 = ((int)(row0 & 4095)) + wm * 64;
    const int d = lane;
    char* basep = (char*)Cv + (((long)(b * 16 + hh) * 64 + d) * 4096 + lb0) * 2;
#pragma unroll
    for (int cc8 = 0; cc8 < 8; ++cc8) {
      unsigned short v[8];
#pragma unroll
      for (int k = 0; k < 8; ++k)
        v[k] = qt[(cc8 * 8 + k) * 64 + (d ^ (k << 1))];
      uint4 o;
      o.x = (unsigned)v[0] | ((unsigned)v[1] << 16);
      o.y = (unsigned)v[2] | ((unsigned)v[3] << 16);
      o.z = (unsigned)v[4] | ((unsigned)v[5] << 16);
      o.w = (unsigned)v[6] | ((unsigned)v[7] << 16);
      *(uint4*)(basep + ((cc8 ^ (d & 7)) << 4)) = o;
    }
    return;
  }

  const int r0 = wm * 64 + (g << 2);
  const int c0 = wn * 64 + e;
#pragma unroll
  for (int j = 0; j < 4; ++j) {
    const long gcol = col0 + c0 + (j << 4);
    const float bvv = bias[gcol];
#pragma unroll
    for (int mf = 0; mf < 4; ++mf) {
#pragma unroll
      for (int r = 0; r < 4; ++r) {
        const long grow = row0 + r0 + (mf << 4) + r;
        float v = acc[mf][j][r] + bvv;
        if (RES) v += res[grow * N + gcol];
        if (RELU) v = fmaxf(v, 0.f);
        if (OBF16) ((unsigned short*)Cv)[grow * N + gcol] = f2bf(v);
        else ((float*)Cv)[grow * N + gcol] = v;
      }
    }
  }
}

// -------- weight transpose + cast: W[K][N] f32 -> Wt[N][K] bf16 --------
__global__ __launch_bounds__(256) void wtrans(const float* __restrict__ W,
                                              unsigned short* __restrict__ Wt,
                                              int K, int N) {
  __shared__ float t[32][33];
  const int tx = threadIdx.x & 31, ty = threadIdx.x >> 5;
  const int n0 = blockIdx.x << 5, k0 = blockIdx.y << 5;
#pragma unroll
  for (int i = 0; i < 32; i += 8)
    t[ty + i][tx] = W[(long)(k0 + ty + i) * N + n0 + tx];
  __syncthreads();
#pragma unroll
  for (int i = 0; i < 32; i += 8)
    Wt[(long)(n0 + ty + i) * K + k0 + tx] = f2bf(t[tx][ty + i]);
}

// -------- projT prep: projTs[m][d] = bf16(proj[d][m]*0.125), pre-swizzled ----
__global__ __launch_bounds__(256) void projt_prep(const float* __restrict__ proj,
                                                  unsigned short* __restrict__ projTs) {
  const int t = threadIdx.x;
  const int m = t >> 1, sh = t & 1;
#pragma unroll
  for (int s4 = 0; s4 < 4; ++s4) {
    const int s = sh * 4 + s4;
    unsigned short v[8];
#pragma unroll
    for (int k = 0; k < 8; ++k)
      v[k] = f2bf(proj[(s * 8 + k) * 128 + m] * 0.125f);
    uint4 o;
    o.x = (unsigned)v[0] | ((unsigned)v[1] << 16);
    o.y = (unsigned)v[2] | ((unsigned)v[3] << 16);
    o.z = (unsigned)v[4] | ((unsigned)v[5] << 16);
    o.w = (unsigned)v[6] | ((unsigned)v[7] << 16);
    *(uint4*)((char*)projTs + m * 128 + ((s ^ (m & 7)) << 4)) = o;
  }
}

// -------- LayerNorm over 1024 cols, f32 in -> bf16 out --------
__global__ __launch_bounds__(256) void ln_kernel(const float* __restrict__ x,
                                                 const float* __restrict__ g,
                                                 const float* __restrict__ b,
                                                 unsigned short* __restrict__ out) {
  const int row = blockIdx.x, tid = threadIdx.x;
  const float* xr = x + (long)row * 1024;
  const float4 xv = *(const float4*)(xr + tid * 4);
  float s = xv.x + xv.y + xv.z + xv.w;
  float s2 = xv.x * xv.x + xv.y * xv.y + xv.z * xv.z + xv.w * xv.w;
#pragma unroll
  for (int off = 32; off > 0; off >>= 1) {
    s += __shfl_down(s, off);
    s2 += __shfl_down(s2, off);
  }
  __shared__ float ps[4], ps2[4];
  if ((tid & 63) == 0) { ps[tid >> 6] = s; ps2[tid >> 6] = s2; }
  __syncthreads();
  const float ts = ps[0] + ps[1] + ps[2] + ps[3];
  const float ts2 = ps2[0] + ps2[1] + ps2[2] + ps2[3];
  const float mu = ts * (1.f / 1024.f);
  const float rstd = rsqrtf(ts2 * (1.f / 1024.f) - mu * mu + 1e-5f);
  const float4 gv = *(const float4*)(g + tid * 4);
  const float4 bv = *(const float4*)(b + tid * 4);
  ushort4 o;
  o.x = f2bf((xv.x - mu) * rstd * gv.x + bv.x);
  o.y = f2bf((xv.y - mu) * rstd * gv.y + bv.y);
  o.z = f2bf((xv.z - mu) * rstd * gv.z + bv.z);
  o.w = f2bf((xv.w - mu) * rstd * gv.w + bv.w);
  *(ushort4*)(out + (long)row * 1024 + tid * 4) = o;
}

// -------- kv kernel: PART[chunk][bhh][d][m] = sum_l vT[d][l]*kp[l][m] --------
__global__ __launch_bounds__(256, 2) void kv_kernel(
    const unsigned short* __restrict__ PH, const unsigned short* __restrict__ VTg,
    float* __restrict__ PART, int half) {
  __shared__ __align__(16) unsigned short Ps[64 * 128];
  __shared__ __align__(16) unsigned short Vs[64 * 64];
  __shared__ __align__(16) unsigned short KPT[256 * 64];
  const int tid = threadIdx.x;
  const int lane = tid & 63, wid = tid >> 6;
  const int bhh = blockIdx.x, chunk = blockIdx.y;
  const int b2 = bhh >> 4, h = bhh & 15;
  const int bh = (half * 2 + b2) * 16 + h;

  f32x4 acc[4][4] = {};
  const int e = lane & 15, g = lane >> 4;
  const int m = tid & 127, isin = tid >> 7;
  const int m2 = (isin << 7) + m, swm = m & 7;

  for (int ti = 0; ti < 4; ++ti) {
    const int l0 = chunk * 256 + ti * 64;
    __syncthreads();
#pragma unroll
    for (int c = 0; c < 4; ++c) {
      const int r = l0 + c * 16 + (tid >> 4);
      gload_lds16((const char*)PH + (long)(b2 * 4096 + r) * 4096 + h * 256 + (tid & 15) * 16,
                  (char*)Ps + c * 4096 + (wid << 10));
    }
#pragma unroll
    for (int c = 0; c < 2; ++c) {
      const int d = c * 32 + (tid >> 3);
      gload_lds16((const char*)VTg + ((long)(bh * 64 + d) * 4096 + l0) * 2 + (tid & 7) * 16,
                  (char*)Vs + c * 4096 + (wid << 10));
    }
    __syncthreads();
    {
      char* krow = (char*)KPT + m2 * 128;
#pragma unroll
      for (int g8 = 0; g8 < 8; ++g8) {
        unsigned pk[4];
#pragma unroll
        for (int k2 = 0; k2 < 4; ++k2) {
          const float p0 = bf2f(Ps[(g8 * 8 + k2 * 2) * 128 + m]);
          const float p1 = bf2f(Ps[(g8 * 8 + k2 * 2 + 1) * 128 + m]);
          const float v0 = (isin ? __sinf(p0) : __cosf(p0)) * RS128;
          const float v1 = (isin ? __sinf(p1) : __cosf(p1)) * RS128;
          pk[k2] = pack2f(v0, v1);
        }
        uint4 o; o.x = pk[0]; o.y = pk[1]; o.z = pk[2]; o.w = pk[3];
        *(uint4*)(krow + ((g8 ^ swm) << 4)) = o;
      }
    }
    __syncthreads();
#pragma unroll
    for (int kk = 0; kk < 2; ++kk) {
      const int ch = (kk << 2) + g;
      bf16x8 af[4], bfr[4];
#pragma unroll
      for (int i = 0; i < 4; ++i) {
        const int dr = (i << 4) + e;
        af[i] = *(const bf16x8*)((char*)Vs + dr * 128 + ((ch ^ (e & 7)) << 4));
      }
#pragma unroll
      for (int j = 0; j < 4; ++j) {
        const int mr = (wid << 6) + (j << 4) + e;
        bfr[j] = *(const bf16x8*)((char*)KPT + mr * 128 + ((ch ^ (e & 7)) << 4));
      }
#pragma unroll
      for (int i = 0; i < 4; ++i)
#pragma unroll
        for (int j = 0; j < 4; ++j)
          acc[i][j] = __builtin_amdgcn_mfma_f32_16x16x32_bf16(af[i], bfr[j],
                                                              acc[i][j], 0, 0, 0);
    }
  }
  float* slice = PART + ((long)chunk * 32 + bhh) * 16384;
#pragma unroll
  for (int i = 0; i < 4; ++i)
#pragma unroll
    for (int j = 0; j < 4; ++j)
#pragma unroll
      for (int r = 0; r < 4; ++r) {
        const int d = (i << 4) + (g << 2) + r;
        const int mc = (wid << 6) + (j << 4) + e;
        slice[d * 256 + mc] = acc[i][j][r];
      }
}

__global__ __launch_bounds__(256) void kv_reduce(const float* __restrict__ PART,
                                                 float* __restrict__ KVacc, int half) {
  const int bhh = blockIdx.x, seg = blockIdx.y;
  const long off = (long)bhh * 16384 + seg * 1024 + threadIdx.x * 4;
  float4 s = make_float4(0.f, 0.f, 0.f, 0.f);
#pragma unroll
  for (int c = 0; c < 16; ++c) {
    const float4 v = *(const float4*)(PART + ((long)c * 32) * 16384 + off);
    s.x += v.x; s.y += v.y; s.z += v.z; s.w += v.w;
  }
  *(float4*)(KVacc + (long)(half * 32) * 16384 + off) = s;
}

__global__ __launch_bounds__(256) void kvt_conv(const float* __restrict__ KVacc,
                                                unsigned short* __restrict__ KVT) {
  const int bh = blockIdx.x, tid = threadIdx.x;
  const int d = tid >> 2, mq = tid & 3;
  const float* src = KVacc + (long)bh * 16384 + d * 256 + mq * 64;
  char* dst = (char*)KVT + bh * 32768 + d * 512;
#pragma unroll
  for (int cc = 0; cc < 8; ++cc) {
    const float4 a = *(const float4*)(src + cc * 8);
    const float4 b = *(const float4*)(src + cc * 8 + 4);
    uint4 o;
    o.x = pack2f(a.x, a.y); o.y = pack2f(a.z, a.w);
    o.z = pack2f(b.x, b.y); o.w = pack2f(b.z, b.w);
    const int chunk = mq * 8 + cc;
    *(uint4*)(dst + ((chunk ^ (d & 7)) << 4)) = o;
  }
}

// -------- attn kernel: ATTN[l][h*64+d] = sum_m qp[l][m]*kvT[d][m] --------
__global__ __launch_bounds__(256, 2) void attn_kernel(
    const unsigned short* __restrict__ PH, const unsigned short* __restrict__ KVT,
    unsigned short* __restrict__ ATTN, int half) {
  __shared__ __align__(16) unsigned short QPs[64 * 256];
  __shared__ __align__(16) unsigned short KVs[64 * 256];
  const int tid = threadIdx.x;
  const int lane = tid & 63, wid = tid >> 6;
  const int bhh = blockIdx.x, chunk = blockIdx.y;
  const int b2 = bhh >> 4, h = bhh & 15;
  const int b = half * 2 + b2, bh = b * 16 + h;
  const int e = lane & 15, g = lane >> 4;

#pragma unroll
  for (int c = 0; c < 8; ++c)
    gload_lds16((const char*)KVT + bh * 32768 + c * 4096 + tid * 16,
                (char*)KVs + c * 4096 + (wid << 10));

  const int lrow = tid >> 2, ms = tid & 3, swl = lrow & 7;

  for (int ti = 0; ti < 4; ++ti) {
    const int l0 = chunk * 256 + ti * 64;
    const char* pg = (const char*)PH + (long)(b2 * 4096 + l0 + lrow) * 4096 + h * 256 + ms * 64;
    uint4 P[4];
#pragma unroll
    for (int q = 0; q < 4; ++q) P[q] = *(const uint4*)(pg + q * 16);
    uint4 CQ[4], SQ[4];
#pragma unroll
    for (int q = 0; q < 4; ++q) {
      const unsigned w[4] = {P[q].x, P[q].y, P[q].z, P[q].w};
      unsigned cw[4], sw[4];
#pragma unroll
      for (int k = 0; k < 4; ++k) {
        float c0, s0, c1, s1;
        __sincosf(bf2f((unsigned short)(w[k] & 0xffff)), &s0, &c0);
        __sincosf(bf2f((unsigned short)(w[k] >> 16)), &s1, &c1);
        cw[k] = pack2f(c0 * RS128, c1 * RS128);
        sw[k] = pack2f(s0 * RS128, s1 * RS128);
      }
      CQ[q].x = cw[0]; CQ[q].y = cw[1]; CQ[q].z = cw[2]; CQ[q].w = cw[3];
      SQ[q].x = sw[0]; SQ[q].y = sw[1]; SQ[q].z = sw[2]; SQ[q].w = sw[3];
    }
    __syncthreads();
    {
      char* qrow = (char*)QPs + lrow * 512;
#pragma unroll
      for (int q = 0; q < 4; ++q) {
        const int c = ms * 4 + q;
        *(uint4*)(qrow + ((c ^ swl) << 4)) = CQ[q];
        *(uint4*)(qrow + ((16 + (c ^ swl)) << 4)) = SQ[q];
      }
    }
    __syncthreads();
    f32x4 acc[4] = {};
    const int lr = (wid << 4) + e;
#pragma unroll
    for (int kk = 0; kk < 8; ++kk) {
      const int ch = (kk << 2) + g;
      const bf16x8 af = *(const bf16x8*)((char*)QPs + lr * 512 + ((ch ^ (e & 7)) << 4));
#pragma unroll
      for (int j = 0; j < 4; ++j) {
        const bf16x8 bfr = *(const bf16x8*)((char*)KVs + ((j << 4) + e) * 512 + ((ch ^ (e & 7)) << 4));
        acc[j] = __builtin_amdgcn_mfma_f32_16x16x32_bf16(af, bfr, acc[j], 0, 0, 0);
      }
    }
#pragma unroll
    for (int j = 0; j < 4; ++j)
#pragma unroll
      for (int r = 0; r < 4; ++r) {
        const int lo = (wid << 4) + (g << 2) + r;
        ATTN[(long)(b * 4096 + l0 + lo) * 1024 + h * 64 + (j << 4) + e] = f2bf(acc[j][r]);
      }
  }
}

extern "C" void kernel_launch(void* const* d_in, const int* in_sizes, int n_in,
                              void* d_out, int out_size, void* d_ws, size_t ws_size,
                              hipStream_t stream) {
  (void)in_sizes; (void)n_in; (void)out_size; (void)ws_size;
  const float* x    = (const float*)d_in[0];
  const float* proj = (const float*)d_in[1];
  const float* wq = (const float*)d_in[2];
  const float* bq = (const float*)d_in[3];
  const float* wk = (const float*)d_in[4];
  const float* bk = (const float*)d_in[5];
  const float* wv = (const float*)d_in[6];
  const float* bv = (const float*)d_in[7];
  const float* wo = (const float*)d_in[8];
  const float* bo = (const float*)d_in[9];
  const float* g1  = (const float*)d_in[10];
  const float* be1 = (const float*)d_in[11];
  const float* w1 = (const float*)d_in[12];
  const float* b1 = (const float*)d_in[13];
  const float* w2 = (const float*)d_in[14];
  const float* b2 = (const float*)d_in[15];
  const float* g2  = (const float*)d_in[16];
  const float* be2 = (const float*)d_in[17];
  float* out = (float*)d_out;

  char* ws = (char*)d_ws;
  const size_t MB = 1u << 20;
  unsigned short* WQT    = (unsigned short*)(ws + 0 * MB);
  unsigned short* WKT    = (unsigned short*)(ws + 2 * MB);
  unsigned short* WVT    = (unsigned short*)(ws + 4 * MB);
  unsigned short* WOT    = (unsigned short*)(ws + 6 * MB);
  unsigned short* projTs = (unsigned short*)(ws + 8 * MB);
  float* KVacc = (float*)(ws + 10 * MB);
  unsigned short* KVT = (unsigned short*)(ws + 14 * MB);
  unsigned short* VTg  = (unsigned short*)(ws + 16 * MB);   // -> ATTN
  unsigned short* PH   = (unsigned short*)(ws + 64 * MB);   // [8192][2048]
  float* PART  = (float*)(ws + 96 * MB);
  unsigned short* Hb  = (unsigned short*)(ws + 0 * MB);     // FFN hidden (128MB)
  unsigned short* X2  = (unsigned short*)(ws + 128 * MB);   // -> X2B
  unsigned short* W1T = (unsigned short*)(ws + 160 * MB);
  unsigned short* W2T = (unsigned short*)(ws + 168 * MB);
  unsigned short* ATTN = VTg;
  unsigned short* X2B  = X2;

  dim3 blk(256), blk5(512);

  // weights prep
  wtrans<<<dim3(32, 32), blk, 0, stream>>>(wq, WQT, 1024, 1024);
  wtrans<<<dim3(32, 32), blk, 0, stream>>>(wk, WKT, 1024, 1024);
  wtrans<<<dim3(32, 32), blk, 0, stream>>>(wv, WVT, 1024, 1024);
  wtrans<<<dim3(32, 32), blk, 0, stream>>>(wo, WOT, 1024, 1024);
  wtrans<<<dim3(128, 32), blk, 0, stream>>>(w1, W1T, 1024, 4096);
  wtrans<<<dim3(32, 128), blk, 0, stream>>>(w2, W2T, 4096, 1024);
  projt_prep<<<1, blk, 0, stream>>>(proj, projTs);

  // LN1
  ln_kernel<<<16384, blk, 0, stream>>>(x, g1, be1, X2);

  // V gemm with fused transpose epilogue -> VTg
  gemm256<false, false, false, false, true><<<512, blk5, 0, stream>>>(
      X2, WVT, VTg, bv, nullptr, nullptr, 16384, 1024, 1024);

  // kv pipeline, two L-halves: K gemm + fused per-head proj -> PH -> kv
  for (int half = 0; half < 2; ++half) {
    gemm256<true, false, false, true, false><<<256, blk5, 0, stream>>>(
        X2 + (long)half * 8192 * 1024, WKT, PH, bk, nullptr, projTs, 8192, 1024, 1024);
    kv_kernel<<<dim3(32, 16), blk, 0, stream>>>(PH, VTg, PART, half);
    kv_reduce<<<dim3(32, 16), blk, 0, stream>>>(PART, KVacc, half);
  }
  kvt_conv<<<64, blk, 0, stream>>>(KVacc, KVT);

  // attn pipeline, two L-halves
  for (int half = 0; half < 2; ++half) {
    gemm256<true, false, false, true, false><<<256, blk5, 0, stream>>>(
        X2 + (long)half * 8192 * 1024, WQT, PH, bq, nullptr, projTs, 8192, 1024, 1024);
    attn_kernel<<<dim3(32, 16), blk, 0, stream>>>(PH, KVT, ATTN, half);
  }

  // Wo + residual -> out (f32)
  gemm256<false, false, true, false, false><<<512, blk5, 0, stream>>>(
      ATTN, WOT, out, bo, x, nullptr, 16384, 1024, 1024);

  // LN2
  ln_kernel<<<16384, blk, 0, stream>>>(out, g2, be2, X2B);

  // FFN (unchunked)
  gemm256<true, true, false, false, false><<<2048, blk5, 0, stream>>>(
      X2B, W1T, Hb, b1, nullptr, nullptr, 16384, 4096, 1024);
  gemm256<false, false, true, false, false><<<512, blk5, 0, stream>>>(
      Hb, W2T, out, b2, out, nullptr, 16384, 1024, 4096);
}

// Round 13
// 613.971 us; speedup vs baseline: 1.4595x; 1.1929x over previous
//
#include <hip/hip_runtime.h>

// EstraNetBlock: pre-norm linear attention (fourier feature kernel) + FFN.
// B=4, L=4096, D=1024, H=16, Dh=64, M=128 (2M=256), D_INNER=4096.
//
// R13 = R12 + FFN in MX-fp8 (e4m3, K=128 mfma_scale at 2x bf16 rate):
// weights pre-scaled x16 (B-scale 2^-4 = e8m0 123), activations scale 1.
// LN2 -> X2B fp8; FFN1 gemm256f8 -> H fp8 (fused relu); FFN2 gemm256f8 ->
// f32 + residual. Same ring/swizzle geometry (128B rows). Rest = R12.
//
// ws (MB): 0 WQT,2 WKT,4 WVT,6 WOT,8 projTs,10 KVacc,14 KVT,16 VTg(->ATTN),
// 64 PH,96 PART,128 X2(->X2B8),160 W1T8(4),164 W2T8(4); FFN H8 = arena 0..64.

#define RS128 0.08838834764831845f

typedef short bf16x8 __attribute__((ext_vector_type(8)));
typedef float f32x4 __attribute__((ext_vector_type(4)));
typedef int i32x4v __attribute__((ext_vector_type(4)));
typedef int i32x8v __attribute__((ext_vector_type(8)));

__device__ __forceinline__ unsigned short f2bf(float f) {
  unsigned int u = __float_as_uint(f);
  u += 0x7fffu + ((u >> 16) & 1u);
  return (unsigned short)(u >> 16);
}
__device__ __forceinline__ float bf2f(unsigned short h) {
  return __uint_as_float(((unsigned int)h) << 16);
}
__device__ __forceinline__ unsigned int pack2f(float a, float b) {
  return (unsigned int)f2bf(a) | ((unsigned int)f2bf(b) << 16);
}
__device__ __forceinline__ void gload_lds16(const void* g, void* l) {
  __builtin_amdgcn_global_load_lds(
      (const __attribute__((address_space(1))) void*)g,
      (__attribute__((address_space(3))) void*)l, 16, 0, 0);
}
__device__ __forceinline__ void barrier_pin() {
  __builtin_amdgcn_sched_barrier(0);
  __builtin_amdgcn_s_barrier();
  __builtin_amdgcn_sched_barrier(0);
}
#define WAIT_VM(N) { asm volatile("s_waitcnt vmcnt(" #N ")" ::: "memory"); __builtin_amdgcn_sched_barrier(0); }
#define WAIT_LGKM0() { asm volatile("s_waitcnt lgkmcnt(0)" ::: "memory"); __builtin_amdgcn_sched_barrier(0); }

__device__ __forceinline__ i32x8v mk8(i32x4v lo, i32x4v hi) {
  i32x8v v;
  v[0] = lo[0]; v[1] = lo[1]; v[2] = lo[2]; v[3] = lo[3];
  v[4] = hi[0]; v[5] = hi[1]; v[6] = hi[2]; v[7] = hi[3];
  return v;
}
__device__ __forceinline__ unsigned int pk4fp8(float a, float b, float c, float d) {
  int p = __builtin_amdgcn_cvt_pk_fp8_f32(a, b, 0, false);
  p = __builtin_amdgcn_cvt_pk_fp8_f32(c, d, p, true);
  return (unsigned int)p;
}

// -------- 256x128-tile 8-wave GEMM (R6 ring structure, bf16) ----------------
template <bool OBF16, bool RELU, bool RES, bool PROJ, bool TRANSV>
__global__ __launch_bounds__(512, 2) void gemm256(
    const unsigned short* __restrict__ A, const unsigned short* __restrict__ Bt,
    void* Cv, const float* __restrict__ bias, const float* res,
    const unsigned short* __restrict__ projTs, int M, int N, int K) {
  __shared__ __align__(16) char lds[163840];
  const int tid = threadIdx.x;
  const int lane = tid & 63, wid = tid >> 6;
  const int e = lane & 15, g = lane >> 4;
  const int wm = wid >> 1, wn = wid & 1;
  const int ntn = N >> 7;
  const int nwg = (int)gridDim.x, cpx = nwg >> 3;
  const int swz = ((int)blockIdx.x & 7) * cpx + ((int)blockIdx.x >> 3);
  const int bm = swz / ntn, bn = swz % ntn;
  const long row0 = (long)bm << 8, col0 = (long)bn << 7;

  const int srow = tid >> 3;
  const int skb = ((tid & 7) << 4) ^ ((srow & 7) << 4);
  const unsigned short* Abase = A + (row0 + srow) * (long)K + (skb >> 1);
  const unsigned short* Bbase = Bt + (col0 + srow) * (long)K + (skb >> 1);
  const int lof = wid << 10;

  f32x4 acc[4][4] = {};
  const int nkt = K >> 6;
  const int rx = (e & 7) << 4;

  char* bufA = lds;
  char* bufB = lds + 49152;
  char* bufC = lds + 98304;

  if (PROJ) {
    gload_lds16((const char*)projTs + (wid << 10) + (lane << 4),
                lds + 147456 + (wid << 10));
    gload_lds16((const char*)projTs + 8192 + (wid << 10) + (lane << 4),
                lds + 147456 + 8192 + (wid << 10));
  }
#pragma unroll
  for (int c = 0; c < 4; ++c)
    gload_lds16(Abase + (long)c * 64 * K, bufA + lof + c * 8192);
#pragma unroll
  for (int c = 0; c < 2; ++c)
    gload_lds16(Bbase + (long)c * 64 * K, bufA + 32768 + lof + c * 8192);
#pragma unroll
  for (int c = 0; c < 4; ++c)
    gload_lds16(Abase + (long)c * 64 * K + 64, bufB + lof + c * 8192);
#pragma unroll
  for (int c = 0; c < 2; ++c)
    gload_lds16(Bbase + (long)c * 64 * K + 64, bufB + 32768 + lof + c * 8192);
  WAIT_VM(6);
  barrier_pin();

  for (int kt = 0; kt < nkt; ++kt) {
    char* Ac = bufA;
    char* Bc = bufA + 32768;
    const bool pf2 = (kt + 2 < nkt);
    const long kn2 = (long)(kt + 2) << 6;

    // phase 0
    bf16x8 bfr[4][2];
#pragma unroll
    for (int j = 0; j < 4; ++j) {
      const int r = wn * 64 + j * 16 + e;
#pragma unroll
      for (int kh = 0; kh < 2; ++kh)
        bfr[j][kh] = *(const bf16x8*)(Bc + r * 128 + ((g * 16 + kh * 64) ^ rx));
    }
    bf16x8 af0[2][2];
#pragma unroll
    for (int i = 0; i < 2; ++i) {
      const int r = wm * 64 + i * 16 + e;
#pragma unroll
      for (int kh = 0; kh < 2; ++kh)
        af0[i][kh] = *(const bf16x8*)(Ac + r * 128 + ((g * 16 + kh * 64) ^ rx));
    }
    if (pf2) {
#pragma unroll
      for (int c = 0; c < 3; ++c)
        gload_lds16(Abase + (long)c * 64 * K + kn2, bufC + lof + c * 8192);
    }
    barrier_pin();
    WAIT_LGKM0();
    __builtin_amdgcn_s_setprio(1);
#pragma unroll
    for (int i = 0; i < 2; ++i)
#pragma unroll
      for (int j = 0; j < 4; ++j)
#pragma unroll
        for (int kh = 0; kh < 2; ++kh)
          acc[i][j] = __builtin_amdgcn_mfma_f32_16x16x32_bf16(
              af0[i][kh], bfr[j][kh], acc[i][j], 0, 0, 0);
    __builtin_amdgcn_s_setprio(0);
    barrier_pin();

    // phase 1
    bf16x8 af1[2][2];
#pragma unroll
    for (int i = 0; i < 2; ++i) {
      const int r = wm * 64 + (2 + i) * 16 + e;
#pragma unroll
      for (int kh = 0; kh < 2; ++kh)
        af1[i][kh] = *(const bf16x8*)(Ac + r * 128 + ((g * 16 + kh * 64) ^ rx));
    }
    if (pf2) {
      gload_lds16(Abase + (long)3 * 64 * K + kn2, bufC + lof + 3 * 8192);
      gload_lds16(Bbase + kn2, bufC + 32768 + lof);
      gload_lds16(Bbase + (long)64 * K + kn2, bufC + 32768 + lof + 8192);
      WAIT_VM(6);
    } else if (kt + 1 < nkt) {
      WAIT_VM(0);
    }
    barrier_pin();
    WAIT_LGKM0();
    __builtin_amdgcn_s_setprio(1);
#pragma unroll
    for (int i = 0; i < 2; ++i)
#pragma unroll
      for (int j = 0; j < 4; ++j)
#pragma unroll
        for (int kh = 0; kh < 2; ++kh)
          acc[2 + i][j] = __builtin_amdgcn_mfma_f32_16x16x32_bf16(
              af1[i][kh], bfr[j][kh], acc[2 + i][j], 0, 0, 0);
    __builtin_amdgcn_s_setprio(0);
    barrier_pin();

    char* t = bufA; bufA = bufB; bufB = bufC; bufC = t;
  }

  if (PROJ) {
    char* qt = lds + (wid << 13);
    const int c0p = wn * 64 + e;
#pragma unroll
    for (int j = 0; j < 4; ++j) {
      const float bvv = bias[col0 + c0p + (j << 4)];
#pragma unroll
      for (int mf = 0; mf < 4; ++mf)
#pragma unroll
        for (int r = 0; r < 4; ++r) {
          const int lrow = (mf << 4) + (g << 2) + r;
          const int dby = ((((j << 4) + e) << 1)) ^ ((lrow & 7) << 4);
          *(unsigned short*)(qt + lrow * 128 + dby) = f2bf(acc[mf][j][r] + bvv);
        }
    }
    WAIT_LGKM0();
    const char* pj = lds + 147456;
    bf16x8 paf[4][2];
#pragma unroll
    for (int i = 0; i < 4; ++i) {
      const int r = (i << 4) + e;
#pragma unroll
      for (int kh = 0; kh < 2; ++kh)
        paf[i][kh] = *(const bf16x8*)(qt + r * 128 + ((g * 16 + kh * 64) ^ rx));
    }
    f32x4 pacc[4][8] = {};
#pragma unroll
    for (int j = 0; j < 8; ++j) {
      const int m = (j << 4) + e;
      const bf16x8 pb0 = *(const bf16x8*)(pj + m * 128 + ((g * 16) ^ rx));
      const bf16x8 pb1 = *(const bf16x8*)(pj + m * 128 + ((g * 16 + 64) ^ rx));
#pragma unroll
      for (int i = 0; i < 4; ++i) {
        pacc[i][j] = __builtin_amdgcn_mfma_f32_16x16x32_bf16(paf[i][0], pb0,
                                                             pacc[i][j], 0, 0, 0);
        pacc[i][j] = __builtin_amdgcn_mfma_f32_16x16x32_bf16(paf[i][1], pb1,
                                                             pacc[i][j], 0, 0, 0);
      }
    }
    unsigned short* PHp = (unsigned short*)Cv;
    const int hh = 2 * bn + wn;
    const long lbase = row0 + wm * 64;
#pragma unroll
    for (int i = 0; i < 4; ++i)
#pragma unroll
      for (int j = 0; j < 8; ++j)
#pragma unroll
        for (int r = 0; r < 4; ++r) {
          const long l = lbase + (i << 4) + (g << 2) + r;
          PHp[l * 2048 + hh * 128 + (j << 4) + e] = f2bf(pacc[i][j][r]);
        }
    return;
  }

  if (TRANSV) {
    unsigned short* qt = (unsigned short*)(lds + (wid << 13));
#pragma unroll
    for (int j = 0; j < 4; ++j) {
      const int dcol = (j << 4) + e;
      const float bvv = bias[col0 + wn * 64 + dcol];
#pragma unroll
      for (int mf = 0; mf < 4; ++mf)
#pragma unroll
        for (int r = 0; r < 4; ++r) {
          const int lr = (mf << 4) + (g << 2) + r;
          qt[lr * 64 + (dcol ^ ((lr & 7) << 1))] = f2bf(acc[mf][j][r] + bvv);
        }
    }
    WAIT_LGKM0();
    const int b = (int)(row0 >> 12);
    const int hh = 2 * bn + wn;
    const int lb0 = ((int)(row0 & 4095)) + wm * 64;
    const int d = lane;
    char* basep = (char*)Cv + (((long)(b * 16 + hh) * 64 + d) * 4096 + lb0) * 2;
#pragma unroll
    for (int cc8 = 0; cc8 < 8; ++cc8) {
      unsigned short v[8];
#pragma unroll
      for (int k = 0; k < 8; ++k)
        v[k] = qt[(cc8 * 8 + k) * 64 + (d ^ (k << 1))];
      uint4 o;
      o.x = (unsigned)v[0] | ((unsigned)v[1] << 16);
      o.y = (unsigned)v[2] | ((unsigned)v[3] << 16);
      o.z = (unsigned)v[4] | ((unsigned)v[5] << 16);
      o.w = (unsigned)v[6] | ((unsigned)v[7] << 16);
      *(uint4*)(basep + ((cc8 ^ (d & 7)) << 4)) = o;
    }
    return;
  }

  const int r0 = wm * 64 + (g << 2);
  const int c0 = wn * 64 + e;
#pragma unroll
  for (int j = 0; j < 4; ++j) {
    const long gcol = col0 + c0 + (j << 4);
    const float bvv = bias[gcol];
#pragma unroll
    for (int mf = 0; mf < 4; ++mf) {
#pragma unroll
      for (int r = 0; r < 4; ++r) {
        const long grow = row0 + r0 + (mf << 4) + r;
        float v = acc[mf][j][r] + bvv;
        if (RES) v += res[grow * N + gcol];
        if (RELU) v = fmaxf(v, 0.f);
        if (OBF16) ((unsigned short*)Cv)[grow * N + gcol] = f2bf(v);
        else ((float*)Cv)[grow * N + gcol] = v;
      }
    }
  }
}

// -------- 256x128-tile 8-wave fp8 GEMM (MX-scaled, K=128/tile) --------------
// Same ring/byte geometry as gemm256 (128B rows). A-scale 1.0 (127); B-scale
// 2^(SB-127) (weights pre-scaled x16 -> SB=123). OFP8: relu + fp8 out.
// Else: f32 out + res.
template <bool OFP8, int SB>
__global__ __launch_bounds__(512, 2) void gemm256f8(
    const char* __restrict__ A, const char* __restrict__ Bt,
    void* Cv, const float* __restrict__ bias, const float* res,
    int M, int N, int K) {
  __shared__ __align__(16) char lds[147456];
  const int tid = threadIdx.x;
  const int lane = tid & 63, wid = tid >> 6;
  const int e = lane & 15, g = lane >> 4;
  const int wm = wid >> 1, wn = wid & 1;
  const int ntn = N >> 7;
  const int nwg = (int)gridDim.x, cpx = nwg >> 3;
  const int swz = ((int)blockIdx.x & 7) * cpx + ((int)blockIdx.x >> 3);
  const int bm = swz / ntn, bn = swz % ntn;
  const long row0 = (long)bm << 8, col0 = (long)bn << 7;

  const int srow = tid >> 3;
  const int skb = ((tid & 7) << 4) ^ ((srow & 7) << 4);
  const char* Abase = A + (row0 + srow) * (long)K + skb;
  const char* Bbase = Bt + (col0 + srow) * (long)K + skb;
  const int lof = wid << 10;

  f32x4 acc[4][4] = {};
  const int nkt = K >> 7;  // 128 fp8 per K-tile = 128B rows
  const int rx = (e & 7) << 4;

  char* bufA = lds;
  char* bufB = lds + 49152;
  char* bufC = lds + 98304;

#pragma unroll
  for (int c = 0; c < 4; ++c)
    gload_lds16(Abase + (long)c * 64 * K, bufA + lof + c * 8192);
#pragma unroll
  for (int c = 0; c < 2; ++c)
    gload_lds16(Bbase + (long)c * 64 * K, bufA + 32768 + lof + c * 8192);
#pragma unroll
  for (int c = 0; c < 4; ++c)
    gload_lds16(Abase + (long)c * 64 * K + 128, bufB + lof + c * 8192);
#pragma unroll
  for (int c = 0; c < 2; ++c)
    gload_lds16(Bbase + (long)c * 64 * K + 128, bufB + 32768 + lof + c * 8192);
  WAIT_VM(6);
  barrier_pin();

  for (int kt = 0; kt < nkt; ++kt) {
    char* Ac = bufA;
    char* Bc = bufA + 32768;
    const bool pf2 = (kt + 2 < nkt);
    const long kn2 = (long)(kt + 2) << 7;

    // phase 0: all B frags + A frags 0,1
    i32x8v bfr[4];
#pragma unroll
    for (int j = 0; j < 4; ++j) {
      const int r = wn * 64 + j * 16 + e;
      const i32x4v lo = *(const i32x4v*)(Bc + r * 128 + ((g * 32) ^ rx));
      const i32x4v hi = *(const i32x4v*)(Bc + r * 128 + ((g * 32 + 16) ^ rx));
      bfr[j] = mk8(lo, hi);
    }
    i32x8v af0[2];
#pragma unroll
    for (int i = 0; i < 2; ++i) {
      const int r = wm * 64 + i * 16 + e;
      const i32x4v lo = *(const i32x4v*)(Ac + r * 128 + ((g * 32) ^ rx));
      const i32x4v hi = *(const i32x4v*)(Ac + r * 128 + ((g * 32 + 16) ^ rx));
      af0[i] = mk8(lo, hi);
    }
    if (pf2) {
#pragma unroll
      for (int c = 0; c < 3; ++c)
        gload_lds16(Abase + (long)c * 64 * K + kn2, bufC + lof + c * 8192);
    }
    barrier_pin();
    WAIT_LGKM0();
    __builtin_amdgcn_s_setprio(1);
#pragma unroll
    for (int i = 0; i < 2; ++i)
#pragma unroll
      for (int j = 0; j < 4; ++j)
        acc[i][j] = __builtin_amdgcn_mfma_scale_f32_16x16x128_f8f6f4(
            af0[i], bfr[j], acc[i][j], 0, 0, 0, 127, 0, SB);
    __builtin_amdgcn_s_setprio(0);
    barrier_pin();

    // phase 1: A frags 2,3
    i32x8v af1[2];
#pragma unroll
    for (int i = 0; i < 2; ++i) {
      const int r = wm * 64 + (2 + i) * 16 + e;
      const i32x4v lo = *(const i32x4v*)(Ac + r * 128 + ((g * 32) ^ rx));
      const i32x4v hi = *(const i32x4v*)(Ac + r * 128 + ((g * 32 + 16) ^ rx));
      af1[i] = mk8(lo, hi);
    }
    if (pf2) {
      gload_lds16(Abase + (long)3 * 64 * K + kn2, bufC + lof + 3 * 8192);
      gload_lds16(Bbase + kn2, bufC + 32768 + lof);
      gload_lds16(Bbase + (long)64 * K + kn2, bufC + 32768 + lof + 8192);
      WAIT_VM(6);
    } else if (kt + 1 < nkt) {
      WAIT_VM(0);
    }
    barrier_pin();
    WAIT_LGKM0();
    __builtin_amdgcn_s_setprio(1);
#pragma unroll
    for (int i = 0; i < 2; ++i)
#pragma unroll
      for (int j = 0; j < 4; ++j)
        acc[2 + i][j] = __builtin_amdgcn_mfma_scale_f32_16x16x128_f8f6f4(
            af1[i], bfr[j], acc[2 + i][j], 0, 0, 0, 127, 0, SB);
    __builtin_amdgcn_s_setprio(0);
    barrier_pin();

    char* t = bufA; bufA = bufB; bufB = bufC; bufC = t;
  }

  const int r0 = wm * 64 + (g << 2);
  const int c0 = wn * 64 + e;
  if (OFP8) {
    unsigned char* O = (unsigned char*)Cv;
#pragma unroll
    for (int j = 0; j < 4; ++j) {
      const long gcol = col0 + c0 + (j << 4);
      const float bvv = bias[gcol];
#pragma unroll
      for (int mf = 0; mf < 4; ++mf)
#pragma unroll
        for (int r = 0; r < 4; ++r) {
          const long grow = row0 + r0 + (mf << 4) + r;
          const float v = fmaxf(acc[mf][j][r] + bvv, 0.f);
          O[grow * (long)N + gcol] =
              (unsigned char)(__builtin_amdgcn_cvt_pk_fp8_f32(v, v, 0, false) & 0xFF);
        }
    }
  } else {
    float* O = (float*)Cv;
#pragma unroll
    for (int j = 0; j < 4; ++j) {
      const long gcol = col0 + c0 + (j << 4);
      const float bvv = bias[gcol];
#pragma unroll
      for (int mf = 0; mf < 4; ++mf)
#pragma unroll
        for (int r = 0; r < 4; ++r) {
          const long grow = row0 + r0 + (mf << 4) + r;
          O[grow * (long)N + gcol] = acc[mf][j][r] + bvv + res[grow * (long)N + gcol];
        }
    }
  }
}

// -------- weight transpose + cast: W[K][N] f32 -> Wt[N][K] bf16 --------
__global__ __launch_bounds__(256) void wtrans(const float* __restrict__ W,
                                              unsigned short* __restrict__ Wt,
                                              int K, int N) {
  __shared__ float t[32][33];
  const int tx = threadIdx.x & 31, ty = threadIdx.x >> 5;
  const int n0 = blockIdx.x << 5, k0 = blockIdx.y << 5;
#pragma unroll
  for (int i = 0; i < 32; i += 8)
    t[ty + i][tx] = W[(long)(k0 + ty + i) * N + n0 + tx];
  __syncthreads();
#pragma unroll
  for (int i = 0; i < 32; i += 8)
    Wt[(long)(n0 + ty + i) * K + k0 + tx] = f2bf(t[tx][ty + i]);
}

// -------- weight transpose + cast to fp8 (x scale): W -> Wt8[N][K] ----------
__global__ __launch_bounds__(256) void wtrans8(const float* __restrict__ W,
                                               unsigned char* __restrict__ Wt,
                                               int K, int N, float scale) {
  __shared__ float t[32][33];
  const int tx = threadIdx.x & 31, ty = threadIdx.x >> 5;
  const int n0 = blockIdx.x << 5, k0 = blockIdx.y << 5;
#pragma unroll
  for (int i = 0; i < 32; i += 8)
    t[ty + i][tx] = W[(long)(k0 + ty + i) * N + n0 + tx];
  __syncthreads();
  const int n = threadIdx.x >> 3, kq = threadIdx.x & 7;
  const unsigned int p = pk4fp8(t[kq * 4 + 0][n] * scale, t[kq * 4 + 1][n] * scale,
                                t[kq * 4 + 2][n] * scale, t[kq * 4 + 3][n] * scale);
  *(unsigned int*)(Wt + (long)(n0 + n) * K + k0 + kq * 4) = p;
}

// -------- projT prep: projTs[m][d] = bf16(proj[d][m]*0.125), pre-swizzled ----
__global__ __launch_bounds__(256) void projt_prep(const float* __restrict__ proj,
                                                  unsigned short* __restrict__ projTs) {
  const int t = threadIdx.x;
  const int m = t >> 1, sh = t & 1;
#pragma unroll
  for (int s4 = 0; s4 < 4; ++s4) {
    const int s = sh * 4 + s4;
    unsigned short v[8];
#pragma unroll
    for (int k = 0; k < 8; ++k)
      v[k] = f2bf(proj[(s * 8 + k) * 128 + m] * 0.125f);
    uint4 o;
    o.x = (unsigned)v[0] | ((unsigned)v[1] << 16);
    o.y = (unsigned)v[2] | ((unsigned)v[3] << 16);
    o.z = (unsigned)v[4] | ((unsigned)v[5] << 16);
    o.w = (unsigned)v[6] | ((unsigned)v[7] << 16);
    *(uint4*)((char*)projTs + m * 128 + ((s ^ (m & 7)) << 4)) = o;
  }
}

// -------- LayerNorm over 1024 cols, f32 in -> bf16 out --------
__global__ __launch_bounds__(256) void ln_kernel(const float* __restrict__ x,
                                                 const float* __restrict__ g,
                                                 const float* __restrict__ b,
                                                 unsigned short* __restrict__ out) {
  const int row = blockIdx.x, tid = threadIdx.x;
  const float* xr = x + (long)row * 1024;
  const float4 xv = *(const float4*)(xr + tid * 4);
  float s = xv.x + xv.y + xv.z + xv.w;
  float s2 = xv.x * xv.x + xv.y * xv.y + xv.z * xv.z + xv.w * xv.w;
#pragma unroll
  for (int off = 32; off > 0; off >>= 1) {
    s += __shfl_down(s, off);
    s2 += __shfl_down(s2, off);
  }
  __shared__ float ps[4], ps2[4];
  if ((tid & 63) == 0) { ps[tid >> 6] = s; ps2[tid >> 6] = s2; }
  __syncthreads();
  const float ts = ps[0] + ps[1] + ps[2] + ps[3];
  const float ts2 = ps2[0] + ps2[1] + ps2[2] + ps2[3];
  const float mu = ts * (1.f / 1024.f);
  const float rstd = rsqrtf(ts2 * (1.f / 1024.f) - mu * mu + 1e-5f);
  const float4 gv = *(const float4*)(g + tid * 4);
  const float4 bv = *(const float4*)(b + tid * 4);
  ushort4 o;
  o.x = f2bf((xv.x - mu) * rstd * gv.x + bv.x);
  o.y = f2bf((xv.y - mu) * rstd * gv.y + bv.y);
  o.z = f2bf((xv.z - mu) * rstd * gv.z + bv.z);
  o.w = f2bf((xv.w - mu) * rstd * gv.w + bv.w);
  *(ushort4*)(out + (long)row * 1024 + tid * 4) = o;
}

// -------- LayerNorm -> fp8 out (for FFN path) --------
__global__ __launch_bounds__(256) void ln_kernel8(const float* __restrict__ x,
                                                  const float* __restrict__ g,
                                                  const float* __restrict__ b,
                                                  unsigned char* __restrict__ out) {
  const int row = blockIdx.x, tid = threadIdx.x;
  const float* xr = x + (long)row * 1024;
  const float4 xv = *(const float4*)(xr + tid * 4);
  float s = xv.x + xv.y + xv.z + xv.w;
  float s2 = xv.x * xv.x + xv.y * xv.y + xv.z * xv.z + xv.w * xv.w;
#pragma unroll
  for (int off = 32; off > 0; off >>= 1) {
    s += __shfl_down(s, off);
    s2 += __shfl_down(s2, off);
  }
  __shared__ float ps[4], ps2[4];
  if ((tid & 63) == 0) { ps[tid >> 6] = s; ps2[tid >> 6] = s2; }
  __syncthreads();
  const float ts = ps[0] + ps[1] + ps[2] + ps[3];
  const float ts2 = ps2[0] + ps2[1] + ps2[2] + ps2[3];
  const float mu = ts * (1.f / 1024.f);
  const float rstd = rsqrtf(ts2 * (1.f / 1024.f) - mu * mu + 1e-5f);
  const float4 gv = *(const float4*)(g + tid * 4);
  const float4 bv = *(const float4*)(b + tid * 4);
  const unsigned int p = pk4fp8((xv.x - mu) * rstd * gv.x + bv.x,
                                (xv.y - mu) * rstd * gv.y + bv.y,
                                (xv.z - mu) * rstd * gv.z + bv.z,
                                (xv.w - mu) * rstd * gv.w + bv.w);
  *(unsigned int*)(out + (long)row * 1024 + tid * 4) = p;
}

// -------- kv kernel --------
__global__ __launch_bounds__(256, 2) void kv_kernel(
    const unsigned short* __restrict__ PH, const unsigned short* __restrict__ VTg,
    float* __restrict__ PART, int half) {
  __shared__ __align__(16) unsigned short Ps[64 * 128];
  __shared__ __align__(16) unsigned short Vs[64 * 64];
  __shared__ __align__(16) unsigned short KPT[256 * 64];
  const int tid = threadIdx.x;
  const int lane = tid & 63, wid = tid >> 6;
  const int bhh = blockIdx.x, chunk = blockIdx.y;
  const int b2 = bhh >> 4, h = bhh & 15;
  const int bh = (half * 2 + b2) * 16 + h;

  f32x4 acc[4][4] = {};
  const int e = lane & 15, g = lane >> 4;
  const int m = tid & 127, isin = tid >> 7;
  const int m2 = (isin << 7) + m, swm = m & 7;

  for (int ti = 0; ti < 4; ++ti) {
    const int l0 = chunk * 256 + ti * 64;
    __syncthreads();
#pragma unroll
    for (int c = 0; c < 4; ++c) {
      const int r = l0 + c * 16 + (tid >> 4);
      gload_lds16((const char*)PH + (long)(b2 * 4096 + r) * 4096 + h * 256 + (tid & 15) * 16,
                  (char*)Ps + c * 4096 + (wid << 10));
    }
#pragma unroll
    for (int c = 0; c < 2; ++c) {
      const int d = c * 32 + (tid >> 3);
      gload_lds16((const char*)VTg + ((long)(bh * 64 + d) * 4096 + l0) * 2 + (tid & 7) * 16,
                  (char*)Vs + c * 4096 + (wid << 10));
    }
    __syncthreads();
    {
      char* krow = (char*)KPT + m2 * 128;
#pragma unroll
      for (int g8 = 0; g8 < 8; ++g8) {
        unsigned pk[4];
#pragma unroll
        for (int k2 = 0; k2 < 4; ++k2) {
          const float p0 = bf2f(Ps[(g8 * 8 + k2 * 2) * 128 + m]);
          const float p1 = bf2f(Ps[(g8 * 8 + k2 * 2 + 1) * 128 + m]);
          const float v0 = (isin ? __sinf(p0) : __cosf(p0)) * RS128;
          const float v1 = (isin ? __sinf(p1) : __cosf(p1)) * RS128;
          pk[k2] = pack2f(v0, v1);
        }
        uint4 o; o.x = pk[0]; o.y = pk[1]; o.z = pk[2]; o.w = pk[3];
        *(uint4*)(krow + ((g8 ^ swm) << 4)) = o;
      }
    }
    __syncthreads();
#pragma unroll
    for (int kk = 0; kk < 2; ++kk) {
      const int ch = (kk << 2) + g;
      bf16x8 af[4], bfr[4];
#pragma unroll
      for (int i = 0; i < 4; ++i) {
        const int dr = (i << 4) + e;
        af[i] = *(const bf16x8*)((char*)Vs + dr * 128 + ((ch ^ (e & 7)) << 4));
      }
#pragma unroll
      for (int j = 0; j < 4; ++j) {
        const int mr = (wid << 6) + (j << 4) + e;
        bfr[j] = *(const bf16x8*)((char*)KPT + mr * 128 + ((ch ^ (e & 7)) << 4));
      }
#pragma unroll
      for (int i = 0; i < 4; ++i)
#pragma unroll
        for (int j = 0; j < 4; ++j)
          acc[i][j] = __builtin_amdgcn_mfma_f32_16x16x32_bf16(af[i], bfr[j],
                                                              acc[i][j], 0, 0, 0);
    }
  }
  float* slice = PART + ((long)chunk * 32 + bhh) * 16384;
#pragma unroll
  for (int i = 0; i < 4; ++i)
#pragma unroll
    for (int j = 0; j < 4; ++j)
#pragma unroll
      for (int r = 0; r < 4; ++r) {
        const int d = (i << 4) + (g << 2) + r;
        const int mc = (wid << 6) + (j << 4) + e;
        slice[d * 256 + mc] = acc[i][j][r];
      }
}

__global__ __launch_bounds__(256) void kv_reduce(const float* __restrict__ PART,
                                                 float* __restrict__ KVacc, int half) {
  const int bhh = blockIdx.x, seg = blockIdx.y;
  const long off = (long)bhh * 16384 + seg * 1024 + threadIdx.x * 4;
  float4 s = make_float4(0.f, 0.f, 0.f, 0.f);
#pragma unroll
  for (int c = 0; c < 16; ++c) {
    const float4 v = *(const float4*)(PART + ((long)c * 32) * 16384 + off);
    s.x += v.x; s.y += v.y; s.z += v.z; s.w += v.w;
  }
  *(float4*)(KVacc + (long)(half * 32) * 16384 + off) = s;
}

__global__ __launch_bounds__(256) void kvt_conv(const float* __restrict__ KVacc,
                                                unsigned short* __restrict__ KVT) {
  const int bh = blockIdx.x, tid = threadIdx.x;
  const int d = tid >> 2, mq = tid & 3;
  const float* src = KVacc + (long)bh * 16384 + d * 256 + mq * 64;
  char* dst = (char*)KVT + bh * 32768 + d * 512;
#pragma unroll
  for (int cc = 0; cc < 8; ++cc) {
    const float4 a = *(const float4*)(src + cc * 8);
    const float4 b = *(const float4*)(src + cc * 8 + 4);
    uint4 o;
    o.x = pack2f(a.x, a.y); o.y = pack2f(a.z, a.w);
    o.z = pack2f(b.x, b.y); o.w = pack2f(b.z, b.w);
    const int chunk = mq * 8 + cc;
    *(uint4*)(dst + ((chunk ^ (d & 7)) << 4)) = o;
  }
}

// -------- attn kernel --------
__global__ __launch_bounds__(256, 2) void attn_kernel(
    const unsigned short* __restrict__ PH, const unsigned short* __restrict__ KVT,
    unsigned short* __restrict__ ATTN, int half) {
  __shared__ __align__(16) unsigned short QPs[64 * 256];
  __shared__ __align__(16) unsigned short KVs[64 * 256];
  const int tid = threadIdx.x;
  const int lane = tid & 63, wid = tid >> 6;
  const int bhh = blockIdx.x, chunk = blockIdx.y;
  const int b2 = bhh >> 4, h = bhh & 15;
  const int b = half * 2 + b2, bh = b * 16 + h;
  const int e = lane & 15, g = lane >> 4;

#pragma unroll
  for (int c = 0; c < 8; ++c)
    gload_lds16((const char*)KVT + bh * 32768 + c * 4096 + tid * 16,
                (char*)KVs + c * 4096 + (wid << 10));

  const int lrow = tid >> 2, ms = tid & 3, swl = lrow & 7;

  for (int ti = 0; ti < 4; ++ti) {
    const int l0 = chunk * 256 + ti * 64;
    const char* pg = (const char*)PH + (long)(b2 * 4096 + l0 + lrow) * 4096 + h * 256 + ms * 64;
    uint4 P[4];
#pragma unroll
    for (int q = 0; q < 4; ++q) P[q] = *(const uint4*)(pg + q * 16);
    uint4 CQ[4], SQ[4];
#pragma unroll
    for (int q = 0; q < 4; ++q) {
      const unsigned w[4] = {P[q].x, P[q].y, P[q].z, P[q].w};
      unsigned cw[4], sw[4];
#pragma unroll
      for (int k = 0; k < 4; ++k) {
        float c0, s0, c1, s1;
        __sincosf(bf2f((unsigned short)(w[k] & 0xffff)), &s0, &c0);
        __sincosf(bf2f((unsigned short)(w[k] >> 16)), &s1, &c1);
        cw[k] = pack2f(c0 * RS128, c1 * RS128);
        sw[k] = pack2f(s0 * RS128, s1 * RS128);
      }
      CQ[q].x = cw[0]; CQ[q].y = cw[1]; CQ[q].z = cw[2]; CQ[q].w = cw[3];
      SQ[q].x = sw[0]; SQ[q].y = sw[1]; SQ[q].z = sw[2]; SQ[q].w = sw[3];
    }
    __syncthreads();
    {
      char* qrow = (char*)QPs + lrow * 512;
#pragma unroll
      for (int q = 0; q < 4; ++q) {
        const int c = ms * 4 + q;
        *(uint4*)(qrow + ((c ^ swl) << 4)) = CQ[q];
        *(uint4*)(qrow + ((16 + (c ^ swl)) << 4)) = SQ[q];
      }
    }
    __syncthreads();
    f32x4 acc[4] = {};
    const int lr = (wid << 4) + e;
#pragma unroll
    for (int kk = 0; kk < 8; ++kk) {
      const int ch = (kk << 2) + g;
      const bf16x8 af = *(const bf16x8*)((char*)QPs + lr * 512 + ((ch ^ (e & 7)) << 4));
#pragma unroll
      for (int j = 0; j < 4; ++j) {
        const bf16x8 bfr = *(const bf16x8*)((char*)KVs + ((j << 4) + e) * 512 + ((ch ^ (e & 7)) << 4));
        acc[j] = __builtin_amdgcn_mfma_f32_16x16x32_bf16(af, bfr, acc[j], 0, 0, 0);
      }
    }
#pragma unroll
    for (int j = 0; j < 4; ++j)
#pragma unroll
      for (int r = 0; r < 4; ++r) {
        const int lo = (wid << 4) + (g << 2) + r;
        ATTN[(long)(b * 4096 + l0 + lo) * 1024 + h * 64 + (j << 4) + e] = f2bf(acc[j][r]);
      }
  }
}

extern "C" void kernel_launch(void* const* d_in, const int* in_sizes, int n_in,
                              void* d_out, int out_size, void* d_ws, size_t ws_size,
                              hipStream_t stream) {
  (void)in_sizes; (void)n_in; (void)out_size; (void)ws_size;
  const float* x    = (const float*)d_in[0];
  const float* proj = (const float*)d_in[1];
  const float* wq = (const float*)d_in[2];
  const float* bq = (const float*)d_in[3];
  const float* wk = (const float*)d_in[4];
  const float* bk = (const float*)d_in[5];
  const float* wv = (const float*)d_in[6];
  const float* bv = (const float*)d_in[7];
  const float* wo = (const float*)d_in[8];
  const float* bo = (const float*)d_in[9];
  const float* g1  = (const float*)d_in[10];
  const float* be1 = (const float*)d_in[11];
  const float* w1 = (const float*)d_in[12];
  const float* b1 = (const float*)d_in[13];
  const float* w2 = (const float*)d_in[14];
  const float* b2 = (const float*)d_in[15];
  const float* g2  = (const float*)d_in[16];
  const float* be2 = (const float*)d_in[17];
  float* out = (float*)d_out;

  char* ws = (char*)d_ws;
  const size_t MB = 1u << 20;
  unsigned short* WQT    = (unsigned short*)(ws + 0 * MB);
  unsigned short* WKT    = (unsigned short*)(ws + 2 * MB);
  unsigned short* WVT    = (unsigned short*)(ws + 4 * MB);
  unsigned short* WOT    = (unsigned short*)(ws + 6 * MB);
  unsigned short* projTs = (unsigned short*)(ws + 8 * MB);
  float* KVacc = (float*)(ws + 10 * MB);
  unsigned short* KVT = (unsigned short*)(ws + 14 * MB);
  unsigned short* VTg  = (unsigned short*)(ws + 16 * MB);   // -> ATTN
  unsigned short* PH   = (unsigned short*)(ws + 64 * MB);   // [8192][2048]
  float* PART  = (float*)(ws + 96 * MB);
  unsigned char* Hb8   = (unsigned char*)(ws + 0 * MB);     // FFN hidden fp8 (64MB)
  unsigned short* X2   = (unsigned short*)(ws + 128 * MB);  // -> X2B8
  unsigned char* X2B8  = (unsigned char*)(ws + 128 * MB);
  unsigned char* W1T8  = (unsigned char*)(ws + 160 * MB);   // 4MB
  unsigned char* W2T8  = (unsigned char*)(ws + 164 * MB);   // 4MB
  unsigned short* ATTN = VTg;

  dim3 blk(256), blk5(512);

  // weights prep
  wtrans<<<dim3(32, 32), blk, 0, stream>>>(wq, WQT, 1024, 1024);
  wtrans<<<dim3(32, 32), blk, 0, stream>>>(wk, WKT, 1024, 1024);
  wtrans<<<dim3(32, 32), blk, 0, stream>>>(wv, WVT, 1024, 1024);
  wtrans<<<dim3(32, 32), blk, 0, stream>>>(wo, WOT, 1024, 1024);
  wtrans8<<<dim3(128, 32), blk, 0, stream>>>(w1, W1T8, 1024, 4096, 16.f);
  wtrans8<<<dim3(32, 128), blk, 0, stream>>>(w2, W2T8, 4096, 1024, 16.f);
  projt_prep<<<1, blk, 0, stream>>>(proj, projTs);

  // LN1
  ln_kernel<<<16384, blk, 0, stream>>>(x, g1, be1, X2);

  // V gemm with fused transpose epilogue -> VTg
  gemm256<false, false, false, false, true><<<512, blk5, 0, stream>>>(
      X2, WVT, VTg, bv, nullptr, nullptr, 16384, 1024, 1024);

  // kv pipeline, two L-halves: K gemm + fused per-head proj -> PH -> kv
  for (int half = 0; half < 2; ++half) {
    gemm256<true, false, false, true, false><<<256, blk5, 0, stream>>>(
        X2 + (long)half * 8192 * 1024, WKT, PH, bk, nullptr, projTs, 8192, 1024, 1024);
    kv_kernel<<<dim3(32, 16), blk, 0, stream>>>(PH, VTg, PART, half);
    kv_reduce<<<dim3(32, 16), blk, 0, stream>>>(PART, KVacc, half);
  }
  kvt_conv<<<64, blk, 0, stream>>>(KVacc, KVT);

  // attn pipeline, two L-halves
  for (int half = 0; half < 2; ++half) {
    gemm256<true, false, false, true, false><<<256, blk5, 0, stream>>>(
        X2 + (long)half * 8192 * 1024, WQT, PH, bq, nullptr, projTs, 8192, 1024, 1024);
    attn_kernel<<<dim3(32, 16), blk, 0, stream>>>(PH, KVT, ATTN, half);
  }

  // Wo + residual -> out (f32)
  gemm256<false, false, true, false, false><<<512, blk5, 0, stream>>>(
      ATTN, WOT, out, bo, x, nullptr, 16384, 1024, 1024);

  // LN2 -> fp8 (X2 region dead)
  ln_kernel8<<<16384, blk, 0, stream>>>(out, g2, be2, X2B8);

  // FFN in MX-fp8 (weights x16 -> B-scale e8m0=123 == 2^-4)
  gemm256f8<true, 123><<<2048, blk5, 0, stream>>>(
      (const char*)X2B8, (const char*)W1T8, Hb8, b1, nullptr, 16384, 4096, 1024);
  gemm256f8<false, 123><<<512, blk5, 0, stream>>>(
      (const char*)Hb8, (const char*)W2T8, out, b2, out, 16384, 1024, 4096);
}

// Round 16
// 595.169 us; speedup vs baseline: 1.5056x; 1.0316x over previous
//
#include <hip/hip_runtime.h>

// EstraNetBlock: pre-norm linear attention (fourier feature kernel) + FFN.
// B=4, L=4096, D=1024, H=16, Dh=64, M=128 (2M=256), D_INNER=4096.
//
// R16 = R13 (best passing: fp8 ONLY in FFN; attention content path bf16 —
// R14/R15 showed fp8 on attn/Wo fails absmax) + fp8 LDS de-conflict: k-chunk
// slot permutation c(s)=s<4?2s:2s-7 baked into staging source so fp8 reads
// use the bf16 kernel's measured-zero-conflict offsets (g*16+kh*64)^rx.
//
// ws (MB): 0 WQT,2 WKT,4 WVT,6 WOT,8 projTs,10 KVacc,14 KVT,16 VTg(->ATTN),
// 64 PH,96 PART,128 X2(->X2B8),160 W1T8(4),164 W2T8(4); FFN H8 = arena 0..64.

#define RS128 0.08838834764831845f

typedef short bf16x8 __attribute__((ext_vector_type(8)));
typedef float f32x4 __attribute__((ext_vector_type(4)));
typedef int i32x4v __attribute__((ext_vector_type(4)));
typedef int i32x8v __attribute__((ext_vector_type(8)));

__device__ __forceinline__ unsigned short f2bf(float f) {
  unsigned int u = __float_as_uint(f);
  u += 0x7fffu + ((u >> 16) & 1u);
  return (unsigned short)(u >> 16);
}
__device__ __forceinline__ float bf2f(unsigned short h) {
  return __uint_as_float(((unsigned int)h) << 16);
}
__device__ __forceinline__ unsigned int pack2f(float a, float b) {
  return (unsigned int)f2bf(a) | ((unsigned int)f2bf(b) << 16);
}
__device__ __forceinline__ void gload_lds16(const void* g, void* l) {
  __builtin_amdgcn_global_load_lds(
      (const __attribute__((address_space(1))) void*)g,
      (__attribute__((address_space(3))) void*)l, 16, 0, 0);
}
__device__ __forceinline__ void barrier_pin() {
  __builtin_amdgcn_sched_barrier(0);
  __builtin_amdgcn_s_barrier();
  __builtin_amdgcn_sched_barrier(0);
}
#define WAIT_VM(N) { asm volatile("s_waitcnt vmcnt(" #N ")" ::: "memory"); __builtin_amdgcn_sched_barrier(0); }
#define WAIT_LGKM0() { asm volatile("s_waitcnt lgkmcnt(0)" ::: "memory"); __builtin_amdgcn_sched_barrier(0); }

__device__ __forceinline__ i32x8v mk8(i32x4v lo, i32x4v hi) {
  i32x8v v;
  v[0] = lo[0]; v[1] = lo[1]; v[2] = lo[2]; v[3] = lo[3];
  v[4] = hi[0]; v[5] = hi[1]; v[6] = hi[2]; v[7] = hi[3];
  return v;
}
__device__ __forceinline__ unsigned int pk4fp8(float a, float b, float c, float d) {
  int p = __builtin_amdgcn_cvt_pk_fp8_f32(a, b, 0, false);
  p = __builtin_amdgcn_cvt_pk_fp8_f32(c, d, p, true);
  return (unsigned int)p;
}

// -------- 256x128-tile 8-wave GEMM (R6 ring structure, bf16) ----------------
template <bool OBF16, bool RELU, bool RES, bool PROJ, bool TRANSV>
__global__ __launch_bounds__(512, 2) void gemm256(
    const unsigned short* __restrict__ A, const unsigned short* __restrict__ Bt,
    void* Cv, const float* __restrict__ bias, const float* res,
    const unsigned short* __restrict__ projTs, int M, int N, int K) {
  __shared__ __align__(16) char lds[163840];
  const int tid = threadIdx.x;
  const int lane = tid & 63, wid = tid >> 6;
  const int e = lane & 15, g = lane >> 4;
  const int wm = wid >> 1, wn = wid & 1;
  const int ntn = N >> 7;
  const int nwg = (int)gridDim.x, cpx = nwg >> 3;
  const int swz = ((int)blockIdx.x & 7) * cpx + ((int)blockIdx.x >> 3);
  const int bm = swz / ntn, bn = swz % ntn;
  const long row0 = (long)bm << 8, col0 = (long)bn << 7;

  const int srow = tid >> 3;
  const int skb = ((tid & 7) << 4) ^ ((srow & 7) << 4);
  const unsigned short* Abase = A + (row0 + srow) * (long)K + (skb >> 1);
  const unsigned short* Bbase = Bt + (col0 + srow) * (long)K + (skb >> 1);
  const int lof = wid << 10;

  f32x4 acc[4][4] = {};
  const int nkt = K >> 6;
  const int rx = (e & 7) << 4;

  char* bufA = lds;
  char* bufB = lds + 49152;
  char* bufC = lds + 98304;

  if (PROJ) {
    gload_lds16((const char*)projTs + (wid << 10) + (lane << 4),
                lds + 147456 + (wid << 10));
    gload_lds16((const char*)projTs + 8192 + (wid << 10) + (lane << 4),
                lds + 147456 + 8192 + (wid << 10));
  }
#pragma unroll
  for (int c = 0; c < 4; ++c)
    gload_lds16(Abase + (long)c * 64 * K, bufA + lof + c * 8192);
#pragma unroll
  for (int c = 0; c < 2; ++c)
    gload_lds16(Bbase + (long)c * 64 * K, bufA + 32768 + lof + c * 8192);
#pragma unroll
  for (int c = 0; c < 4; ++c)
    gload_lds16(Abase + (long)c * 64 * K + 64, bufB + lof + c * 8192);
#pragma unroll
  for (int c = 0; c < 2; ++c)
    gload_lds16(Bbase + (long)c * 64 * K + 64, bufB + 32768 + lof + c * 8192);
  WAIT_VM(6);
  barrier_pin();

  for (int kt = 0; kt < nkt; ++kt) {
    char* Ac = bufA;
    char* Bc = bufA + 32768;
    const bool pf2 = (kt + 2 < nkt);
    const long kn2 = (long)(kt + 2) << 6;

    // phase 0
    bf16x8 bfr[4][2];
#pragma unroll
    for (int j = 0; j < 4; ++j) {
      const int r = wn * 64 + j * 16 + e;
#pragma unroll
      for (int kh = 0; kh < 2; ++kh)
        bfr[j][kh] = *(const bf16x8*)(Bc + r * 128 + ((g * 16 + kh * 64) ^ rx));
    }
    bf16x8 af0[2][2];
#pragma unroll
    for (int i = 0; i < 2; ++i) {
      const int r = wm * 64 + i * 16 + e;
#pragma unroll
      for (int kh = 0; kh < 2; ++kh)
        af0[i][kh] = *(const bf16x8*)(Ac + r * 128 + ((g * 16 + kh * 64) ^ rx));
    }
    if (pf2) {
#pragma unroll
      for (int c = 0; c < 3; ++c)
        gload_lds16(Abase + (long)c * 64 * K + kn2, bufC + lof + c * 8192);
    }
    barrier_pin();
    WAIT_LGKM0();
    __builtin_amdgcn_s_setprio(1);
#pragma unroll
    for (int i = 0; i < 2; ++i)
#pragma unroll
      for (int j = 0; j < 4; ++j)
#pragma unroll
        for (int kh = 0; kh < 2; ++kh)
          acc[i][j] = __builtin_amdgcn_mfma_f32_16x16x32_bf16(
              af0[i][kh], bfr[j][kh], acc[i][j], 0, 0, 0);
    __builtin_amdgcn_s_setprio(0);
    barrier_pin();

    // phase 1
    bf16x8 af1[2][2];
#pragma unroll
    for (int i = 0; i < 2; ++i) {
      const int r = wm * 64 + (2 + i) * 16 + e;
#pragma unroll
      for (int kh = 0; kh < 2; ++kh)
        af1[i][kh] = *(const bf16x8*)(Ac + r * 128 + ((g * 16 + kh * 64) ^ rx));
    }
    if (pf2) {
      gload_lds16(Abase + (long)3 * 64 * K + kn2, bufC + lof + 3 * 8192);
      gload_lds16(Bbase + kn2, bufC + 32768 + lof);
      gload_lds16(Bbase + (long)64 * K + kn2, bufC + 32768 + lof + 8192);
      WAIT_VM(6);
    } else if (kt + 1 < nkt) {
      WAIT_VM(0);
    }
    barrier_pin();
    WAIT_LGKM0();
    __builtin_amdgcn_s_setprio(1);
#pragma unroll
    for (int i = 0; i < 2; ++i)
#pragma unroll
      for (int j = 0; j < 4; ++j)
#pragma unroll
        for (int kh = 0; kh < 2; ++kh)
          acc[2 + i][j] = __builtin_amdgcn_mfma_f32_16x16x32_bf16(
              af1[i][kh], bfr[j][kh], acc[2 + i][j], 0, 0, 0);
    __builtin_amdgcn_s_setprio(0);
    barrier_pin();

    char* t = bufA; bufA = bufB; bufB = bufC; bufC = t;
  }

  if (PROJ) {
    char* qt = lds + (wid << 13);
    const int c0p = wn * 64 + e;
#pragma unroll
    for (int j = 0; j < 4; ++j) {
      const float bvv = bias[col0 + c0p + (j << 4)];
#pragma unroll
      for (int mf = 0; mf < 4; ++mf)
#pragma unroll
        for (int r = 0; r < 4; ++r) {
          const int lrow = (mf << 4) + (g << 2) + r;
          const int dby = ((((j << 4) + e) << 1)) ^ ((lrow & 7) << 4);
          *(unsigned short*)(qt + lrow * 128 + dby) = f2bf(acc[mf][j][r] + bvv);
        }
    }
    WAIT_LGKM0();
    const char* pj = lds + 147456;
    bf16x8 paf[4][2];
#pragma unroll
    for (int i = 0; i < 4; ++i) {
      const int r = (i << 4) + e;
#pragma unroll
      for (int kh = 0; kh < 2; ++kh)
        paf[i][kh] = *(const bf16x8*)(qt + r * 128 + ((g * 16 + kh * 64) ^ rx));
    }
    f32x4 pacc[4][8] = {};
#pragma unroll
    for (int j = 0; j < 8; ++j) {
      const int m = (j << 4) + e;
      const bf16x8 pb0 = *(const bf16x8*)(pj + m * 128 + ((g * 16) ^ rx));
      const bf16x8 pb1 = *(const bf16x8*)(pj + m * 128 + ((g * 16 + 64) ^ rx));
#pragma unroll
      for (int i = 0; i < 4; ++i) {
        pacc[i][j] = __builtin_amdgcn_mfma_f32_16x16x32_bf16(paf[i][0], pb0,
                                                             pacc[i][j], 0, 0, 0);
        pacc[i][j] = __builtin_amdgcn_mfma_f32_16x16x32_bf16(paf[i][1], pb1,
                                                             pacc[i][j], 0, 0, 0);
      }
    }
    unsigned short* PHp = (unsigned short*)Cv;
    const int hh = 2 * bn + wn;
    const long lbase = row0 + wm * 64;
#pragma unroll
    for (int i = 0; i < 4; ++i)
#pragma unroll
      for (int j = 0; j < 8; ++j)
#pragma unroll
        for (int r = 0; r < 4; ++r) {
          const long l = lbase + (i << 4) + (g << 2) + r;
          PHp[l * 2048 + hh * 128 + (j << 4) + e] = f2bf(pacc[i][j][r]);
        }
    return;
  }

  if (TRANSV) {
    unsigned short* qt = (unsigned short*)(lds + (wid << 13));
#pragma unroll
    for (int j = 0; j < 4; ++j) {
      const int dcol = (j << 4) + e;
      const float bvv = bias[col0 + wn * 64 + dcol];
#pragma unroll
      for (int mf = 0; mf < 4; ++mf)
#pragma unroll
        for (int r = 0; r < 4; ++r) {
          const int lr = (mf << 4) + (g << 2) + r;
          qt[lr * 64 + (dcol ^ ((lr & 7) << 1))] = f2bf(acc[mf][j][r] + bvv);
        }
    }
    WAIT_LGKM0();
    const int b = (int)(row0 >> 12);
    const int hh = 2 * bn + wn;
    const int lb0 = ((int)(row0 & 4095)) + wm * 64;
    const int d = lane;
    char* basep = (char*)Cv + (((long)(b * 16 + hh) * 64 + d) * 4096 + lb0) * 2;
#pragma unroll
    for (int cc8 = 0; cc8 < 8; ++cc8) {
      unsigned short v[8];
#pragma unroll
      for (int k = 0; k < 8; ++k)
        v[k] = qt[(cc8 * 8 + k) * 64 + (d ^ (k << 1))];
      uint4 o;
      o.x = (unsigned)v[0] | ((unsigned)v[1] << 16);
      o.y = (unsigned)v[2] | ((unsigned)v[3] << 16);
      o.z = (unsigned)v[4] | ((unsigned)v[5] << 16);
      o.w = (unsigned)v[6] | ((unsigned)v[7] << 16);
      *(uint4*)(basep + ((cc8 ^ (d & 7)) << 4)) = o;
    }
    return;
  }

  const int r0 = wm * 64 + (g << 2);
  const int c0 = wn * 64 + e;
#pragma unroll
  for (int j = 0; j < 4; ++j) {
    const long gcol = col0 + c0 + (j << 4);
    const float bvv = bias[gcol];
#pragma unroll
    for (int mf = 0; mf < 4; ++mf) {
#pragma unroll
      for (int r = 0; r < 4; ++r) {
        const long grow = row0 + r0 + (mf << 4) + r;
        float v = acc[mf][j][r] + bvv;
        if (RES) v += res[grow * N + gcol];
        if (RELU) v = fmaxf(v, 0.f);
        if (OBF16) ((unsigned short*)Cv)[grow * N + gcol] = f2bf(v);
        else ((float*)Cv)[grow * N + gcol] = v;
      }
    }
  }
}

// -------- 256x128-tile 8-wave MX-fp8 GEMM (K=128/tile) ----------------------
// De-conflicted LDS layout: within each 128B row, slot s (16B) holds k-chunk
// c(s) = s<4 ? 2s : 2(s-4)+1 (composed with the row-XOR in the staging source
// address). Reads then use the bf16 kernel's zero-conflict offsets
// (g*16 + kh*64) ^ rx, delivering k-bytes [32g,32g+16) and [32g+16,32g+32).
template <bool OFP8, int SB>
__global__ __launch_bounds__(512, 2) void gemm256f8(
    const char* __restrict__ A, const char* __restrict__ Bt,
    void* Cv, const float* __restrict__ bias, const float* res,
    int M, int N, int K) {
  __shared__ __align__(16) char lds[147456];
  const int tid = threadIdx.x;
  const int lane = tid & 63, wid = tid >> 6;
  const int e = lane & 15, g = lane >> 4;
  const int wm = wid >> 1, wn = wid & 1;
  const int ntn = N >> 7;
  const int nwg = (int)gridDim.x, cpx = nwg >> 3;
  const int swz = ((int)blockIdx.x & 7) * cpx + ((int)blockIdx.x >> 3);
  const int bm = swz / ntn, bn = swz % ntn;
  const long row0 = (long)bm << 8, col0 = (long)bn << 7;

  const int srow = tid >> 3;
  const int sl = (tid & 7) ^ (srow & 7);              // logical slot after row-XOR
  const int gc = (sl < 4) ? (2 * sl) : (2 * (sl - 4) + 1);  // k-chunk permutation
  const int skb = gc << 4;
  const char* Abase = A + (row0 + srow) * (long)K + skb;
  const char* Bbase = Bt + (col0 + srow) * (long)K + skb;
  const int lof = wid << 10;

  f32x4 acc[4][4] = {};
  const int nkt = K >> 7;
  const int rx = (e & 7) << 4;

  char* bufA = lds;
  char* bufB = lds + 49152;
  char* bufC = lds + 98304;

#pragma unroll
  for (int c = 0; c < 4; ++c)
    gload_lds16(Abase + (long)c * 64 * K, bufA + lof + c * 8192);
#pragma unroll
  for (int c = 0; c < 2; ++c)
    gload_lds16(Bbase + (long)c * 64 * K, bufA + 32768 + lof + c * 8192);
#pragma unroll
  for (int c = 0; c < 4; ++c)
    gload_lds16(Abase + (long)c * 64 * K + 128, bufB + lof + c * 8192);
#pragma unroll
  for (int c = 0; c < 2; ++c)
    gload_lds16(Bbase + (long)c * 64 * K + 128, bufB + 32768 + lof + c * 8192);
  WAIT_VM(6);
  barrier_pin();

  for (int kt = 0; kt < nkt; ++kt) {
    char* Ac = bufA;
    char* Bc = bufA + 32768;
    const bool pf2 = (kt + 2 < nkt);
    const long kn2 = (long)(kt + 2) << 7;

    // phase 0: all B frags + A frags 0,1 (bf16-pattern offsets, conflict-free)
    i32x8v bfr[4];
#pragma unroll
    for (int j = 0; j < 4; ++j) {
      const int r = wn * 64 + j * 16 + e;
      const i32x4v lo = *(const i32x4v*)(Bc + r * 128 + ((g * 16) ^ rx));
      const i32x4v hi = *(const i32x4v*)(Bc + r * 128 + ((g * 16 + 64) ^ rx));
      bfr[j] = mk8(lo, hi);
    }
    i32x8v af0[2];
#pragma unroll
    for (int i = 0; i < 2; ++i) {
      const int r = wm * 64 + i * 16 + e;
      const i32x4v lo = *(const i32x4v*)(Ac + r * 128 + ((g * 16) ^ rx));
      const i32x4v hi = *(const i32x4v*)(Ac + r * 128 + ((g * 16 + 64) ^ rx));
      af0[i] = mk8(lo, hi);
    }
    if (pf2) {
#pragma unroll
      for (int c = 0; c < 3; ++c)
        gload_lds16(Abase + (long)c * 64 * K + kn2, bufC + lof + c * 8192);
    }
    barrier_pin();
    WAIT_LGKM0();
    __builtin_amdgcn_s_setprio(1);
#pragma unroll
    for (int i = 0; i < 2; ++i)
#pragma unroll
      for (int j = 0; j < 4; ++j)
        acc[i][j] = __builtin_amdgcn_mfma_scale_f32_16x16x128_f8f6f4(
            af0[i], bfr[j], acc[i][j], 0, 0, 0, 127, 0, SB);
    __builtin_amdgcn_s_setprio(0);
    barrier_pin();

    // phase 1: A frags 2,3
    i32x8v af1[2];
#pragma unroll
    for (int i = 0; i < 2; ++i) {
      const int r = wm * 64 + (2 + i) * 16 + e;
      const i32x4v lo = *(const i32x4v*)(Ac + r * 128 + ((g * 16) ^ rx));
      const i32x4v hi = *(const i32x4v*)(Ac + r * 128 + ((g * 16 + 64) ^ rx));
      af1[i] = mk8(lo, hi);
    }
    if (pf2) {
      gload_lds16(Abase + (long)3 * 64 * K + kn2, bufC + lof + 3 * 8192);
      gload_lds16(Bbase + kn2, bufC + 32768 + lof);
      gload_lds16(Bbase + (long)64 * K + kn2, bufC + 32768 + lof + 8192);
      WAIT_VM(6);
    } else if (kt + 1 < nkt) {
      WAIT_VM(0);
    }
    barrier_pin();
    WAIT_LGKM0();
    __builtin_amdgcn_s_setprio(1);
#pragma unroll
    for (int i = 0; i < 2; ++i)
#pragma unroll
      for (int j = 0; j < 4; ++j)
        acc[2 + i][j] = __builtin_amdgcn_mfma_scale_f32_16x16x128_f8f6f4(
            af1[i], bfr[j], acc[2 + i][j], 0, 0, 0, 127, 0, SB);
    __builtin_amdgcn_s_setprio(0);
    barrier_pin();

    char* t = bufA; bufA = bufB; bufB = bufC; bufC = t;
  }

  const int r0 = wm * 64 + (g << 2);
  const int c0 = wn * 64 + e;
  if (OFP8) {
    unsigned char* O = (unsigned char*)Cv;
#pragma unroll
    for (int j = 0; j < 4; ++j) {
      const long gcol = col0 + c0 + (j << 4);
      const float bvv = bias[gcol];
#pragma unroll
      for (int mf = 0; mf < 4; ++mf)
#pragma unroll
        for (int r = 0; r < 4; ++r) {
          const long grow = row0 + r0 + (mf << 4) + r;
          const float v = fmaxf(acc[mf][j][r] + bvv, 0.f);
          O[grow * (long)N + gcol] =
              (unsigned char)(__builtin_amdgcn_cvt_pk_fp8_f32(v, v, 0, false) & 0xFF);
        }
    }
  } else {
    float* O = (float*)Cv;
#pragma unroll
    for (int j = 0; j < 4; ++j) {
      const long gcol = col0 + c0 + (j << 4);
      const float bvv = bias[gcol];
#pragma unroll
      for (int mf = 0; mf < 4; ++mf)
#pragma unroll
        for (int r = 0; r < 4; ++r) {
          const long grow = row0 + r0 + (mf << 4) + r;
          O[grow * (long)N + gcol] = acc[mf][j][r] + bvv + res[grow * (long)N + gcol];
        }
    }
  }
}

// -------- weight transpose + cast: W[K][N] f32 -> Wt[N][K] bf16 --------
__global__ __launch_bounds__(256) void wtrans(const float* __restrict__ W,
                                              unsigned short* __restrict__ Wt,
                                              int K, int N) {
  __shared__ float t[32][33];
  const int tx = threadIdx.x & 31, ty = threadIdx.x >> 5;
  const int n0 = blockIdx.x << 5, k0 = blockIdx.y << 5;
#pragma unroll
  for (int i = 0; i < 32; i += 8)
    t[ty + i][tx] = W[(long)(k0 + ty + i) * N + n0 + tx];
  __syncthreads();
#pragma unroll
  for (int i = 0; i < 32; i += 8)
    Wt[(long)(n0 + ty + i) * K + k0 + tx] = f2bf(t[tx][ty + i]);
}

// -------- weight transpose + cast to fp8 (x scale): W -> Wt8[N][K] ----------
__global__ __launch_bounds__(256) void wtrans8(const float* __restrict__ W,
                                               unsigned char* __restrict__ Wt,
                                               int K, int N, float scale) {
  __shared__ float t[32][33];
  const int tx = threadIdx.x & 31, ty = threadIdx.x >> 5;
  const int n0 = blockIdx.x << 5, k0 = blockIdx.y << 5;
#pragma unroll
  for (int i = 0; i < 32; i += 8)
    t[ty + i][tx] = W[(long)(k0 + ty + i) * N + n0 + tx];
  __syncthreads();
  const int n = threadIdx.x >> 3, kq = threadIdx.x & 7;
  const unsigned int p = pk4fp8(t[kq * 4 + 0][n] * scale, t[kq * 4 + 1][n] * scale,
                                t[kq * 4 + 2][n] * scale, t[kq * 4 + 3][n] * scale);
  *(unsigned int*)(Wt + (long)(n0 + n) * K + k0 + kq * 4) = p;
}

// -------- projT prep: projTs[m][d] = bf16(proj[d][m]*0.125), pre-swizzled ----
__global__ __launch_bounds__(256) void projt_prep(const float* __restrict__ proj,
                                                  unsigned short* __restrict__ projTs) {
  const int t = threadIdx.x;
  const int m = t >> 1, sh = t & 1;
#pragma unroll
  for (int s4 = 0; s4 < 4; ++s4) {
    const int s = sh * 4 + s4;
    unsigned short v[8];
#pragma unroll
    for (int k = 0; k < 8; ++k)
      v[k] = f2bf(proj[(s * 8 + k) * 128 + m] * 0.125f);
    uint4 o;
    o.x = (unsigned)v[0] | ((unsigned)v[1] << 16);
    o.y = (unsigned)v[2] | ((unsigned)v[3] << 16);
    o.z = (unsigned)v[4] | ((unsigned)v[5] << 16);
    o.w = (unsigned)v[6] | ((unsigned)v[7] << 16);
    *(uint4*)((char*)projTs + m * 128 + ((s ^ (m & 7)) << 4)) = o;
  }
}

// -------- LayerNorm over 1024 cols, f32 in -> bf16 out --------
__global__ __launch_bounds__(256) void ln_kernel(const float* __restrict__ x,
                                                 const float* __restrict__ g,
                                                 const float* __restrict__ b,
                                                 unsigned short* __restrict__ out) {
  const int row = blockIdx.x, tid = threadIdx.x;
  const float* xr = x + (long)row * 1024;
  const float4 xv = *(const float4*)(xr + tid * 4);
  float s = xv.x + xv.y + xv.z + xv.w;
  float s2 = xv.x * xv.x + xv.y * xv.y + xv.z * xv.z + xv.w * xv.w;
#pragma unroll
  for (int off = 32; off > 0; off >>= 1) {
    s += __shfl_down(s, off);
    s2 += __shfl_down(s2, off);
  }
  __shared__ float ps[4], ps2[4];
  if ((tid & 63) == 0) { ps[tid >> 6] = s; ps2[tid >> 6] = s2; }
  __syncthreads();
  const float ts = ps[0] + ps[1] + ps[2] + ps[3];
  const float ts2 = ps2[0] + ps2[1] + ps2[2] + ps2[3];
  const float mu = ts * (1.f / 1024.f);
  const float rstd = rsqrtf(ts2 * (1.f / 1024.f) - mu * mu + 1e-5f);
  const float4 gv = *(const float4*)(g + tid * 4);
  const float4 bv = *(const float4*)(b + tid * 4);
  ushort4 o;
  o.x = f2bf((xv.x - mu) * rstd * gv.x + bv.x);
  o.y = f2bf((xv.y - mu) * rstd * gv.y + bv.y);
  o.z = f2bf((xv.z - mu) * rstd * gv.z + bv.z);
  o.w = f2bf((xv.w - mu) * rstd * gv.w + bv.w);
  *(ushort4*)(out + (long)row * 1024 + tid * 4) = o;
}

// -------- LayerNorm -> fp8 out (for FFN path) --------
__global__ __launch_bounds__(256) void ln_kernel8(const float* __restrict__ x,
                                                  const float* __restrict__ g,
                                                  const float* __restrict__ b,
                                                  unsigned char* __restrict__ out) {
  const int row = blockIdx.x, tid = threadIdx.x;
  const float* xr = x + (long)row * 1024;
  const float4 xv = *(const float4*)(xr + tid * 4);
  float s = xv.x + xv.y + xv.z + xv.w;
  float s2 = xv.x * xv.x + xv.y * xv.y + xv.z * xv.z + xv.w * xv.w;
#pragma unroll
  for (int off = 32; off > 0; off >>= 1) {
    s += __shfl_down(s, off);
    s2 += __shfl_down(s2, off);
  }
  __shared__ float ps[4], ps2[4];
  if ((tid & 63) == 0) { ps[tid >> 6] = s; ps2[tid >> 6] = s2; }
  __syncthreads();
  const float ts = ps[0] + ps[1] + ps[2] + ps[3];
  const float ts2 = ps2[0] + ps2[1] + ps2[2] + ps2[3];
  const float mu = ts * (1.f / 1024.f);
  const float rstd = rsqrtf(ts2 * (1.f / 1024.f) - mu * mu + 1e-5f);
  const float4 gv = *(const float4*)(g + tid * 4);
  const float4 bv = *(const float4*)(b + tid * 4);
  const unsigned int p = pk4fp8((xv.x - mu) * rstd * gv.x + bv.x,
                                (xv.y - mu) * rstd * gv.y + bv.y,
                                (xv.z - mu) * rstd * gv.z + bv.z,
                                (xv.w - mu) * rstd * gv.w + bv.w);
  *(unsigned int*)(out + (long)row * 1024 + tid * 4) = p;
}

// -------- kv kernel --------
__global__ __launch_bounds__(256, 2) void kv_kernel(
    const unsigned short* __restrict__ PH, const unsigned short* __restrict__ VTg,
    float* __restrict__ PART, int half) {
  __shared__ __align__(16) unsigned short Ps[64 * 128];
  __shared__ __align__(16) unsigned short Vs[64 * 64];
  __shared__ __align__(16) unsigned short KPT[256 * 64];
  const int tid = threadIdx.x;
  const int lane = tid & 63, wid = tid >> 6;
  const int bhh = blockIdx.x, chunk = blockIdx.y;
  const int b2 = bhh >> 4, h = bhh & 15;
  const int bh = (half * 2 + b2) * 16 + h;

  f32x4 acc[4][4] = {};
  const int e = lane & 15, g = lane >> 4;
  const int m = tid & 127, isin = tid >> 7;
  const int m2 = (isin << 7) + m, swm = m & 7;

  for (int ti = 0; ti < 4; ++ti) {
    const int l0 = chunk * 256 + ti * 64;
    __syncthreads();
#pragma unroll
    for (int c = 0; c < 4; ++c) {
      const int r = l0 + c * 16 + (tid >> 4);
      gload_lds16((const char*)PH + (long)(b2 * 4096 + r) * 4096 + h * 256 + (tid & 15) * 16,
                  (char*)Ps + c * 4096 + (wid << 10));
    }
#pragma unroll
    for (int c = 0; c < 2; ++c) {
      const int d = c * 32 + (tid >> 3);
      gload_lds16((const char*)VTg + ((long)(bh * 64 + d) * 4096 + l0) * 2 + (tid & 7) * 16,
                  (char*)Vs + c * 4096 + (wid << 10));
    }
    __syncthreads();
    {
      char* krow = (char*)KPT + m2 * 128;
#pragma unroll
      for (int g8 = 0; g8 < 8; ++g8) {
        unsigned pk[4];
#pragma unroll
        for (int k2 = 0; k2 < 4; ++k2) {
          const float p0 = bf2f(Ps[(g8 * 8 + k2 * 2) * 128 + m]);
          const float p1 = bf2f(Ps[(g8 * 8 + k2 * 2 + 1) * 128 + m]);
          const float v0 = (isin ? __sinf(p0) : __cosf(p0)) * RS128;
          const float v1 = (isin ? __sinf(p1) : __cosf(p1)) * RS128;
          pk[k2] = pack2f(v0, v1);
        }
        uint4 o; o.x = pk[0]; o.y = pk[1]; o.z = pk[2]; o.w = pk[3];
        *(uint4*)(krow + ((g8 ^ swm) << 4)) = o;
      }
    }
    __syncthreads();
#pragma unroll
    for (int kk = 0; kk < 2; ++kk) {
      const int ch = (kk << 2) + g;
      bf16x8 af[4], bfr[4];
#pragma unroll
      for (int i = 0; i < 4; ++i) {
        const int dr = (i << 4) + e;
        af[i] = *(const bf16x8*)((char*)Vs + dr * 128 + ((ch ^ (e & 7)) << 4));
      }
#pragma unroll
      for (int j = 0; j < 4; ++j) {
        const int mr = (wid << 6) + (j << 4) + e;
        bfr[j] = *(const bf16x8*)((char*)KPT + mr * 128 + ((ch ^ (e & 7)) << 4));
      }
#pragma unroll
      for (int i = 0; i < 4; ++i)
#pragma unroll
        for (int j = 0; j < 4; ++j)
          acc[i][j] = __builtin_amdgcn_mfma_f32_16x16x32_bf16(af[i], bfr[j],
                                                              acc[i][j], 0, 0, 0);
    }
  }
  float* slice = PART + ((long)chunk * 32 + bhh) * 16384;
#pragma unroll
  for (int i = 0; i < 4; ++i)
#pragma unroll
    for (int j = 0; j < 4; ++j)
#pragma unroll
      for (int r = 0; r < 4; ++r) {
        const int d = (i << 4) + (g << 2) + r;
        const int mc = (wid << 6) + (j << 4) + e;
        slice[d * 256 + mc] = acc[i][j][r];
      }
}

__global__ __launch_bounds__(256) void kv_reduce(const float* __restrict__ PART,
                                                 float* __restrict__ KVacc, int half) {
  const int bhh = blockIdx.x, seg = blockIdx.y;
  const long off = (long)bhh * 16384 + seg * 1024 + threadIdx.x * 4;
  float4 s = make_float4(0.f, 0.f, 0.f, 0.f);
#pragma unroll
  for (int c = 0; c < 16; ++c) {
    const float4 v = *(const float4*)(PART + ((long)c * 32) * 16384 + off);
    s.x += v.x; s.y += v.y; s.z += v.z; s.w += v.w;
  }
  *(float4*)(KVacc + (long)(half * 32) * 16384 + off) = s;
}

__global__ __launch_bounds__(256) void kvt_conv(const float* __restrict__ KVacc,
                                                unsigned short* __restrict__ KVT) {
  const int bh = blockIdx.x, tid = threadIdx.x;
  const int d = tid >> 2, mq = tid & 3;
  const float* src = KVacc + (long)bh * 16384 + d * 256 + mq * 64;
  char* dst = (char*)KVT + bh * 32768 + d * 512;
#pragma unroll
  for (int cc = 0; cc < 8; ++cc) {
    const float4 a = *(const float4*)(src + cc * 8);
    const float4 b = *(const float4*)(src + cc * 8 + 4);
    uint4 o;
    o.x = pack2f(a.x, a.y); o.y = pack2f(a.z, a.w);
    o.z = pack2f(b.x, b.y); o.w = pack2f(b.z, b.w);
    const int chunk = mq * 8 + cc;
    *(uint4*)(dst + ((chunk ^ (d & 7)) << 4)) = o;
  }
}

// -------- attn kernel --------
__global__ __launch_bounds__(256, 2) void attn_kernel(
    const unsigned short* __restrict__ PH, const unsigned short* __restrict__ KVT,
    unsigned short* __restrict__ ATTN, int half) {
  __shared__ __align__(16) unsigned short QPs[64 * 256];
  __shared__ __align__(16) unsigned short KVs[64 * 256];
  const int tid = threadIdx.x;
  const int lane = tid & 63, wid = tid >> 6;
  const int bhh = blockIdx.x, chunk = blockIdx.y;
  const int b2 = bhh >> 4, h = bhh & 15;
  const int b = half * 2 + b2, bh = b * 16 + h;
  const int e = lane & 15, g = lane >> 4;

#pragma unroll
  for (int c = 0; c < 8; ++c)
    gload_lds16((const char*)KVT + bh * 32768 + c * 4096 + tid * 16,
                (char*)KVs + c * 4096 + (wid << 10));

  const int lrow = tid >> 2, ms = tid & 3, swl = lrow & 7;

  for (int ti = 0; ti < 4; ++ti) {
    const int l0 = chunk * 256 + ti * 64;
    const char* pg = (const char*)PH + (long)(b2 * 4096 + l0 + lrow) * 4096 + h * 256 + ms * 64;
    uint4 P[4];
#pragma unroll
    for (int q = 0; q < 4; ++q) P[q] = *(const uint4*)(pg + q * 16);
    uint4 CQ[4], SQ[4];
#pragma unroll
    for (int q = 0; q < 4; ++q) {
      const unsigned w[4] = {P[q].x, P[q].y, P[q].z, P[q].w};
      unsigned cw[4], sw[4];
#pragma unroll
      for (int k = 0; k < 4; ++k) {
        float c0, s0, c1, s1;
        __sincosf(bf2f((unsigned short)(w[k] & 0xffff)), &s0, &c0);
        __sincosf(bf2f((unsigned short)(w[k] >> 16)), &s1, &c1);
        cw[k] = pack2f(c0 * RS128, c1 * RS128);
        sw[k] = pack2f(s0 * RS128, s1 * RS128);
      }
      CQ[q].x = cw[0]; CQ[q].y = cw[1]; CQ[q].z = cw[2]; CQ[q].w = cw[3];
      SQ[q].x = sw[0]; SQ[q].y = sw[1]; SQ[q].z = sw[2]; SQ[q].w = sw[3];
    }
    __syncthreads();
    {
      char* qrow = (char*)QPs + lrow * 512;
#pragma unroll
      for (int q = 0; q < 4; ++q) {
        const int c = ms * 4 + q;
        *(uint4*)(qrow + ((c ^ swl) << 4)) = CQ[q];
        *(uint4*)(qrow + ((16 + (c ^ swl)) << 4)) = SQ[q];
      }
    }
    __syncthreads();
    f32x4 acc[4] = {};
    const int lr = (wid << 4) + e;
#pragma unroll
    for (int kk = 0; kk < 8; ++kk) {
      const int ch = (kk << 2) + g;
      const bf16x8 af = *(const bf16x8*)((char*)QPs + lr * 512 + ((ch ^ (e & 7)) << 4));
#pragma unroll
      for (int j = 0; j < 4; ++j) {
        const bf16x8 bfr = *(const bf16x8*)((char*)KVs + ((j << 4) + e) * 512 + ((ch ^ (e & 7)) << 4));
        acc[j] = __builtin_amdgcn_mfma_f32_16x16x32_bf16(af, bfr, acc[j], 0, 0, 0);
      }
    }
#pragma unroll
    for (int j = 0; j < 4; ++j)
#pragma unroll
      for (int r = 0; r < 4; ++r) {
        const int lo = (wid << 4) + (g << 2) + r;
        ATTN[(long)(b * 4096 + l0 + lo) * 1024 + h * 64 + (j << 4) + e] = f2bf(acc[j][r]);
      }
  }
}

extern "C" void kernel_launch(void* const* d_in, const int* in_sizes, int n_in,
                              void* d_out, int out_size, void* d_ws, size_t ws_size,
                              hipStream_t stream) {
  (void)in_sizes; (void)n_in; (void)out_size; (void)ws_size;
  const float* x    = (const float*)d_in[0];
  const float* proj = (const float*)d_in[1];
  const float* wq = (const float*)d_in[2];
  const float* bq = (const float*)d_in[3];
  const float* wk = (const float*)d_in[4];
  const float* bk = (const float*)d_in[5];
  const float* wv = (const float*)d_in[6];
  const float* bv = (const float*)d_in[7];
  const float* wo = (const float*)d_in[8];
  const float* bo = (const float*)d_in[9];
  const float* g1  = (const float*)d_in[10];
  const float* be1 = (const float*)d_in[11];
  const float* w1 = (const float*)d_in[12];
  const float* b1 = (const float*)d_in[13];
  const float* w2 = (const float*)d_in[14];
  const float* b2 = (const float*)d_in[15];
  const float* g2  = (const float*)d_in[16];
  const float* be2 = (const float*)d_in[17];
  float* out = (float*)d_out;

  char* ws = (char*)d_ws;
  const size_t MB = 1u << 20;
  unsigned short* WQT    = (unsigned short*)(ws + 0 * MB);
  unsigned short* WKT    = (unsigned short*)(ws + 2 * MB);
  unsigned short* WVT    = (unsigned short*)(ws + 4 * MB);
  unsigned short* WOT    = (unsigned short*)(ws + 6 * MB);
  unsigned short* projTs = (unsigned short*)(ws + 8 * MB);
  float* KVacc = (float*)(ws + 10 * MB);
  unsigned short* KVT = (unsigned short*)(ws + 14 * MB);
  unsigned short* VTg  = (unsigned short*)(ws + 16 * MB);   // -> ATTN
  unsigned short* PH   = (unsigned short*)(ws + 64 * MB);
  float* PART  = (float*)(ws + 96 * MB);
  unsigned char* Hb8   = (unsigned char*)(ws + 0 * MB);     // FFN hidden fp8 (64MB)
  unsigned short* X2   = (unsigned short*)(ws + 128 * MB);  // -> X2B8
  unsigned char* X2B8  = (unsigned char*)(ws + 128 * MB);
  unsigned char* W1T8  = (unsigned char*)(ws + 160 * MB);
  unsigned char* W2T8  = (unsigned char*)(ws + 164 * MB);
  unsigned short* ATTN = VTg;

  dim3 blk(256), blk5(512);

  // weights prep
  wtrans<<<dim3(32, 32), blk, 0, stream>>>(wq, WQT, 1024, 1024);
  wtrans<<<dim3(32, 32), blk, 0, stream>>>(wk, WKT, 1024, 1024);
  wtrans<<<dim3(32, 32), blk, 0, stream>>>(wv, WVT, 1024, 1024);
  wtrans<<<dim3(32, 32), blk, 0, stream>>>(wo, WOT, 1024, 1024);
  wtrans8<<<dim3(128, 32), blk, 0, stream>>>(w1, W1T8, 1024, 4096, 16.f);
  wtrans8<<<dim3(32, 128), blk, 0, stream>>>(w2, W2T8, 4096, 1024, 16.f);
  projt_prep<<<1, blk, 0, stream>>>(proj, projTs);

  // LN1 -> bf16
  ln_kernel<<<16384, blk, 0, stream>>>(x, g1, be1, X2);

  // V gemm (bf16) with fused transpose epilogue -> VTg
  gemm256<false, false, false, false, true><<<512, blk5, 0, stream>>>(
      X2, WVT, VTg, bv, nullptr, nullptr, 16384, 1024, 1024);

  // kv pipeline, two L-halves: K gemm (bf16) + PROJ -> PH -> kv
  for (int half = 0; half < 2; ++half) {
    gemm256<true, false, false, true, false><<<256, blk5, 0, stream>>>(
        X2 + (long)half * 8192 * 1024, WKT, PH, bk, nullptr, projTs, 8192, 1024, 1024);
    kv_kernel<<<dim3(32, 16), blk, 0, stream>>>(PH, VTg, PART, half);
    kv_reduce<<<dim3(32, 16), blk, 0, stream>>>(PART, KVacc, half);
  }
  kvt_conv<<<64, blk, 0, stream>>>(KVacc, KVT);

  // attn pipeline, two L-halves (ATTN bf16)
  for (int half = 0; half < 2; ++half) {
    gemm256<true, false, false, true, false><<<256, blk5, 0, stream>>>(
        X2 + (long)half * 8192 * 1024, WQT, PH, bq, nullptr, projTs, 8192, 1024, 1024);
    attn_kernel<<<dim3(32, 16), blk, 0, stream>>>(PH, KVT, ATTN, half);
  }

  // Wo (bf16) + residual -> out (f32)
  gemm256<false, false, true, false, false><<<512, blk5, 0, stream>>>(
      ATTN, WOT, out, bo, x, nullptr, 16384, 1024, 1024);

  // LN2 -> fp8 (X2 region dead)
  ln_kernel8<<<16384, blk, 0, stream>>>(out, g2, be2, X2B8);

  // FFN in MX-fp8 (weights x16 -> B-scale e8m0=123 == 2^-4)
  gemm256f8<true, 123><<<2048, blk5, 0, stream>>>(
      (const char*)X2B8, (const char*)W1T8, Hb8, b1, nullptr, 16384, 4096, 1024);
  gemm256f8<false, 123><<<512, blk5, 0, stream>>>(
      (const char*)Hb8, (const char*)W2T8, out, b2, out, 16384, 1024, 4096);
}

// Round 17
// 592.705 us; speedup vs baseline: 1.5118x; 1.0042x over previous
//
#include <hip/hip_runtime.h>

// EstraNetBlock: pre-norm linear attention (fourier feature kernel) + FFN.
// B=4, L=4096, D=1024, H=16, Dh=64, M=128 (2M=256), D_INNER=4096.
//
// R17 = R16 + (1) coalesced PROJ epilogue: pacc repacked via wave-private LDS
// in two 32-row halves, PH written as 16B stores (256B contiguous per 16
// lanes) instead of 128 scalar 2B stores/thread; (2) kvt_conv fused into
// kv_reduce (writes KVT bf16 swizzled directly; KVacc deleted).
//
// ws (MB): 0 WQT,2 WKT,4 WVT,6 WOT,8 projTs,14 KVT(2),16 VTg(->ATTN),
// 64 PH,96 PART,128 X2(->X2B8),160 W1T8(4),164 W2T8(4); FFN H8 = arena 0..64.

#define RS128 0.08838834764831845f

typedef short bf16x8 __attribute__((ext_vector_type(8)));
typedef float f32x4 __attribute__((ext_vector_type(4)));
typedef int i32x4v __attribute__((ext_vector_type(4)));
typedef int i32x8v __attribute__((ext_vector_type(8)));

__device__ __forceinline__ unsigned short f2bf(float f) {
  unsigned int u = __float_as_uint(f);
  u += 0x7fffu + ((u >> 16) & 1u);
  return (unsigned short)(u >> 16);
}
__device__ __forceinline__ float bf2f(unsigned short h) {
  return __uint_as_float(((unsigned int)h) << 16);
}
__device__ __forceinline__ unsigned int pack2f(float a, float b) {
  return (unsigned int)f2bf(a) | ((unsigned int)f2bf(b) << 16);
}
__device__ __forceinline__ void gload_lds16(const void* g, void* l) {
  __builtin_amdgcn_global_load_lds(
      (const __attribute__((address_space(1))) void*)g,
      (__attribute__((address_space(3))) void*)l, 16, 0, 0);
}
__device__ __forceinline__ void barrier_pin() {
  __builtin_amdgcn_sched_barrier(0);
  __builtin_amdgcn_s_barrier();
  __builtin_amdgcn_sched_barrier(0);
}
#define WAIT_VM(N) { asm volatile("s_waitcnt vmcnt(" #N ")" ::: "memory"); __builtin_amdgcn_sched_barrier(0); }
#define WAIT_LGKM0() { asm volatile("s_waitcnt lgkmcnt(0)" ::: "memory"); __builtin_amdgcn_sched_barrier(0); }

__device__ __forceinline__ i32x8v mk8(i32x4v lo, i32x4v hi) {
  i32x8v v;
  v[0] = lo[0]; v[1] = lo[1]; v[2] = lo[2]; v[3] = lo[3];
  v[4] = hi[0]; v[5] = hi[1]; v[6] = hi[2]; v[7] = hi[3];
  return v;
}
__device__ __forceinline__ unsigned int pk4fp8(float a, float b, float c, float d) {
  int p = __builtin_amdgcn_cvt_pk_fp8_f32(a, b, 0, false);
  p = __builtin_amdgcn_cvt_pk_fp8_f32(c, d, p, true);
  return (unsigned int)p;
}

// -------- 256x128-tile 8-wave GEMM (ring structure, bf16) -------------------
template <bool OBF16, bool RELU, bool RES, bool PROJ, bool TRANSV>
__global__ __launch_bounds__(512, 2) void gemm256(
    const unsigned short* __restrict__ A, const unsigned short* __restrict__ Bt,
    void* Cv, const float* __restrict__ bias, const float* res,
    const unsigned short* __restrict__ projTs, int M, int N, int K) {
  __shared__ __align__(16) char lds[163840];
  const int tid = threadIdx.x;
  const int lane = tid & 63, wid = tid >> 6;
  const int e = lane & 15, g = lane >> 4;
  const int wm = wid >> 1, wn = wid & 1;
  const int ntn = N >> 7;
  const int nwg = (int)gridDim.x, cpx = nwg >> 3;
  const int swz = ((int)blockIdx.x & 7) * cpx + ((int)blockIdx.x >> 3);
  const int bm = swz / ntn, bn = swz % ntn;
  const long row0 = (long)bm << 8, col0 = (long)bn << 7;

  const int srow = tid >> 3;
  const int skb = ((tid & 7) << 4) ^ ((srow & 7) << 4);
  const unsigned short* Abase = A + (row0 + srow) * (long)K + (skb >> 1);
  const unsigned short* Bbase = Bt + (col0 + srow) * (long)K + (skb >> 1);
  const int lof = wid << 10;

  f32x4 acc[4][4] = {};
  const int nkt = K >> 6;
  const int rx = (e & 7) << 4;

  char* bufA = lds;
  char* bufB = lds + 49152;
  char* bufC = lds + 98304;

  if (PROJ) {
    gload_lds16((const char*)projTs + (wid << 10) + (lane << 4),
                lds + 147456 + (wid << 10));
    gload_lds16((const char*)projTs + 8192 + (wid << 10) + (lane << 4),
                lds + 147456 + 8192 + (wid << 10));
  }
#pragma unroll
  for (int c = 0; c < 4; ++c)
    gload_lds16(Abase + (long)c * 64 * K, bufA + lof + c * 8192);
#pragma unroll
  for (int c = 0; c < 2; ++c)
    gload_lds16(Bbase + (long)c * 64 * K, bufA + 32768 + lof + c * 8192);
#pragma unroll
  for (int c = 0; c < 4; ++c)
    gload_lds16(Abase + (long)c * 64 * K + 64, bufB + lof + c * 8192);
#pragma unroll
  for (int c = 0; c < 2; ++c)
    gload_lds16(Bbase + (long)c * 64 * K + 64, bufB + 32768 + lof + c * 8192);
  WAIT_VM(6);
  barrier_pin();

  for (int kt = 0; kt < nkt; ++kt) {
    char* Ac = bufA;
    char* Bc = bufA + 32768;
    const bool pf2 = (kt + 2 < nkt);
    const long kn2 = (long)(kt + 2) << 6;

    // phase 0
    bf16x8 bfr[4][2];
#pragma unroll
    for (int j = 0; j < 4; ++j) {
      const int r = wn * 64 + j * 16 + e;
#pragma unroll
      for (int kh = 0; kh < 2; ++kh)
        bfr[j][kh] = *(const bf16x8*)(Bc + r * 128 + ((g * 16 + kh * 64) ^ rx));
    }
    bf16x8 af0[2][2];
#pragma unroll
    for (int i = 0; i < 2; ++i) {
      const int r = wm * 64 + i * 16 + e;
#pragma unroll
      for (int kh = 0; kh < 2; ++kh)
        af0[i][kh] = *(const bf16x8*)(Ac + r * 128 + ((g * 16 + kh * 64) ^ rx));
    }
    if (pf2) {
#pragma unroll
      for (int c = 0; c < 3; ++c)
        gload_lds16(Abase + (long)c * 64 * K + kn2, bufC + lof + c * 8192);
    }
    barrier_pin();
    WAIT_LGKM0();
    __builtin_amdgcn_s_setprio(1);
#pragma unroll
    for (int i = 0; i < 2; ++i)
#pragma unroll
      for (int j = 0; j < 4; ++j)
#pragma unroll
        for (int kh = 0; kh < 2; ++kh)
          acc[i][j] = __builtin_amdgcn_mfma_f32_16x16x32_bf16(
              af0[i][kh], bfr[j][kh], acc[i][j], 0, 0, 0);
    __builtin_amdgcn_s_setprio(0);
    barrier_pin();

    // phase 1
    bf16x8 af1[2][2];
#pragma unroll
    for (int i = 0; i < 2; ++i) {
      const int r = wm * 64 + (2 + i) * 16 + e;
#pragma unroll
      for (int kh = 0; kh < 2; ++kh)
        af1[i][kh] = *(const bf16x8*)(Ac + r * 128 + ((g * 16 + kh * 64) ^ rx));
    }
    if (pf2) {
      gload_lds16(Abase + (long)3 * 64 * K + kn2, bufC + lof + 3 * 8192);
      gload_lds16(Bbase + kn2, bufC + 32768 + lof);
      gload_lds16(Bbase + (long)64 * K + kn2, bufC + 32768 + lof + 8192);
      WAIT_VM(6);
    } else if (kt + 1 < nkt) {
      WAIT_VM(0);
    }
    barrier_pin();
    WAIT_LGKM0();
    __builtin_amdgcn_s_setprio(1);
#pragma unroll
    for (int i = 0; i < 2; ++i)
#pragma unroll
      for (int j = 0; j < 4; ++j)
#pragma unroll
        for (int kh = 0; kh < 2; ++kh)
          acc[2 + i][j] = __builtin_amdgcn_mfma_f32_16x16x32_bf16(
              af1[i][kh], bfr[j][kh], acc[2 + i][j], 0, 0, 0);
    __builtin_amdgcn_s_setprio(0);
    barrier_pin();

    char* t = bufA; bufA = bufB; bufB = bufC; bufC = t;
  }

  if (PROJ) {
    // ---- fused per-head fourier projection (head hh = 2*bn+wn) ----
    char* qt = lds + (wid << 13);
    const int c0p = wn * 64 + e;
#pragma unroll
    for (int j = 0; j < 4; ++j) {
      const float bvv = bias[col0 + c0p + (j << 4)];
#pragma unroll
      for (int mf = 0; mf < 4; ++mf)
#pragma unroll
        for (int r = 0; r < 4; ++r) {
          const int lrow = (mf << 4) + (g << 2) + r;
          const int dby = ((((j << 4) + e) << 1)) ^ ((lrow & 7) << 4);
          *(unsigned short*)(qt + lrow * 128 + dby) = f2bf(acc[mf][j][r] + bvv);
        }
    }
    WAIT_LGKM0();
    const char* pj = lds + 147456;
    bf16x8 paf[4][2];
#pragma unroll
    for (int i = 0; i < 4; ++i) {
      const int r = (i << 4) + e;
#pragma unroll
      for (int kh = 0; kh < 2; ++kh)
        paf[i][kh] = *(const bf16x8*)(qt + r * 128 + ((g * 16 + kh * 64) ^ rx));
    }
    f32x4 pacc[4][8] = {};
#pragma unroll
    for (int j = 0; j < 8; ++j) {
      const int m = (j << 4) + e;
      const bf16x8 pb0 = *(const bf16x8*)(pj + m * 128 + ((g * 16) ^ rx));
      const bf16x8 pb1 = *(const bf16x8*)(pj + m * 128 + ((g * 16 + 64) ^ rx));
#pragma unroll
      for (int i = 0; i < 4; ++i) {
        pacc[i][j] = __builtin_amdgcn_mfma_f32_16x16x32_bf16(paf[i][0], pb0,
                                                             pacc[i][j], 0, 0, 0);
        pacc[i][j] = __builtin_amdgcn_mfma_f32_16x16x32_bf16(paf[i][1], pb1,
                                                             pacc[i][j], 0, 0, 0);
      }
    }
    // coalesced PH write: repack via wave-private 8KB in two 32-row halves,
    // then 16B stores (16 lanes = full 256B row segment).
    unsigned short* q2 = (unsigned short*)qt;  // qt1 data dead after paf reads
    unsigned short* PHp = (unsigned short*)Cv;
    const int hh = 2 * bn + wn;
    const long lbase = row0 + wm * 64;
#pragma unroll
    for (int h2 = 0; h2 < 2; ++h2) {
#pragma unroll
      for (int i2 = 0; i2 < 2; ++i2) {
        const int i = h2 * 2 + i2;
#pragma unroll
        for (int j = 0; j < 8; ++j)
#pragma unroll
          for (int r = 0; r < 4; ++r) {
            const int lrow = (i2 << 4) + (g << 2) + r;  // 0..31 within half
            q2[lrow * 128 + (j << 4) + e] = f2bf(pacc[i][j][r]);
          }
      }
      WAIT_LGKM0();  // own-wave ds_writes drained before ds_reads
#pragma unroll
      for (int p = 0; p < 8; ++p) {
        const int row = p * 4 + (lane >> 4);  // 0..31 within half
        const uint4 v = *(const uint4*)(q2 + row * 128 + (lane & 15) * 8);
        *(uint4*)((char*)(PHp + (lbase + h2 * 32 + row) * 2048 + hh * 128) +
                  (lane & 15) * 16) = v;
      }
      WAIT_LGKM0();  // reads of this half done before next half overwrites
    }
    return;
  }

  if (TRANSV) {
    unsigned short* qt = (unsigned short*)(lds + (wid << 13));
#pragma unroll
    for (int j = 0; j < 4; ++j) {
      const int dcol = (j << 4) + e;
      const float bvv = bias[col0 + wn * 64 + dcol];
#pragma unroll
      for (int mf = 0; mf < 4; ++mf)
#pragma unroll
        for (int r = 0; r < 4; ++r) {
          const int lr = (mf << 4) + (g << 2) + r;
          qt[lr * 64 + (dcol ^ ((lr & 7) << 1))] = f2bf(acc[mf][j][r] + bvv);
        }
    }
    WAIT_LGKM0();
    const int b = (int)(row0 >> 12);
    const int hh = 2 * bn + wn;
    const int lb0 = ((int)(row0 & 4095)) + wm * 64;
    const int d = lane;
    char* basep = (char*)Cv + (((long)(b * 16 + hh) * 64 + d) * 4096 + lb0) * 2;
#pragma unroll
    for (int cc8 = 0; cc8 < 8; ++cc8) {
      unsigned short v[8];
#pragma unroll
      for (int k = 0; k < 8; ++k)
        v[k] = qt[(cc8 * 8 + k) * 64 + (d ^ (k << 1))];
      uint4 o;
      o.x = (unsigned)v[0] | ((unsigned)v[1] << 16);
      o.y = (unsigned)v[2] | ((unsigned)v[3] << 16);
      o.z = (unsigned)v[4] | ((unsigned)v[5] << 16);
      o.w = (unsigned)v[6] | ((unsigned)v[7] << 16);
      *(uint4*)(basep + ((cc8 ^ (d & 7)) << 4)) = o;
    }
    return;
  }

  const int r0 = wm * 64 + (g << 2);
  const int c0 = wn * 64 + e;
#pragma unroll
  for (int j = 0; j < 4; ++j) {
    const long gcol = col0 + c0 + (j << 4);
    const float bvv = bias[gcol];
#pragma unroll
    for (int mf = 0; mf < 4; ++mf) {
#pragma unroll
      for (int r = 0; r < 4; ++r) {
        const long grow = row0 + r0 + (mf << 4) + r;
        float v = acc[mf][j][r] + bvv;
        if (RES) v += res[grow * N + gcol];
        if (RELU) v = fmaxf(v, 0.f);
        if (OBF16) ((unsigned short*)Cv)[grow * N + gcol] = f2bf(v);
        else ((float*)Cv)[grow * N + gcol] = v;
      }
    }
  }
}

// -------- 256x128-tile 8-wave MX-fp8 GEMM (K=128/tile, de-conflicted) -------
template <bool OFP8, int SB>
__global__ __launch_bounds__(512, 2) void gemm256f8(
    const char* __restrict__ A, const char* __restrict__ Bt,
    void* Cv, const float* __restrict__ bias, const float* res,
    int M, int N, int K) {
  __shared__ __align__(16) char lds[147456];
  const int tid = threadIdx.x;
  const int lane = tid & 63, wid = tid >> 6;
  const int e = lane & 15, g = lane >> 4;
  const int wm = wid >> 1, wn = wid & 1;
  const int ntn = N >> 7;
  const int nwg = (int)gridDim.x, cpx = nwg >> 3;
  const int swz = ((int)blockIdx.x & 7) * cpx + ((int)blockIdx.x >> 3);
  const int bm = swz / ntn, bn = swz % ntn;
  const long row0 = (long)bm << 8, col0 = (long)bn << 7;

  const int srow = tid >> 3;
  const int sl = (tid & 7) ^ (srow & 7);
  const int gc = (sl < 4) ? (2 * sl) : (2 * (sl - 4) + 1);
  const int skb = gc << 4;
  const char* Abase = A + (row0 + srow) * (long)K + skb;
  const char* Bbase = Bt + (col0 + srow) * (long)K + skb;
  const int lof = wid << 10;

  f32x4 acc[4][4] = {};
  const int nkt = K >> 7;
  const int rx = (e & 7) << 4;

  char* bufA = lds;
  char* bufB = lds + 49152;
  char* bufC = lds + 98304;

#pragma unroll
  for (int c = 0; c < 4; ++c)
    gload_lds16(Abase + (long)c * 64 * K, bufA + lof + c * 8192);
#pragma unroll
  for (int c = 0; c < 2; ++c)
    gload_lds16(Bbase + (long)c * 64 * K, bufA + 32768 + lof + c * 8192);
#pragma unroll
  for (int c = 0; c < 4; ++c)
    gload_lds16(Abase + (long)c * 64 * K + 128, bufB + lof + c * 8192);
#pragma unroll
  for (int c = 0; c < 2; ++c)
    gload_lds16(Bbase + (long)c * 64 * K + 128, bufB + 32768 + lof + c * 8192);
  WAIT_VM(6);
  barrier_pin();

  for (int kt = 0; kt < nkt; ++kt) {
    char* Ac = bufA;
    char* Bc = bufA + 32768;
    const bool pf2 = (kt + 2 < nkt);
    const long kn2 = (long)(kt + 2) << 7;

    i32x8v bfr[4];
#pragma unroll
    for (int j = 0; j < 4; ++j) {
      const int r = wn * 64 + j * 16 + e;
      const i32x4v lo = *(const i32x4v*)(Bc + r * 128 + ((g * 16) ^ rx));
      const i32x4v hi = *(const i32x4v*)(Bc + r * 128 + ((g * 16 + 64) ^ rx));
      bfr[j] = mk8(lo, hi);
    }
    i32x8v af0[2];
#pragma unroll
    for (int i = 0; i < 2; ++i) {
      const int r = wm * 64 + i * 16 + e;
      const i32x4v lo = *(const i32x4v*)(Ac + r * 128 + ((g * 16) ^ rx));
      const i32x4v hi = *(const i32x4v*)(Ac + r * 128 + ((g * 16 + 64) ^ rx));
      af0[i] = mk8(lo, hi);
    }
    if (pf2) {
#pragma unroll
      for (int c = 0; c < 3; ++c)
        gload_lds16(Abase + (long)c * 64 * K + kn2, bufC + lof + c * 8192);
    }
    barrier_pin();
    WAIT_LGKM0();
    __builtin_amdgcn_s_setprio(1);
#pragma unroll
    for (int i = 0; i < 2; ++i)
#pragma unroll
      for (int j = 0; j < 4; ++j)
        acc[i][j] = __builtin_amdgcn_mfma_scale_f32_16x16x128_f8f6f4(
            af0[i], bfr[j], acc[i][j], 0, 0, 0, 127, 0, SB);
    __builtin_amdgcn_s_setprio(0);
    barrier_pin();

    i32x8v af1[2];
#pragma unroll
    for (int i = 0; i < 2; ++i) {
      const int r = wm * 64 + (2 + i) * 16 + e;
      const i32x4v lo = *(const i32x4v*)(Ac + r * 128 + ((g * 16) ^ rx));
      const i32x4v hi = *(const i32x4v*)(Ac + r * 128 + ((g * 16 + 64) ^ rx));
      af1[i] = mk8(lo, hi);
    }
    if (pf2) {
      gload_lds16(Abase + (long)3 * 64 * K + kn2, bufC + lof + 3 * 8192);
      gload_lds16(Bbase + kn2, bufC + 32768 + lof);
      gload_lds16(Bbase + (long)64 * K + kn2, bufC + 32768 + lof + 8192);
      WAIT_VM(6);
    } else if (kt + 1 < nkt) {
      WAIT_VM(0);
    }
    barrier_pin();
    WAIT_LGKM0();
    __builtin_amdgcn_s_setprio(1);
#pragma unroll
    for (int i = 0; i < 2; ++i)
#pragma unroll
      for (int j = 0; j < 4; ++j)
        acc[2 + i][j] = __builtin_amdgcn_mfma_scale_f32_16x16x128_f8f6f4(
            af1[i], bfr[j], acc[2 + i][j], 0, 0, 0, 127, 0, SB);
    __builtin_amdgcn_s_setprio(0);
    barrier_pin();

    char* t = bufA; bufA = bufB; bufB = bufC; bufC = t;
  }

  const int r0 = wm * 64 + (g << 2);
  const int c0 = wn * 64 + e;
  if (OFP8) {
    unsigned char* O = (unsigned char*)Cv;
#pragma unroll
    for (int j = 0; j < 4; ++j) {
      const long gcol = col0 + c0 + (j << 4);
      const float bvv = bias[gcol];
#pragma unroll
      for (int mf = 0; mf < 4; ++mf)
#pragma unroll
        for (int r = 0; r < 4; ++r) {
          const long grow = row0 + r0 + (mf << 4) + r;
          const float v = fmaxf(acc[mf][j][r] + bvv, 0.f);
          O[grow * (long)N + gcol] =
              (unsigned char)(__builtin_amdgcn_cvt_pk_fp8_f32(v, v, 0, false) & 0xFF);
        }
    }
  } else {
    float* O = (float*)Cv;
#pragma unroll
    for (int j = 0; j < 4; ++j) {
      const long gcol = col0 + c0 + (j << 4);
      const float bvv = bias[gcol];
#pragma unroll
      for (int mf = 0; mf < 4; ++mf)
#pragma unroll
        for (int r = 0; r < 4; ++r) {
          const long grow = row0 + r0 + (mf << 4) + r;
          O[grow * (long)N + gcol] = acc[mf][j][r] + bvv + res[grow * (long)N + gcol];
        }
    }
  }
}

// -------- weight transpose + cast: W[K][N] f32 -> Wt[N][K] bf16 --------
__global__ __launch_bounds__(256) void wtrans(const float* __restrict__ W,
                                              unsigned short* __restrict__ Wt,
                                              int K, int N) {
  __shared__ float t[32][33];
  const int tx = threadIdx.x & 31, ty = threadIdx.x >> 5;
  const int n0 = blockIdx.x << 5, k0 = blockIdx.y << 5;
#pragma unroll
  for (int i = 0; i < 32; i += 8)
    t[ty + i][tx] = W[(long)(k0 + ty + i) * N + n0 + tx];
  __syncthreads();
#pragma unroll
  for (int i = 0; i < 32; i += 8)
    Wt[(long)(n0 + ty + i) * K + k0 + tx] = f2bf(t[tx][ty + i]);
}

// -------- weight transpose + cast to fp8 (x scale): W -> Wt8[N][K] ----------
__global__ __launch_bounds__(256) void wtrans8(const float* __restrict__ W,
                                               unsigned char* __restrict__ Wt,
                                               int K, int N, float scale) {
  __shared__ float t[32][33];
  const int tx = threadIdx.x & 31, ty = threadIdx.x >> 5;
  const int n0 = blockIdx.x << 5, k0 = blockIdx.y << 5;
#pragma unroll
  for (int i = 0; i < 32; i += 8)
    t[ty + i][tx] = W[(long)(k0 + ty + i) * N + n0 + tx];
  __syncthreads();
  const int n = threadIdx.x >> 3, kq = threadIdx.x & 7;
  const unsigned int p = pk4fp8(t[kq * 4 + 0][n] * scale, t[kq * 4 + 1][n] * scale,
                                t[kq * 4 + 2][n] * scale, t[kq * 4 + 3][n] * scale);
  *(unsigned int*)(Wt + (long)(n0 + n) * K + k0 + kq * 4) = p;
}

// -------- projT prep: projTs[m][d] = bf16(proj[d][m]*0.125), pre-swizzled ----
__global__ __launch_bounds__(256) void projt_prep(const float* __restrict__ proj,
                                                  unsigned short* __restrict__ projTs) {
  const int t = threadIdx.x;
  const int m = t >> 1, sh = t & 1;
#pragma unroll
  for (int s4 = 0; s4 < 4; ++s4) {
    const int s = sh * 4 + s4;
    unsigned short v[8];
#pragma unroll
    for (int k = 0; k < 8; ++k)
      v[k] = f2bf(proj[(s * 8 + k) * 128 + m] * 0.125f);
    uint4 o;
    o.x = (unsigned)v[0] | ((unsigned)v[1] << 16);
    o.y = (unsigned)v[2] | ((unsigned)v[3] << 16);
    o.z = (unsigned)v[4] | ((unsigned)v[5] << 16);
    o.w = (unsigned)v[6] | ((unsigned)v[7] << 16);
    *(uint4*)((char*)projTs + m * 128 + ((s ^ (m & 7)) << 4)) = o;
  }
}

// -------- LayerNorm over 1024 cols, f32 in -> bf16 out --------
__global__ __launch_bounds__(256) void ln_kernel(const float* __restrict__ x,
                                                 const float* __restrict__ g,
                                                 const float* __restrict__ b,
                                                 unsigned short* __restrict__ out) {
  const int row = blockIdx.x, tid = threadIdx.x;
  const float* xr = x + (long)row * 1024;
  const float4 xv = *(const float4*)(xr + tid * 4);
  float s = xv.x + xv.y + xv.z + xv.w;
  float s2 = xv.x * xv.x + xv.y * xv.y + xv.z * xv.z + xv.w * xv.w;
#pragma unroll
  for (int off = 32; off > 0; off >>= 1) {
    s += __shfl_down(s, off);
    s2 += __shfl_down(s2, off);
  }
  __shared__ float ps[4], ps2[4];
  if ((tid & 63) == 0) { ps[tid >> 6] = s; ps2[tid >> 6] = s2; }
  __syncthreads();
  const float ts = ps[0] + ps[1] + ps[2] + ps[3];
  const float ts2 = ps2[0] + ps2[1] + ps2[2] + ps2[3];
  const float mu = ts * (1.f / 1024.f);
  const float rstd = rsqrtf(ts2 * (1.f / 1024.f) - mu * mu + 1e-5f);
  const float4 gv = *(const float4*)(g + tid * 4);
  const float4 bv = *(const float4*)(b + tid * 4);
  ushort4 o;
  o.x = f2bf((xv.x - mu) * rstd * gv.x + bv.x);
  o.y = f2bf((xv.y - mu) * rstd * gv.y + bv.y);
  o.z = f2bf((xv.z - mu) * rstd * gv.z + bv.z);
  o.w = f2bf((xv.w - mu) * rstd * gv.w + bv.w);
  *(ushort4*)(out + (long)row * 1024 + tid * 4) = o;
}

// -------- LayerNorm -> fp8 out (for FFN path) --------
__global__ __launch_bounds__(256) void ln_kernel8(const float* __restrict__ x,
                                                  const float* __restrict__ g,
                                                  const float* __restrict__ b,
                                                  unsigned char* __restrict__ out) {
  const int row = blockIdx.x, tid = threadIdx.x;
  const float* xr = x + (long)row * 1024;
  const float4 xv = *(const float4*)(xr + tid * 4);
  float s = xv.x + xv.y + xv.z + xv.w;
  float s2 = xv.x * xv.x + xv.y * xv.y + xv.z * xv.z + xv.w * xv.w;
#pragma unroll
  for (int off = 32; off > 0; off >>= 1) {
    s += __shfl_down(s, off);
    s2 += __shfl_down(s2, off);
  }
  __shared__ float ps[4], ps2[4];
  if ((tid & 63) == 0) { ps[tid >> 6] = s; ps2[tid >> 6] = s2; }
  __syncthreads();
  const float ts = ps[0] + ps[1] + ps[2] + ps[3];
  const float ts2 = ps2[0] + ps2[1] + ps2[2] + ps2[3];
  const float mu = ts * (1.f / 1024.f);
  const float rstd = rsqrtf(ts2 * (1.f / 1024.f) - mu * mu + 1e-5f);
  const float4 gv = *(const float4*)(g + tid * 4);
  const float4 bv = *(const float4*)(b + tid * 4);
  const unsigned int p = pk4fp8((xv.x - mu) * rstd * gv.x + bv.x,
                                (xv.y - mu) * rstd * gv.y + bv.y,
                                (xv.z - mu) * rstd * gv.z + bv.z,
                                (xv.w - mu) * rstd * gv.w + bv.w);
  *(unsigned int*)(out + (long)row * 1024 + tid * 4) = p;
}

// -------- kv kernel --------
__global__ __launch_bounds__(256, 2) void kv_kernel(
    const unsigned short* __restrict__ PH, const unsigned short* __restrict__ VTg,
    float* __restrict__ PART, int half) {
  __shared__ __align__(16) unsigned short Ps[64 * 128];
  __shared__ __align__(16) unsigned short Vs[64 * 64];
  __shared__ __align__(16) unsigned short KPT[256 * 64];
  const int tid = threadIdx.x;
  const int lane = tid & 63, wid = tid >> 6;
  const int bhh = blockIdx.x, chunk = blockIdx.y;
  const int b2 = bhh >> 4, h = bhh & 15;
  const int bh = (half * 2 + b2) * 16 + h;

  f32x4 acc[4][4] = {};
  const int e = lane & 15, g = lane >> 4;
  const int m = tid & 127, isin = tid >> 7;
  const int m2 = (isin << 7) + m, swm = m & 7;

  for (int ti = 0; ti < 4; ++ti) {
    const int l0 = chunk * 256 + ti * 64;
    __syncthreads();
#pragma unroll
    for (int c = 0; c < 4; ++c) {
      const int r = l0 + c * 16 + (tid >> 4);
      gload_lds16((const char*)PH + (long)(b2 * 4096 + r) * 4096 + h * 256 + (tid & 15) * 16,
                  (char*)Ps + c * 4096 + (wid << 10));
    }
#pragma unroll
    for (int c = 0; c < 2; ++c) {
      const int d = c * 32 + (tid >> 3);
      gload_lds16((const char*)VTg + ((long)(bh * 64 + d) * 4096 + l0) * 2 + (tid & 7) * 16,
                  (char*)Vs + c * 4096 + (wid << 10));
    }
    __syncthreads();
    {
      char* krow = (char*)KPT + m2 * 128;
#pragma unroll
      for (int g8 = 0; g8 < 8; ++g8) {
        unsigned pk[4];
#pragma unroll
        for (int k2 = 0; k2 < 4; ++k2) {
          const float p0 = bf2f(Ps[(g8 * 8 + k2 * 2) * 128 + m]);
          const float p1 = bf2f(Ps[(g8 * 8 + k2 * 2 + 1) * 128 + m]);
          const float v0 = (isin ? __sinf(p0) : __cosf(p0)) * RS128;
          const float v1 = (isin ? __sinf(p1) : __cosf(p1)) * RS128;
          pk[k2] = pack2f(v0, v1);
        }
        uint4 o; o.x = pk[0]; o.y = pk[1]; o.z = pk[2]; o.w = pk[3];
        *(uint4*)(krow + ((g8 ^ swm) << 4)) = o;
      }
    }
    __syncthreads();
#pragma unroll
    for (int kk = 0; kk < 2; ++kk) {
      const int ch = (kk << 2) + g;
      bf16x8 af[4], bfr[4];
#pragma unroll
      for (int i = 0; i < 4; ++i) {
        const int dr = (i << 4) + e;
        af[i] = *(const bf16x8*)((char*)Vs + dr * 128 + ((ch ^ (e & 7)) << 4));
      }
#pragma unroll
      for (int j = 0; j < 4; ++j) {
        const int mr = (wid << 6) + (j << 4) + e;
        bfr[j] = *(const bf16x8*)((char*)KPT + mr * 128 + ((ch ^ (e & 7)) << 4));
      }
#pragma unroll
      for (int i = 0; i < 4; ++i)
#pragma unroll
        for (int j = 0; j < 4; ++j)
          acc[i][j] = __builtin_amdgcn_mfma_f32_16x16x32_bf16(af[i], bfr[j],
                                                              acc[i][j], 0, 0, 0);
    }
  }
  float* slice = PART + ((long)chunk * 32 + bhh) * 16384;
#pragma unroll
  for (int i = 0; i < 4; ++i)
#pragma unroll
    for (int j = 0; j < 4; ++j)
#pragma unroll
      for (int r = 0; r < 4; ++r) {
        const int d = (i << 4) + (g << 2) + r;
        const int mc = (wid << 6) + (j << 4) + e;
        slice[d * 256 + mc] = acc[i][j][r];
      }
}

// -------- kv_reduce: sum 16 partials -> KVT bf16 (chunk-swizzled), fused ----
__global__ __launch_bounds__(256) void kv_reduce(const float* __restrict__ PART,
                                                 unsigned short* __restrict__ KVT,
                                                 int half) {
  const int bhh = blockIdx.x, seg = blockIdx.y;   // grid (32, 8)
  const int idx = seg * 2048 + threadIdx.x * 8;   // 8 m's per thread
  const long off = (long)bhh * 16384 + idx;
  float4 a = make_float4(0.f, 0.f, 0.f, 0.f);
  float4 b = make_float4(0.f, 0.f, 0.f, 0.f);
#pragma unroll
  for (int c = 0; c < 16; ++c) {
    const float4 v0 = *(const float4*)(PART + ((long)c * 32) * 16384 + off);
    const float4 v1 = *(const float4*)(PART + ((long)c * 32) * 16384 + off + 4);
    a.x += v0.x; a.y += v0.y; a.z += v0.z; a.w += v0.w;
    b.x += v1.x; b.y += v1.y; b.z += v1.z; b.w += v1.w;
  }
  const int d = idx >> 8, m0 = idx & 255;
  const int chunk = m0 >> 3;
  uint4 o;
  o.x = pack2f(a.x, a.y); o.y = pack2f(a.z, a.w);
  o.z = pack2f(b.x, b.y); o.w = pack2f(b.z, b.w);
  char* dst = (char*)KVT + (long)(half * 32 + bhh) * 32768 + d * 512;
  *(uint4*)(dst + ((chunk ^ (d & 7)) << 4)) = o;
}

// -------- attn kernel --------
__global__ __launch_bounds__(256, 2) void attn_kernel(
    const unsigned short* __restrict__ PH, const unsigned short* __restrict__ KVT,
    unsigned short* __restrict__ ATTN, int half) {
  __shared__ __align__(16) unsigned short QPs[64 * 256];
  __shared__ __align__(16) unsigned short KVs[64 * 256];
  const int tid = threadIdx.x;
  const int lane = tid & 63, wid = tid >> 6;
  const int bhh = blockIdx.x, chunk = blockIdx.y;
  const int b2 = bhh >> 4, h = bhh & 15;
  const int b = half * 2 + b2, bh = b * 16 + h;
  const int e = lane & 15, g = lane >> 4;

#pragma unroll
  for (int c = 0; c < 8; ++c)
    gload_lds16((const char*)KVT + bh * 32768 + c * 4096 + tid * 16,
                (char*)KVs + c * 4096 + (wid << 10));

  const int lrow = tid >> 2, ms = tid & 3, swl = lrow & 7;

  for (int ti = 0; ti < 4; ++ti) {
    const int l0 = chunk * 256 + ti * 64;
    const char* pg = (const char*)PH + (long)(b2 * 4096 + l0 + lrow) * 4096 + h * 256 + ms * 64;
    uint4 P[4];
#pragma unroll
    for (int q = 0; q < 4; ++q) P[q] = *(const uint4*)(pg + q * 16);
    uint4 CQ[4], SQ[4];
#pragma unroll
    for (int q = 0; q < 4; ++q) {
      const unsigned w[4] = {P[q].x, P[q].y, P[q].z, P[q].w};
      unsigned cw[4], sw[4];
#pragma unroll
      for (int k = 0; k < 4; ++k) {
        float c0, s0, c1, s1;
        __sincosf(bf2f((unsigned short)(w[k] & 0xffff)), &s0, &c0);
        __sincosf(bf2f((unsigned short)(w[k] >> 16)), &s1, &c1);
        cw[k] = pack2f(c0 * RS128, c1 * RS128);
        sw[k] = pack2f(s0 * RS128, s1 * RS128);
      }
      CQ[q].x = cw[0]; CQ[q].y = cw[1]; CQ[q].z = cw[2]; CQ[q].w = cw[3];
      SQ[q].x = sw[0]; SQ[q].y = sw[1]; SQ[q].z = sw[2]; SQ[q].w = sw[3];
    }
    __syncthreads();
    {
      char* qrow = (char*)QPs + lrow * 512;
#pragma unroll
      for (int q = 0; q < 4; ++q) {
        const int c = ms * 4 + q;
        *(uint4*)(qrow + ((c ^ swl) << 4)) = CQ[q];
        *(uint4*)(qrow + ((16 + (c ^ swl)) << 4)) = SQ[q];
      }
    }
    __syncthreads();
    f32x4 acc[4] = {};
    const int lr = (wid << 4) + e;
#pragma unroll
    for (int kk = 0; kk < 8; ++kk) {
      const int ch = (kk << 2) + g;
      const bf16x8 af = *(const bf16x8*)((char*)QPs + lr * 512 + ((ch ^ (e & 7)) << 4));
#pragma unroll
      for (int j = 0; j < 4; ++j) {
        const bf16x8 bfr = *(const bf16x8*)((char*)KVs + ((j << 4) + e) * 512 + ((ch ^ (e & 7)) << 4));
        acc[j] = __builtin_amdgcn_mfma_f32_16x16x32_bf16(af, bfr, acc[j], 0, 0, 0);
      }
    }
#pragma unroll
    for (int j = 0; j < 4; ++j)
#pragma unroll
      for (int r = 0; r < 4; ++r) {
        const int lo = (wid << 4) + (g << 2) + r;
        ATTN[(long)(b * 4096 + l0 + lo) * 1024 + h * 64 + (j << 4) + e] = f2bf(acc[j][r]);
      }
  }
}

extern "C" void kernel_launch(void* const* d_in, const int* in_sizes, int n_in,
                              void* d_out, int out_size, void* d_ws, size_t ws_size,
                              hipStream_t stream) {
  (void)in_sizes; (void)n_in; (void)out_size; (void)ws_size;
  const float* x    = (const float*)d_in[0];
  const float* proj = (const float*)d_in[1];
  const float* wq = (const float*)d_in[2];
  const float* bq = (const float*)d_in[3];
  const float* wk = (const float*)d_in[4];
  const float* bk = (const float*)d_in[5];
  const float* wv = (const float*)d_in[6];
  const float* bv = (const float*)d_in[7];
  const float* wo = (const float*)d_in[8];
  const float* bo = (const float*)d_in[9];
  const float* g1  = (const float*)d_in[10];
  const float* be1 = (const float*)d_in[11];
  const float* w1 = (const float*)d_in[12];
  const float* b1 = (const float*)d_in[13];
  const float* w2 = (const float*)d_in[14];
  const float* b2 = (const float*)d_in[15];
  const float* g2  = (const float*)d_in[16];
  const float* be2 = (const float*)d_in[17];
  float* out = (float*)d_out;

  char* ws = (char*)d_ws;
  const size_t MB = 1u << 20;
  unsigned short* WQT    = (unsigned short*)(ws + 0 * MB);
  unsigned short* WKT    = (unsigned short*)(ws + 2 * MB);
  unsigned short* WVT    = (unsigned short*)(ws + 4 * MB);
  unsigned short* WOT    = (unsigned short*)(ws + 6 * MB);
  unsigned short* projTs = (unsigned short*)(ws + 8 * MB);
  unsigned short* KVT = (unsigned short*)(ws + 14 * MB);
  unsigned short* VTg  = (unsigned short*)(ws + 16 * MB);   // -> ATTN
  unsigned short* PH   = (unsigned short*)(ws + 64 * MB);
  float* PART  = (float*)(ws + 96 * MB);
  unsigned char* Hb8   = (unsigned char*)(ws + 0 * MB);     // FFN hidden fp8 (64MB)
  unsigned short* X2   = (unsigned short*)(ws + 128 * MB);  // -> X2B8
  unsigned char* X2B8  = (unsigned char*)(ws + 128 * MB);
  unsigned char* W1T8  = (unsigned char*)(ws + 160 * MB);
  unsigned char* W2T8  = (unsigned char*)(ws + 164 * MB);
  unsigned short* ATTN = VTg;

  dim3 blk(256), blk5(512);

  // weights prep
  wtrans<<<dim3(32, 32), blk, 0, stream>>>(wq, WQT, 1024, 1024);
  wtrans<<<dim3(32, 32), blk, 0, stream>>>(wk, WKT, 1024, 1024);
  wtrans<<<dim3(32, 32), blk, 0, stream>>>(wv, WVT, 1024, 1024);
  wtrans<<<dim3(32, 32), blk, 0, stream>>>(wo, WOT, 1024, 1024);
  wtrans8<<<dim3(128, 32), blk, 0, stream>>>(w1, W1T8, 1024, 4096, 16.f);
  wtrans8<<<dim3(32, 128), blk, 0, stream>>>(w2, W2T8, 4096, 1024, 16.f);
  projt_prep<<<1, blk, 0, stream>>>(proj, projTs);

  // LN1 -> bf16
  ln_kernel<<<16384, blk, 0, stream>>>(x, g1, be1, X2);

  // V gemm (bf16) with fused transpose epilogue -> VTg
  gemm256<false, false, false, false, true><<<512, blk5, 0, stream>>>(
      X2, WVT, VTg, bv, nullptr, nullptr, 16384, 1024, 1024);

  // kv pipeline, two L-halves: K gemm (bf16) + PROJ -> PH -> kv -> KVT
  for (int half = 0; half < 2; ++half) {
    gemm256<true, false, false, true, false><<<256, blk5, 0, stream>>>(
        X2 + (long)half * 8192 * 1024, WKT, PH, bk, nullptr, projTs, 8192, 1024, 1024);
    kv_kernel<<<dim3(32, 16), blk, 0, stream>>>(PH, VTg, PART, half);
    kv_reduce<<<dim3(32, 8), blk, 0, stream>>>(PART, KVT, half);
  }

  // attn pipeline, two L-halves (ATTN bf16)
  for (int half = 0; half < 2; ++half) {
    gemm256<true, false, false, true, false><<<256, blk5, 0, stream>>>(
        X2 + (long)half * 8192 * 1024, WQT, PH, bq, nullptr, projTs, 8192, 1024, 1024);
    attn_kernel<<<dim3(32, 16), blk, 0, stream>>>(PH, KVT, ATTN, half);
  }

  // Wo (bf16) + residual -> out (f32)
  gemm256<false, false, true, false, false><<<512, blk5, 0, stream>>>(
      ATTN, WOT, out, bo, x, nullptr, 16384, 1024, 1024);

  // LN2 -> fp8 (X2 region dead)
  ln_kernel8<<<16384, blk, 0, stream>>>(out, g2, be2, X2B8);

  // FFN in MX-fp8 (weights x16 -> B-scale e8m0=123 == 2^-4)
  gemm256f8<true, 123><<<2048, blk5, 0, stream>>>(
      (const char*)X2B8, (const char*)W1T8, Hb8, b1, nullptr, 16384, 4096, 1024);
  gemm256f8<false, 123><<<512, blk5, 0, stream>>>(
      (const char*)Hb8, (const char*)W2T8, out, b2, out, 16384, 1024, 4096);
}